// Round 1
// 720.603 us; speedup vs baseline: 1.1144x; 1.1144x over previous
//
#include <hip/hip_runtime.h>
#include <hip/hip_bf16.h>

typedef __hip_bfloat16 bf16;
typedef __attribute__((ext_vector_type(8))) short short8;
typedef __attribute__((ext_vector_type(4))) float floatx4;

#define DI __device__ __forceinline__

DI float ldf(const float* p, long long i){ return p[i]; }
DI float ldf(const bf16* p, long long i){ return __bfloat162float(p[i]); }
DI void stf(float* p, long long i, float v){ p[i] = v; }
DI void stf(bf16* p, long long i, float v){ p[i] = __float2bfloat16(v); }

DI unsigned short bfbits(float f){
    bf16 h = __float2bfloat16(f);
    return *reinterpret_cast<unsigned short*>(&h);
}
DI float bu(unsigned short u){
    union { unsigned int i; float f; } x; x.i = ((unsigned int)u) << 16; return x.f;
}

// direct global->LDS 16B load (m97 trick). lds dest: wave-uniform base + lane*16.
DI void gload16(const void* g, void* l){
    __builtin_amdgcn_global_load_lds(
        (const __attribute__((address_space(1))) unsigned int*)g,
        (__attribute__((address_space(3))) unsigned int*)l,
        16, 0, 0);
}

static constexpr int BATCH = 8;
static constexpr int HH = 56, WW = 56;
static constexpr int NPOS = HH * WW;        // 3136
static constexpr int CDIM = 256;
static constexpr int HIDD = 1024;
static constexpr int MTOT = BATCH * NPOS;   // 25088
static constexpr int NCHUNK = 49;           // 3136 / 64
static constexpr int LP = 40;               // LDS pitch for tn gemm (shorts)
static constexpr int TNS = 7;               // split-K for ctx TN gemm

// ---------------- weight f32 -> bf16 pre-convert ----------------
struct WArgs {
    const float* src[10];
    bf16* dst[10];
    int n[10];
};
__global__ __launch_bounds__(256) void wcvt_kernel(WArgs a){
    int wid = blockIdx.y;
    int i = (blockIdx.x*256 + threadIdx.x) * 8;
    if (i >= a.n[wid]) return;
    const float* s = a.src[wid] + i;
    float4 f0 = *(const float4*)(s);
    float4 f1 = *(const float4*)(s + 4);
    union { uint4 u; unsigned short us[8]; } p;
    p.us[0]=bfbits(f0.x); p.us[1]=bfbits(f0.y); p.us[2]=bfbits(f0.z); p.us[3]=bfbits(f0.w);
    p.us[4]=bfbits(f1.x); p.us[5]=bfbits(f1.y); p.us[6]=bfbits(f1.z); p.us[7]=bfbits(f1.w);
    *(uint4*)(a.dst[wid] + i) = p.u;
}

__global__ __launch_bounds__(256) void wtrans_kernel(const float* __restrict__ w1, const float* __restrict__ w2,
                                                     float* __restrict__ t1, float* __restrict__ t2){
    int i = blockIdx.x*256 + threadIdx.x;   // 0..9215
    const float* w = blockIdx.y ? w2 : w1;
    float* t = blockIdx.y ? t2 : t1;
    int tap = i >> 10, c = i & 1023;
    t[i] = w[c*9 + tap];
}

// ---------------- MFMA bf16 GEMM (NT), global_load_lds staging ----------------
// LDS layout: 16B chunk c holds tile[row=c>>2][col16=(c&3)^(row&3)] (XOR swizzle, no pad).
// XCD-bijective tile swizzle: each XCD owns a contiguous chunk of tiles, n-fastest
//   -> A-tile refetched by blocks on the SAME XCD (L2 hit) instead of 8 different L2s.
// bf16 epilogue: per-wave LDS transpose -> one uint4 (8x bf16) store per lane per row-octet
//   (replaces 64 scalar 2B stores/lane whose 32B segments caused ~2.3x HBM write amplification).
template<typename TC>
__global__ __launch_bounds__(256) void mfma_gemm(
    const bf16* __restrict__ A, const bf16* __restrict__ Bw,
    const float* __restrict__ bias, const float* __restrict__ addend,
    TC* __restrict__ C, int M, int N, int K, int lda,
    long long strA, long long strB, long long strC, long long strAdd)
{
    __shared__ __align__(16) float smemf[4608];   // 18 KB: K-loop tiles (16 KB), then epilogue scratch (17.4 KB)
    short* As = (short*)smemf;                    // bytes [0, 8192)
    short* Bs = (short*)smemf + 4096;             // bytes [8192, 16384)
    int tid = threadIdx.x;
    int bz = blockIdx.z;
    A  += (long long)bz * strA;
    Bw += (long long)bz * strB;
    C  += (long long)bz * strC;
    if (addend) addend += (long long)bz * strAdd;

    // --- bijective XCD chunk swizzle (m204) over the (x,y) tile space ---
    int gx = gridDim.x;
    int nwg = gx * gridDim.y;
    int bidl = blockIdx.y * gx + blockIdx.x;
    int qq = nwg >> 3, rr = nwg & 7;
    int xcd = bidl & 7, ixx = bidl >> 3;
    int tile = (xcd < rr) ? (xcd*(qq+1) + ixx) : (rr*(qq+1) + (xcd-rr)*qq + ixx);
    int n0 = (tile % gx) * 128, m0 = (tile / gx) * 128;

    int w = tid >> 6, lane = tid & 63, lm = lane & 15, quad = lane >> 4;
    int mw = (w >> 1) * 64, nw = (w & 1) * 64;

    // staging: wave w issues instructions t=2w,2w+1; lane covers chunk t*64+lane.
    int c0 = w*128 + lane, c1 = c0 + 64;
    int ar0 = c0 >> 2, ac0 = (c0 & 3) ^ (ar0 & 3);
    int ar1 = c1 >> 2, ac1 = (c1 & 3) ^ (ar1 & 3);
    int rgA0 = m0 + ar0; if (rgA0 > M-1) rgA0 = M-1;
    int rgA1 = m0 + ar1; if (rgA1 > M-1) rgA1 = M-1;
    short* aL0 = &As[(2*w+0)*512];
    short* aL1 = &As[(2*w+1)*512];
    short* bL0 = &Bs[(2*w+0)*512];
    short* bL1 = &Bs[(2*w+1)*512];
    const bf16* Arow0 = A + (long long)rgA0*lda + ac0*8;
    const bf16* Arow1 = A + (long long)rgA1*lda + ac1*8;
    const bf16* Brow0 = Bw + (long long)(n0+ar0)*K + ac0*8;
    const bf16* Brow1 = Bw + (long long)(n0+ar1)*K + ac1*8;

    floatx4 z = {0.f, 0.f, 0.f, 0.f};
    floatx4 acc[4][4];
    #pragma unroll
    for (int mi = 0; mi < 4; mi++)
        #pragma unroll
        for (int ni = 0; ni < 4; ni++) acc[mi][ni] = z;

    int sq = quad ^ (lm & 3);   // read-side swizzle (row&3 == lm&3 for all fragment rows)

    for (int k0 = 0; k0 < K; k0 += 32){
        gload16(Arow0 + k0, aL0);
        gload16(Arow1 + k0, aL1);
        gload16(Brow0 + k0, bL0);
        gload16(Brow1 + k0, bL1);
        __syncthreads();
        short8 af[4], bfr[4];
        #pragma unroll
        for (int mi = 0; mi < 4; mi++)
            af[mi] = *(const short8*)&As[(((mw + mi*16 + lm)<<2) + sq)*8];
        #pragma unroll
        for (int ni = 0; ni < 4; ni++)
            bfr[ni] = *(const short8*)&Bs[(((nw + ni*16 + lm)<<2) + sq)*8];
        #pragma unroll
        for (int mi = 0; mi < 4; mi++)
            #pragma unroll
            for (int ni = 0; ni < 4; ni++)
                acc[mi][ni] = __builtin_amdgcn_mfma_f32_16x16x32_bf16(af[mi], bfr[ni], acc[mi][ni], 0, 0, 0);
        __syncthreads();
    }

    if constexpr (sizeof(TC) == 2) {
        // --- bf16 epilogue: per-wave transpose through LDS, packed 16B stores ---
        // After the final __syncthreads() no wave touches As/Bs again; each wave uses
        // its private scratch strip (stride 68 f32 kills bank conflicts). DS ops of a
        // wave complete in order, so no barrier is needed between write and read-back.
        float bvv[4];
        #pragma unroll
        for (int ni = 0; ni < 4; ni++)
            bvv[ni] = bias ? bias[n0 + nw + ni*16 + lm] : 0.f;
        float* esc = smemf + w*1088;            // 16 rows x 68 floats per wave
        int rl0 = lane >> 3;                    // 0..7
        int cl  = (lane & 7) * 8;               // 0..56, lane-octet covers 128B/row
        #pragma unroll
        for (int mi = 0; mi < 4; mi++){
            #pragma unroll
            for (int ni = 0; ni < 4; ni++)
                #pragma unroll
                for (int r = 0; r < 4; r++)
                    esc[(quad*4 + r)*68 + ni*16 + lm] = acc[mi][ni][r] + bvv[ni];
            #pragma unroll
            for (int p = 0; p < 2; p++){
                int rloc = p*8 + rl0;
                int rg = m0 + mw + mi*16 + rloc;
                float4 u0 = *(const float4*)&esc[rloc*68 + cl];
                float4 u1 = *(const float4*)&esc[rloc*68 + cl + 4];
                if (addend){
                    long long ai = (long long)rg*N + (n0 + nw + cl);
                    float4 a0 = *(const float4*)(addend + ai);
                    float4 a1 = *(const float4*)(addend + ai + 4);
                    u0.x+=a0.x; u0.y+=a0.y; u0.z+=a0.z; u0.w+=a0.w;
                    u1.x+=a1.x; u1.y+=a1.y; u1.z+=a1.z; u1.w+=a1.w;
                }
                union { uint4 u; unsigned short us[8]; } pk;
                pk.us[0]=bfbits(u0.x); pk.us[1]=bfbits(u0.y); pk.us[2]=bfbits(u0.z); pk.us[3]=bfbits(u0.w);
                pk.us[4]=bfbits(u1.x); pk.us[5]=bfbits(u1.y); pk.us[6]=bfbits(u1.z); pk.us[7]=bfbits(u1.w);
                if (rg < M)
                    *(uint4*)(C + (long long)rg*N + (n0 + nw + cl)) = pk.u;
            }
        }
    } else {
        #pragma unroll
        for (int ni = 0; ni < 4; ni++){
            int cg = n0 + nw + ni*16 + lm;
            float bv = bias ? bias[cg] : 0.f;
            #pragma unroll
            for (int mi = 0; mi < 4; mi++){
                #pragma unroll
                for (int r = 0; r < 4; r++){
                    int rg = m0 + mw + mi*16 + quad*4 + r;
                    if (rg < M){
                        long long idx = (long long)rg*N + cg;
                        float v = acc[mi][ni][r] + bv;
                        if (addend) v += addend[idx];
                        stf(C, idx, v);
                    }
                }
            }
        }
    }
}

// ---------------- MFMA bf16 TN GEMM: part[s][vc][kc] = sum_{n in split s} V[n,vc]*K[n,kc] ----------------
__global__ __launch_bounds__(256) void gemm_tn_mfma(const bf16* __restrict__ V, const bf16* __restrict__ Kb,
                                                    float* __restrict__ part){
    __shared__ short As[128*LP];
    __shared__ short Bs[128*LP];
    int tid = threadIdx.x;
    int bz = blockIdx.z;           // b*TNS + s
    int b = bz / TNS, s = bz % TNS;
    const bf16* Vb = V  + (long long)b*NPOS*CDIM;
    const bf16* Kc = Kb + (long long)b*NPOS*CDIM;
    int m0 = blockIdx.y * 128, n0 = blockIdx.x * 128;
    int w = tid >> 6, lane = tid & 63, lm = lane & 15, quad = lane >> 4;
    int mw = (w >> 1) * 64, nw = (w & 1) * 64;

    floatx4 z = {0.f,0.f,0.f,0.f};
    floatx4 acc[4][4];
    #pragma unroll
    for (int mi = 0; mi < 4; mi++)
        #pragma unroll
        for (int ni = 0; ni < 4; ni++) acc[mi][ni] = z;

    int r = tid & 31, cgrp = tid >> 5;

    for (int step = 0; step < 448/32; step++){
        int nb = s*448 + step*32;
        #pragma unroll
        for (int cc = 0; cc < 2; cc++){
            int ch = cgrp*8 + cc*64;
            short8 va = *(const short8*)(Vb + (long long)(nb + r)*CDIM + m0 + ch);
            short8 ka = *(const short8*)(Kc + (long long)(nb + r)*CDIM + n0 + ch);
            #pragma unroll
            for (int i = 0; i < 8; i++){
                As[(ch+i)*LP + r] = va[i];
                Bs[(ch+i)*LP + r] = ka[i];
            }
        }
        __syncthreads();
        short8 af[4], bfr[4];
        #pragma unroll
        for (int mi = 0; mi < 4; mi++)
            af[mi] = *(const short8*)&As[(mw + mi*16 + lm)*LP + quad*8];
        #pragma unroll
        for (int ni = 0; ni < 4; ni++)
            bfr[ni] = *(const short8*)&Bs[(nw + ni*16 + lm)*LP + quad*8];
        #pragma unroll
        for (int mi = 0; mi < 4; mi++)
            #pragma unroll
            for (int ni = 0; ni < 4; ni++)
                acc[mi][ni] = __builtin_amdgcn_mfma_f32_16x16x32_bf16(af[mi], bfr[ni], acc[mi][ni], 0, 0, 0);
        __syncthreads();
    }

    float* pb = part + (long long)bz * CDIM * CDIM;
    #pragma unroll
    for (int ni = 0; ni < 4; ni++){
        int cg = n0 + nw + ni*16 + lm;
        #pragma unroll
        for (int mi = 0; mi < 4; mi++){
            #pragma unroll
            for (int rr = 0; rr < 4; rr++){
                int rg = m0 + mw + mi*16 + quad*4 + rr;
                pb[(long long)rg*CDIM + cg] = acc[mi][ni][rr];
            }
        }
    }
}

__global__ __launch_bounds__(256) void ctx_reduce(const float* __restrict__ part, bf16* __restrict__ ctxb){
    long long idx = (long long)blockIdx.x*256 + threadIdx.x;
    int b = (int)(idx >> 16);
    int rem = (int)(idx & 65535);
    float s = 0.f;
    #pragma unroll
    for (int sp = 0; sp < TNS; sp++)
        s += part[((long long)(b*TNS+sp) << 16) + rem];
    ctxb[idx] = __float2bfloat16(s);
}

// ---------------- LayerNorm: one wave per row ----------------
DI void st4o(float* p, long long i, float a, float b, float c, float d){
    float4 v = make_float4(a,b,c,d); *(float4*)(p + i) = v;
}
DI void st4o(bf16* p, long long i, float a, float b, float c, float d){
    union { unsigned long long u; unsigned short us[4]; } pk;
    pk.us[0]=bfbits(a); pk.us[1]=bfbits(b); pk.us[2]=bfbits(c); pk.us[3]=bfbits(d);
    *(unsigned long long*)(p + i) = pk.u;
}
template<typename TOUT>
__global__ __launch_bounds__(256) void ln4_kernel(const float* __restrict__ x, const float* __restrict__ g,
                                                  const float* __restrict__ b, TOUT* __restrict__ y){
    int wv = threadIdx.x >> 6, lane = threadIdx.x & 63;
    long long row = (long long)blockIdx.x*4 + wv;
    float4 v = *(const float4*)(x + row*256 + lane*4);
    float s  = v.x + v.y + v.z + v.w;
    float ss = v.x*v.x + v.y*v.y + v.z*v.z + v.w*v.w;
    #pragma unroll
    for (int off = 32; off > 0; off >>= 1){
        s  += __shfl_down(s,  off);
        ss += __shfl_down(ss, off);
    }
    s = __shfl(s, 0); ss = __shfl(ss, 0);
    float mean = s * (1.f/256.f);
    float var  = ss * (1.f/256.f) - mean*mean;
    float inv  = rsqrtf(var + 1e-5f);
    float4 gv = *(const float4*)(g + lane*4);
    float4 bv = *(const float4*)(b + lane*4);
    st4o(y, row*256 + lane*4,
         (v.x-mean)*inv*gv.x + bv.x, (v.y-mean)*inv*gv.y + bv.y,
         (v.z-mean)*inv*gv.z + bv.z, (v.w-mean)*inv*gv.w + bv.w);
}

// ---------------- column softmax over N (k = cols 0..255 of KQ[.,512]) ----------------
// NOTE: k bias omitted upstream — softmax over N is invariant to per-column constants.
__global__ __launch_bounds__(256) void colsm_p1(const float* __restrict__ x, float* __restrict__ lmax, float* __restrict__ lsum){
    int b = blockIdx.x / NCHUNK, ch = blockIdx.x % NCHUNK;
    int c = threadIdx.x;
    const float* base = x + ((long long)b*NPOS + ch*64)*512 + c;
    float m = -1e30f;
    for (int r = 0; r < 64; r++) m = fmaxf(m, base[(long long)r*512]);
    float s = 0.f;
    for (int r = 0; r < 64; r++) s += expf(base[(long long)r*512] - m);
    lmax[(long long)blockIdx.x*CDIM + c] = m;
    lsum[(long long)blockIdx.x*CDIM + c] = s;
}
__global__ __launch_bounds__(256) void colsm_p2(const float* __restrict__ lmax, const float* __restrict__ lsum,
                                                float* __restrict__ gmax, float* __restrict__ ginv){
    int b = blockIdx.x; int c = threadIdx.x;
    float g = -1e30f;
    for (int ch = 0; ch < NCHUNK; ch++) g = fmaxf(g, lmax[((long long)b*NCHUNK+ch)*CDIM + c]);
    float s = 0.f;
    for (int ch = 0; ch < NCHUNK; ch++)
        s += lsum[((long long)b*NCHUNK+ch)*CDIM + c] * expf(lmax[((long long)b*NCHUNK+ch)*CDIM + c] - g);
    gmax[b*CDIM + c] = g; ginv[b*CDIM + c] = 1.f / s;
}
__global__ __launch_bounds__(256) void colsm_p3(const float* __restrict__ x, bf16* __restrict__ y,
                                                const float* __restrict__ gmax, const float* __restrict__ ginv){
    long long idx = (long long)blockIdx.x*256 + threadIdx.x;
    int c = (int)(idx & 255);
    long long row = idx >> 8;
    int b = (int)(row / NPOS);
    y[idx] = __float2bfloat16(expf(x[row*512 + c] - gmax[b*CDIM + c]) * ginv[b*CDIM + c]);
}

// ---------------- row softmax (q = cols 256..511 of KQ) + bias, wave-per-row ----------------
__global__ __launch_bounds__(256) void rowsm4b_kernel(const float* __restrict__ x, const float* __restrict__ bias,
                                                      bf16* __restrict__ y){
    int wv = threadIdx.x >> 6, lane = threadIdx.x & 63;
    long long row = (long long)blockIdx.x*4 + wv;
    float4 v = *(const float4*)(x + row*512 + 256 + lane*4);
    float4 bb = *(const float4*)(bias + lane*4);
    v.x += bb.x; v.y += bb.y; v.z += bb.z; v.w += bb.w;
    float m = fmaxf(fmaxf(v.x, v.y), fmaxf(v.z, v.w));
    #pragma unroll
    for (int off = 32; off > 0; off >>= 1) m = fmaxf(m, __shfl_down(m, off));
    m = __shfl(m, 0);
    float e0 = expf(v.x - m), e1 = expf(v.y - m), e2 = expf(v.z - m), e3 = expf(v.w - m);
    float s = e0 + e1 + e2 + e3;
    #pragma unroll
    for (int off = 32; off > 0; off >>= 1) s += __shfl_down(s, off);
    s = __shfl(s, 0);
    float inv = 1.f / s;
    st4o(y, row*256 + lane*4, e0*inv, e1*inv, e2*inv, e3*inv);
}

// ---------------- fused dwconv3x3 + skip + LN + GELU, LDS-tiled, XCD-swizzled ----------------
__global__ __launch_bounds__(256) void dwconv_ln_gelu_kernel(const bf16* __restrict__ f, const float* __restrict__ wT,
        const float* __restrict__ db, const float* __restrict__ lg, const float* __restrict__ lb, bf16* __restrict__ out){
    __shared__ short Ls[18*1024];
    __shared__ float wred[2][8][2];     // [sum|sumsq][wave][pp]
    int tid = threadIdx.x;
    // XCD swizzle: consecutive blockIdx -> different batch images (round-robin XCD => each
    // XCD works one image => halo rows hit its private L2).
    int b = blockIdx.x & 7;
    int rem = blockIdx.x >> 3;              // 0..783
    int h = rem / 14, w0 = (rem % 14) * 4;
    const bf16* fb = f + (long long)b * NPOS * HIDD;

    #pragma unroll
    for (int j = 0; j < 9; j++){
        int idx = j*256 + tid;
        int rc = idx >> 7, chunk = idx & 127;
        int row = rc / 6, col = rc % 6;
        int hy = h - 1 + row, wx = w0 - 1 + col;
        uint4 v = {0,0,0,0};
        if (hy >= 0 && hy < HH && wx >= 0 && wx < WW)
            v = *(const uint4*)(fb + (long long)(hy*WW + wx)*HIDD + chunk*8);
        *(uint4*)&Ls[rc*1024 + chunk*8] = v;
    }
    __syncthreads();

    int ph = tid >> 7, ct = tid & 127;
    int wvid = tid >> 6, ln = tid & 63;
    int c0 = ct * 8;
    float sv[2][8];
    {
        float4 d0 = *(const float4*)(db + c0);
        float4 d1 = *(const float4*)(db + c0 + 4);
        #pragma unroll
        for (int pp = 0; pp < 2; pp++){
            sv[pp][0]=d0.x; sv[pp][1]=d0.y; sv[pp][2]=d0.z; sv[pp][3]=d0.w;
            sv[pp][4]=d1.x; sv[pp][5]=d1.y; sv[pp][6]=d1.z; sv[pp][7]=d1.w;
        }
    }
    #pragma unroll
    for (int tap = 0; tap < 9; tap++){
        int ky = tap / 3, kx = tap % 3;
        float4 w0v = *(const float4*)(wT + tap*1024 + c0);
        float4 w1v = *(const float4*)(wT + tap*1024 + c0 + 4);
        float wv[8] = {w0v.x,w0v.y,w0v.z,w0v.w,w1v.x,w1v.y,w1v.z,w1v.w};
        #pragma unroll
        for (int pp = 0; pp < 2; pp++){
            int pos_local = 2*ph + pp;
            short8 val = *(const short8*)&Ls[(ky*6 + pos_local + kx)*1024 + c0];
            #pragma unroll
            for (int i = 0; i < 8; i++){
                float fv = bu((unsigned short)val[i]);
                sv[pp][i] += fv * wv[i];
                if (tap == 4) sv[pp][i] += fv;
            }
        }
    }
    // LN reduction over 1024 channels = 128 ct-threads (2 waves) per (ph,pp):
    // wave-shuffle reduce + single cross-wave combine (replaces 7-barrier LDS tree).
    #pragma unroll
    for (int pp = 0; pp < 2; pp++){
        float s = 0.f, ss = 0.f;
        #pragma unroll
        for (int i = 0; i < 8; i++){ s += sv[pp][i]; ss += sv[pp][i]*sv[pp][i]; }
        #pragma unroll
        for (int off = 32; off > 0; off >>= 1){
            s  += __shfl_down(s,  off);
            ss += __shfl_down(ss, off);
        }
        if (ln == 0){ wred[0][wvid][pp] = s; wred[1][wvid][pp] = ss; }
    }
    __syncthreads();
    float4 g0 = *(const float4*)(lg + c0), g1 = *(const float4*)(lg + c0 + 4);
    float4 b0 = *(const float4*)(lb + c0), b1 = *(const float4*)(lb + c0 + 4);
    float gg[8] = {g0.x,g0.y,g0.z,g0.w,g1.x,g1.y,g1.z,g1.w};
    float bb[8] = {b0.x,b0.y,b0.z,b0.w,b1.x,b1.y,b1.z,b1.w};
    #pragma unroll
    for (int pp = 0; pp < 2; pp++){
        int pos_local = 2*ph + pp;
        long long n = (long long)b*NPOS + h*WW + (w0 + pos_local);
        float tots  = wred[0][2*ph][pp] + wred[0][2*ph+1][pp];
        float totss = wred[1][2*ph][pp] + wred[1][2*ph+1][pp];
        float mean = tots * (1.f/HIDD);
        float var  = totss * (1.f/HIDD) - mean*mean;
        float inv  = rsqrtf(var + 1e-5f);
        union { uint4 u; unsigned short us[8]; } ov;
        #pragma unroll
        for (int i = 0; i < 8; i++){
            float o = (sv[pp][i]-mean)*inv*gg[i] + bb[i];
            o = 0.5f*o*(1.f + erff(o*0.70710678118654752f));
            ov.us[i] = bfbits(o);
        }
        *(uint4*)(out + n*HIDD + c0) = ov.u;
    }
}

// ---------------- channel-attn: per-channel sum-sq over N ----------------
__global__ __launch_bounds__(256) void ssq_p1(const bf16* __restrict__ qkv, float* __restrict__ lss){
    __shared__ float red[4][64][8];
    int b = blockIdx.x / NCHUNK, ch = blockIdx.x % NCHUNK;
    int tid = threadIdx.x;
    int col = (tid & 63) * 8;
    int rg = tid >> 6;
    float s[8] = {0,0,0,0,0,0,0,0};
    for (int r = rg*16; r < rg*16 + 16; r++){
        long long row = (long long)(b*NPOS + ch*64 + r);
        union { uint4 u; unsigned short us[8]; } v;
        v.u = *(const uint4*)(qkv + row*768 + col);
        #pragma unroll
        for (int i = 0; i < 8; i++){ float f = bu(v.us[i]); s[i] += f*f; }
    }
    #pragma unroll
    for (int i = 0; i < 8; i++) red[rg][tid & 63][i] = s[i];
    __syncthreads();
    if (tid < 64){
        #pragma unroll
        for (int i = 0; i < 8; i++){
            float t = red[0][tid][i] + red[1][tid][i] + red[2][tid][i] + red[3][tid][i];
            lss[(long long)blockIdx.x*512 + tid*8 + i] = t;
        }
    }
}
__global__ __launch_bounds__(256) void ssq_p2(const float* __restrict__ lss, float* __restrict__ invn){
    int b = blockIdx.x; int c = blockIdx.y*256 + threadIdx.x;
    float s = 0.f;
    for (int ch = 0; ch < NCHUNK; ch++) s += lss[((long long)b*NCHUNK+ch)*512 + c];
    invn[b*512 + c] = 1.f / fmaxf(sqrtf(s), 1e-12f);
}

// ---------------- channel-attn QK partials ----------------
__global__ __launch_bounds__(256) void chanattn_qk_part(const bf16* __restrict__ qkv, const float* __restrict__ invn,
                                                        float* __restrict__ part){
    __shared__ float qs[64][36];
    __shared__ float ks[64][36];
    int bz = blockIdx.x;               // (b*8+hh)*TNS + s
    int bh = bz / TNS, s = bz % TNS;
    int b = bh >> 3, hh = bh & 7;
    int tid = threadIdx.x;
    int d = tid >> 3, e0 = (tid & 7) * 4;
    int sr = tid >> 2, sc8 = (tid & 3) * 8;
    float invq[8], invk[8];
    {
        float4 a0 = *(const float4*)(invn + b*512 + hh*32 + sc8);
        float4 a1 = *(const float4*)(invn + b*512 + hh*32 + sc8 + 4);
        float4 b0 = *(const float4*)(invn + b*512 + 256 + hh*32 + sc8);
        float4 b1 = *(const float4*)(invn + b*512 + 256 + hh*32 + sc8 + 4);
        invq[0]=a0.x; invq[1]=a0.y; invq[2]=a0.z; invq[3]=a0.w;
        invq[4]=a1.x; invq[5]=a1.y; invq[6]=a1.z; invq[7]=a1.w;
        invk[0]=b0.x; invk[1]=b0.y; invk[2]=b0.z; invk[3]=b0.w;
        invk[4]=b1.x; invk[5]=b1.y; invk[6]=b1.z; invk[7]=b1.w;
    }
    float acc[4] = {0.f,0.f,0.f,0.f};
    for (int it = 0; it < 7; it++){
        int n0 = s*448 + it*64;
        {
            long long rowb = (long long)(b*NPOS + n0 + sr) * 768;
            union { uint4 u; unsigned short us[8]; } qv, kv;
            qv.u = *(const uint4*)(qkv + rowb + hh*32 + sc8);
            kv.u = *(const uint4*)(qkv + rowb + 256 + hh*32 + sc8);
            #pragma unroll
            for (int i = 0; i < 8; i++){
                qs[sr][sc8+i] = bu(qv.us[i]) * invq[i];
                ks[sr][sc8+i] = bu(kv.us[i]) * invk[i];
            }
        }
        __syncthreads();
        #pragma unroll 4
        for (int r = 0; r < 64; r++){
            float qv = qs[r][d];
            #pragma unroll
            for (int j = 0; j < 4; j++) acc[j] += qv * ks[r][e0+j];
        }
        __syncthreads();
    }
    #pragma unroll
    for (int j = 0; j < 4; j++)
        part[(long long)bz*1024 + d*32 + e0 + j] = acc[j];
}
__global__ __launch_bounds__(256) void chanattn_qk_fin(const float* __restrict__ part, const float* __restrict__ temp,
                                                       float* __restrict__ attn){
    __shared__ float att_s[32][33];
    int bh = blockIdx.x;
    int hh = bh & 7;
    int tid = threadIdx.x;
    int d = tid >> 3, e0 = (tid & 7) * 4;
    float t = temp[hh];
    #pragma unroll
    for (int j = 0; j < 4; j++){
        float s = 0.f;
        for (int sp = 0; sp < TNS; sp++)
            s += part[((long long)bh*TNS + sp)*1024 + d*32 + e0 + j];
        att_s[d][e0+j] = s * t;
    }
    __syncthreads();
    if (tid < 32){
        float m = -1e30f;
        for (int e = 0; e < 32; e++) m = fmaxf(m, att_s[tid][e]);
        float s = 0.f;
        for (int e = 0; e < 32; e++){ float ev = expf(att_s[tid][e] - m); att_s[tid][e] = ev; s += ev; }
        float inv = 1.f / s;
        for (int e = 0; e < 32; e++) att_s[tid][e] *= inv;
    }
    __syncthreads();
    #pragma unroll
    for (int j = 0; j < 4; j++)
        attn[(long long)bh*1024 + d*32 + e0 + j] = att_s[d][e0+j];
}

// ---------------- combined weight: W_b[o][h*32+e] = sum_d capw[o][h*32+d]*attn[b][h][d][e] ----------------
__global__ __launch_bounds__(256) void wcomb_kernel(const float* __restrict__ capw, const float* __restrict__ attn,
                                                    bf16* __restrict__ Wb){
    __shared__ float at_s[8192];
    int b = blockIdx.x, og = blockIdx.y;
    int tid = threadIdx.x;
    #pragma unroll
    for (int j = 0; j < 8; j++)
        *(float4*)&at_s[tid*32 + j*4] = *(const float4*)(attn + (long long)b*8192 + tid*32 + j*4);
    __syncthreads();
    int o = og*32 + (tid & 31);
    int h = tid >> 5;
    float acc[32];
    #pragma unroll
    for (int e = 0; e < 32; e++) acc[e] = 0.f;
    for (int d = 0; d < 32; d++){
        float w = capw[(long long)o*256 + h*32 + d];
        const float* ar = &at_s[h*1024 + d*32];
        #pragma unroll
        for (int eq = 0; eq < 8; eq++){
            float4 av = *(const float4*)(ar + eq*4);
            acc[eq*4+0] += w*av.x; acc[eq*4+1] += w*av.y;
            acc[eq*4+2] += w*av.z; acc[eq*4+3] += w*av.w;
        }
    }
    bf16* dst = Wb + (long long)b*65536 + (long long)o*256 + h*32;
    #pragma unroll
    for (int eq = 0; eq < 4; eq++){
        union { uint4 u; unsigned short us[8]; } p;
        #pragma unroll
        for (int i = 0; i < 8; i++) p.us[i] = bfbits(acc[eq*8+i]);
        *(uint4*)(dst + eq*8) = p.u;
    }
}

// ---------------- orchestration ----------------
extern "C" void kernel_launch(void* const* d_in, const int* in_sizes, int n_in,
                              void* d_out, int out_size, void* d_ws, size_t ws_size,
                              hipStream_t stream){
    const float* x     = (const float*)d_in[0];
    const float* ln1g  = (const float*)d_in[3];
    const float* ln1b  = (const float*)d_in[4];
    const float* eakw  = (const float*)d_in[5];
    const float* eaqw  = (const float*)d_in[7];
    const float* eaqb  = (const float*)d_in[8];
    const float* eavw  = (const float*)d_in[9];
    const float* eavb  = (const float*)d_in[10];
    const float* earw  = (const float*)d_in[11];
    const float* earb  = (const float*)d_in[12];
    const float* ln2g  = (const float*)d_in[13];
    const float* ln2b  = (const float*)d_in[14];
    const float* m1w1  = (const float*)d_in[15];
    const float* m1b1  = (const float*)d_in[16];
    const float* m1dww = (const float*)d_in[17];
    const float* m1dwb = (const float*)d_in[18];
    const float* m1lg  = (const float*)d_in[19];
    const float* m1lb  = (const float*)d_in[20];
    const float* m1w2  = (const float*)d_in[21];
    const float* m1b2  = (const float*)d_in[22];
    const float* ln3g  = (const float*)d_in[23];
    const float* ln3b  = (const float*)d_in[24];
    const float* catemp= (const float*)d_in[25];
    const float* caqkvw= (const float*)d_in[26];
    const float* capw  = (const float*)d_in[27];
    const float* capb  = (const float*)d_in[28];
    const float* ln4g  = (const float*)d_in[29];
    const float* ln4b  = (const float*)d_in[30];
    const float* m2w1  = (const float*)d_in[31];
    const float* m2b1  = (const float*)d_in[32];
    const float* m2dww = (const float*)d_in[33];
    const float* m2dwb = (const float*)d_in[34];
    const float* m2lg  = (const float*)d_in[35];
    const float* m2lb  = (const float*)d_in[36];
    const float* m2w2  = (const float*)d_in[37];
    const float* m2b2  = (const float*)d_in[38];

    char* base = (char*)d_ws;
    auto alloc = [&](size_t nbytes){ char* p = base; base += (nbytes + 255) & ~(size_t)255; return p; };
    constexpr size_t SZ = (size_t)MTOT*CDIM*4;
    float* R  = (float*)alloc(SZ);
    float* A0 = (float*)alloc(SZ);
    float* A1 = (float*)alloc(SZ);
    float* B0 = (float*)alloc(SZ);
    float* B1 = (float*)alloc(SZ);
    bf16* A0b  = (bf16*)A0;                 // s1: ln1 out, then (after kq/v GEMMs) k-softmax bf16
    bf16* kb   = (bf16*)A0;                 //     same region, second life
    bf16* qb   = A0b + (size_t)MTOT*CDIM;   // s1: q softmax out (second half A0)
    bf16* vb   = (bf16*)A1;                 // s1: v bf16
    float* KQ  = B0;                        // s1: fused k|q f32 [MTOT,512] spans B0..B1
    bf16* attb = (bf16*)B0;                 // s1: att out (KQ dead)
    bf16* l2b  = (bf16*)A1;                 // s2: ln2 out
    bf16* F    = (bf16*)B0;                 // s2/s4: fc1 out
    bf16* G    = (bf16*)A0;                 // s2/s4: dwconv out
    bf16* l3b  = (bf16*)B0;                 // s3: ln3 out
    bf16* Qb   = (bf16*)A0;                 // s3: qkv
    bf16* l4b  = (bf16*)A0;                 // s4: ln4 out
    bf16* ctxb = (bf16*)alloc((size_t)BATCH*CDIM*CDIM*2);
    float* lmax = (float*)alloc((size_t)BATCH*NCHUNK*CDIM*4);
    float* lsum = (float*)alloc((size_t)BATCH*NCHUNK*CDIM*4);
    float* gmax = (float*)alloc((size_t)BATCH*CDIM*4);
    float* ginv = (float*)alloc((size_t)BATCH*CDIM*4);
    float* lss  = (float*)alloc((size_t)BATCH*NCHUNK*512*4);
    float* invn = (float*)alloc((size_t)BATCH*512*4);
    float* attnb= (float*)alloc((size_t)BATCH*8*32*32*4);
    float* ptn  = (float*)alloc((size_t)BATCH*TNS*CDIM*CDIM*4);
    float* pqk  = (float*)alloc((size_t)BATCH*8*TNS*1024*4);
    bf16* wbuf  = (bf16*)alloc((size_t)1572864*2);
    float* wT1  = (float*)alloc((size_t)9216*4);
    float* wT2  = (float*)alloc((size_t)9216*4);
    bf16* Wcb   = (bf16*)alloc((size_t)BATCH*CDIM*CDIM*2);

    bf16* kqw_b    = wbuf;                  // [512,256]: rows 0-255 k, 256-511 q
    bf16* eavw_b   = wbuf + 131072;
    bf16* earw_b   = wbuf + 196608;
    bf16* m1w1_b   = wbuf + 262144;
    bf16* m1w2_b   = wbuf + 524288;
    bf16* caqkvw_b = wbuf + 786432;
    bf16* m2w1_b   = wbuf + 1048576;
    bf16* m2w2_b   = wbuf + 1310720;

    dim3 blk(256);
    constexpr int MB = MTOT/128;            // 196
    long long sA1 = (long long)NPOS*CDIM;
    long long sB1 = (long long)CDIM*CDIM;

    // ---- weight prep ----
    {
        WArgs wa;
        const float* srcs[10] = {eakw, eaqw, eavw, earw, m1w1, m1w2, caqkvw, m2w1, m2w2, m2w2};
        bf16* dsts[10] = {kqw_b, kqw_b + 65536, eavw_b, earw_b, m1w1_b, m1w2_b, caqkvw_b, m2w1_b, m2w2_b, m2w2_b};
        int ns[10] = {65536, 65536, 65536, 65536, 262144, 262144, 196608, 262144, 262144, 0};
        for (int i = 0; i < 10; i++){ wa.src[i]=srcs[i]; wa.dst[i]=dsts[i]; wa.n[i]=ns[i]; }
        wcvt_kernel<<<dim3(128,10), blk, 0, stream>>>(wa);
        wtrans_kernel<<<dim3(36,2), blk, 0, stream>>>(m1dww, m2dww, wT1, wT2);
    }

    // ---- Stage 1: EfficientAttention ----
    ln4_kernel<bf16><<<MTOT/4, blk, 0, stream>>>(x, ln1g, ln1b, A0b);
    mfma_gemm<float><<<dim3(4,MB,1), blk, 0, stream>>>(A0b, kqw_b, nullptr, nullptr, KQ, MTOT, 512, 256, 256, 0,0,0,0); // k|q (k bias dropped: softmax-N invariant; q bias added in rowsm)
    mfma_gemm<bf16><<<dim3(2,MB,1), blk, 0, stream>>>(A0b, eavw_b, eavb, nullptr, vb, MTOT, 256, 256, 256, 0,0,0,0);
    rowsm4b_kernel<<<MTOT/4, blk, 0, stream>>>(KQ, eaqb, qb);
    colsm_p1<<<BATCH*NCHUNK, blk, 0, stream>>>(KQ, lmax, lsum);
    colsm_p2<<<BATCH, blk, 0, stream>>>(lmax, lsum, gmax, ginv);
    colsm_p3<<<MTOT, blk, 0, stream>>>(KQ, kb, gmax, ginv);             // kb overwrites dead ln1-out region
    gemm_tn_mfma<<<dim3(2,2,BATCH*TNS), blk, 0, stream>>>(vb, kb, ptn);
    ctx_reduce<<<(BATCH*65536)/256, blk, 0, stream>>>(ptn, ctxb);
    mfma_gemm<bf16><<<dim3(2,25,BATCH), blk, 0, stream>>>(qb, ctxb, nullptr, nullptr, attb,
            NPOS, 256, 256, 256, sA1, sB1, sA1, 0);
    mfma_gemm<float><<<dim3(2,MB,1), blk, 0, stream>>>(attb, earw_b, earb, x, R, MTOT, 256, 256, 256, 0,0,0,0);

    // ---- Stage 2: MixFFN #1 ----
    ln4_kernel<bf16><<<MTOT/4, blk, 0, stream>>>(R, ln2g, ln2b, l2b);
    mfma_gemm<bf16><<<dim3(8,MB,1), blk, 0, stream>>>(l2b, m1w1_b, m1b1, nullptr, F, MTOT, 1024, 256, 256, 0,0,0,0);
    dwconv_ln_gelu_kernel<<<BATCH*HH*14, blk, 0, stream>>>(F, wT1, m1dwb, m1lg, m1lb, G);
    mfma_gemm<float><<<dim3(2,MB,1), blk, 0, stream>>>(G, m1w2_b, m1b2, R, R, MTOT, 256, 1024, 1024, 0,0,0,0);

    // ---- Stage 3: ChannelAttention ----
    ln4_kernel<bf16><<<MTOT/4, blk, 0, stream>>>(R, ln3g, ln3b, l3b);
    mfma_gemm<bf16><<<dim3(6,MB,1), blk, 0, stream>>>(l3b, caqkvw_b, nullptr, nullptr, Qb, MTOT, 768, 256, 256, 0,0,0,0);
    ssq_p1<<<BATCH*NCHUNK, blk, 0, stream>>>(Qb, lss);
    ssq_p2<<<dim3(BATCH,2), blk, 0, stream>>>(lss, invn);
    chanattn_qk_part<<<BATCH*8*TNS, blk, 0, stream>>>(Qb, invn, pqk);
    chanattn_qk_fin<<<BATCH*8, blk, 0, stream>>>(pqk, catemp, attnb);
    wcomb_kernel<<<dim3(BATCH,8), blk, 0, stream>>>(capw, attnb, Wcb);
    mfma_gemm<float><<<dim3(2,25,BATCH), blk, 0, stream>>>(Qb + 512, Wcb, capb, R, R,
            NPOS, 256, 256, 768, (long long)NPOS*768, sB1, sA1, sA1);

    // ---- Stage 4: MixFFN #2 ----
    ln4_kernel<bf16><<<MTOT/4, blk, 0, stream>>>(R, ln4g, ln4b, l4b);
    mfma_gemm<bf16><<<dim3(8,MB,1), blk, 0, stream>>>(l4b, m2w1_b, m2b1, nullptr, F, MTOT, 1024, 256, 256, 0,0,0,0);
    dwconv_ln_gelu_kernel<<<BATCH*HH*14, blk, 0, stream>>>(F, wT2, m2dwb, m2lg, m2lb, G);
    mfma_gemm<float><<<dim3(2,MB,1), blk, 0, stream>>>(G, m2w2_b, m2b2, R, (float*)d_out, MTOT, 256, 1024, 1024, 0,0,0,0);
}

// Round 2
// 600.608 us; speedup vs baseline: 1.3370x; 1.1998x over previous
//
#include <hip/hip_runtime.h>
#include <hip/hip_bf16.h>

typedef __hip_bfloat16 bf16;
typedef __attribute__((ext_vector_type(8))) short short8;
typedef __attribute__((ext_vector_type(4))) float floatx4;

#define DI __device__ __forceinline__

DI float ldf(const float* p, long long i){ return p[i]; }
DI float ldf(const bf16* p, long long i){ return __bfloat162float(p[i]); }

DI unsigned short bfbits(float f){
    bf16 h = __float2bfloat16(f);
    return *reinterpret_cast<unsigned short*>(&h);
}
DI float bu(unsigned short u){
    union { unsigned int i; float f; } x; x.i = ((unsigned int)u) << 16; return x.f;
}

// exact-GELU via A&S 7.1.26 erf approx: |erf err| <= 1.5e-7 (<< bf16 noise).
// ~16 VALU insts vs ~90 for libm erff (which was ~60% of dwconv's VALU).
DI float gelu_exact(float x){
    float z = fabsf(x) * 0.70710678118654752f;          // |x|/sqrt(2)
    float t = __builtin_amdgcn_rcpf(fmaf(0.3275911f, z, 1.f));
    float p = t * fmaf(t, fmaf(t, fmaf(t, fmaf(t, 1.061405429f, -1.453152027f),
                    1.421413741f), -0.284496736f), 0.254829592f);
    float e = __expf(-z*z);
    float er = fmaf(-p, e, 1.f);                        // erf(z), z>=0
    er = copysignf(er, x);
    return 0.5f * x * (1.f + er);
}

// direct global->LDS 16B load (m97 trick). lds dest: wave-uniform base + lane*16.
DI void gload16(const void* g, void* l){
    __builtin_amdgcn_global_load_lds(
        (const __attribute__((address_space(1))) unsigned int*)g,
        (__attribute__((address_space(3))) unsigned int*)l,
        16, 0, 0);
}

static constexpr int BATCH = 8;
static constexpr int HH = 56, WW = 56;
static constexpr int NPOS = HH * WW;        // 3136
static constexpr int CDIM = 256;
static constexpr int HIDD = 1024;
static constexpr int MTOT = BATCH * NPOS;   // 25088
static constexpr int NCHUNK = 49;           // 3136 / 64
static constexpr int LP = 40;               // LDS pitch for tn gemm (shorts)
static constexpr int TNS = 7;               // split-K for ctx TN gemm

// ---------------- weight f32 -> bf16 pre-convert ----------------
struct WArgs {
    const float* src[10];
    bf16* dst[10];
    int n[10];
};
__global__ __launch_bounds__(256) void wcvt_kernel(WArgs a){
    int wid = blockIdx.y;
    int i = (blockIdx.x*256 + threadIdx.x) * 8;
    if (i >= a.n[wid]) return;
    const float* s = a.src[wid] + i;
    float4 f0 = *(const float4*)(s);
    float4 f1 = *(const float4*)(s + 4);
    union { uint4 u; unsigned short us[8]; } p;
    p.us[0]=bfbits(f0.x); p.us[1]=bfbits(f0.y); p.us[2]=bfbits(f0.z); p.us[3]=bfbits(f0.w);
    p.us[4]=bfbits(f1.x); p.us[5]=bfbits(f1.y); p.us[6]=bfbits(f1.z); p.us[7]=bfbits(f1.w);
    *(uint4*)(a.dst[wid] + i) = p.u;
}

__global__ __launch_bounds__(256) void wtrans_kernel(const float* __restrict__ w1, const float* __restrict__ w2,
                                                     float* __restrict__ t1, float* __restrict__ t2){
    int i = blockIdx.x*256 + threadIdx.x;   // 0..9215
    const float* w = blockIdx.y ? w2 : w1;
    float* t = blockIdx.y ? t2 : t1;
    int tap = i >> 10, c = i & 1023;
    t[i] = w[c*9 + tap];
}

// ---------------- MFMA bf16 GEMM (NT), global_load_lds staging ----------------
// LDS layout: 16B chunk c holds tile[row=c>>2][col16=(c&3)^(row&3)] (XOR swizzle, no pad).
// XCD-bijective tile swizzle: each XCD owns a contiguous chunk of tiles, n-fastest
//   -> A-tile refetched by blocks on the SAME XCD (L2 hit) instead of 8 different L2s.
// Epilogue (both f32 and bf16 out): per-wave transpose through LDS (stride-68 scratch,
// conflict-free), then 128B-contiguous wide stores + vectorized addend reads.
template<typename TC>
__global__ __launch_bounds__(256) void mfma_gemm(
    const bf16* __restrict__ A, const bf16* __restrict__ Bw,
    const float* __restrict__ bias, const float* __restrict__ addend,
    TC* __restrict__ C, int M, int N, int K, int lda,
    long long strA, long long strB, long long strC, long long strAdd)
{
    __shared__ __align__(16) float smemf[4608];   // 18 KB: K-loop tiles (16 KB), then epilogue scratch (17.4 KB)
    short* As = (short*)smemf;                    // bytes [0, 8192)
    short* Bs = (short*)smemf + 4096;             // bytes [8192, 16384)
    int tid = threadIdx.x;
    int bz = blockIdx.z;
    A  += (long long)bz * strA;
    Bw += (long long)bz * strB;
    C  += (long long)bz * strC;
    if (addend) addend += (long long)bz * strAdd;

    // --- bijective XCD chunk swizzle (m204) over the (x,y) tile space ---
    int gx = gridDim.x;
    int nwg = gx * gridDim.y;
    int bidl = blockIdx.y * gx + blockIdx.x;
    int qq = nwg >> 3, rr = nwg & 7;
    int xcd = bidl & 7, ixx = bidl >> 3;
    int tile = (xcd < rr) ? (xcd*(qq+1) + ixx) : (rr*(qq+1) + (xcd-rr)*qq + ixx);
    int n0 = (tile % gx) * 128, m0 = (tile / gx) * 128;

    int w = tid >> 6, lane = tid & 63, lm = lane & 15, quad = lane >> 4;
    int mw = (w >> 1) * 64, nw = (w & 1) * 64;

    // staging: wave w issues instructions t=2w,2w+1; lane covers chunk t*64+lane.
    int c0 = w*128 + lane, c1 = c0 + 64;
    int ar0 = c0 >> 2, ac0 = (c0 & 3) ^ (ar0 & 3);
    int ar1 = c1 >> 2, ac1 = (c1 & 3) ^ (ar1 & 3);
    int rgA0 = m0 + ar0; if (rgA0 > M-1) rgA0 = M-1;
    int rgA1 = m0 + ar1; if (rgA1 > M-1) rgA1 = M-1;
    short* aL0 = &As[(2*w+0)*512];
    short* aL1 = &As[(2*w+1)*512];
    short* bL0 = &Bs[(2*w+0)*512];
    short* bL1 = &Bs[(2*w+1)*512];
    const bf16* Arow0 = A + (long long)rgA0*lda + ac0*8;
    const bf16* Arow1 = A + (long long)rgA1*lda + ac1*8;
    const bf16* Brow0 = Bw + (long long)(n0+ar0)*K + ac0*8;
    const bf16* Brow1 = Bw + (long long)(n0+ar1)*K + ac1*8;

    floatx4 z = {0.f, 0.f, 0.f, 0.f};
    floatx4 acc[4][4];
    #pragma unroll
    for (int mi = 0; mi < 4; mi++)
        #pragma unroll
        for (int ni = 0; ni < 4; ni++) acc[mi][ni] = z;

    int sq = quad ^ (lm & 3);   // read-side swizzle (row&3 == lm&3 for all fragment rows)

    for (int k0 = 0; k0 < K; k0 += 32){
        gload16(Arow0 + k0, aL0);
        gload16(Arow1 + k0, aL1);
        gload16(Brow0 + k0, bL0);
        gload16(Brow1 + k0, bL1);
        __syncthreads();
        short8 af[4], bfr[4];
        #pragma unroll
        for (int mi = 0; mi < 4; mi++)
            af[mi] = *(const short8*)&As[(((mw + mi*16 + lm)<<2) + sq)*8];
        #pragma unroll
        for (int ni = 0; ni < 4; ni++)
            bfr[ni] = *(const short8*)&Bs[(((nw + ni*16 + lm)<<2) + sq)*8];
        #pragma unroll
        for (int mi = 0; mi < 4; mi++)
            #pragma unroll
            for (int ni = 0; ni < 4; ni++)
                acc[mi][ni] = __builtin_amdgcn_mfma_f32_16x16x32_bf16(af[mi], bfr[ni], acc[mi][ni], 0, 0, 0);
        __syncthreads();
    }

    // --- epilogue: per-wave transpose through LDS, wide contiguous stores ---
    // After the final __syncthreads() no wave touches As/Bs again; each wave uses
    // its private scratch strip (stride 68 f32 => balanced banks). A wave's DS ops
    // complete in order, so no barrier is needed between write and read-back.
    float bvv[4];
    #pragma unroll
    for (int ni = 0; ni < 4; ni++)
        bvv[ni] = bias ? bias[n0 + nw + ni*16 + lm] : 0.f;
    float* esc = smemf + w*1088;            // 16 rows x 68 floats per wave
    int rl0 = lane >> 3;                    // 0..7
    #pragma unroll
    for (int mi = 0; mi < 4; mi++){
        #pragma unroll
        for (int ni = 0; ni < 4; ni++)
            #pragma unroll
            for (int r = 0; r < 4; r++)
                esc[(quad*4 + r)*68 + ni*16 + lm] = acc[mi][ni][r] + bvv[ni];
        #pragma unroll
        for (int p = 0; p < 2; p++){
            int rloc = p*8 + rl0;
            int rg = m0 + mw + mi*16 + rloc;
            if (rg < M){
                if constexpr (sizeof(TC) == 2){
                    int cl = (lane & 7) * 8;        // 8 lanes x 8 bf16 = 128B/row
                    float4 u0 = *(const float4*)&esc[rloc*68 + cl];
                    float4 u1 = *(const float4*)&esc[rloc*68 + cl + 4];
                    if (addend){
                        long long ai = (long long)rg*N + (n0 + nw + cl);
                        float4 a0 = *(const float4*)(addend + ai);
                        float4 a1 = *(const float4*)(addend + ai + 4);
                        u0.x+=a0.x; u0.y+=a0.y; u0.z+=a0.z; u0.w+=a0.w;
                        u1.x+=a1.x; u1.y+=a1.y; u1.z+=a1.z; u1.w+=a1.w;
                    }
                    union { uint4 u; unsigned short us[8]; } pk;
                    pk.us[0]=bfbits(u0.x); pk.us[1]=bfbits(u0.y); pk.us[2]=bfbits(u0.z); pk.us[3]=bfbits(u0.w);
                    pk.us[4]=bfbits(u1.x); pk.us[5]=bfbits(u1.y); pk.us[6]=bfbits(u1.z); pk.us[7]=bfbits(u1.w);
                    *(uint4*)(C + (long long)rg*N + (n0 + nw + cl)) = pk.u;
                } else {
                    int cl4 = (lane & 7) * 4;       // 8 lanes x 4 f32 = 128B per half-row
                    long long co = (long long)rg*N + (n0 + nw);
                    float4 u0 = *(const float4*)&esc[rloc*68 + cl4];
                    float4 u1 = *(const float4*)&esc[rloc*68 + 32 + cl4];
                    if (addend){
                        float4 a0 = *(const float4*)(addend + co + cl4);
                        float4 a1 = *(const float4*)(addend + co + 32 + cl4);
                        u0.x+=a0.x; u0.y+=a0.y; u0.z+=a0.z; u0.w+=a0.w;
                        u1.x+=a1.x; u1.y+=a1.y; u1.z+=a1.z; u1.w+=a1.w;
                    }
                    *(float4*)(C + co + cl4) = u0;
                    *(float4*)(C + co + 32 + cl4) = u1;
                }
            }
        }
    }
}

// ---------------- MFMA bf16 TN GEMM: part[s][vc][kc] = sum_{n in split s} V[n,vc]*K[n,kc] ----------------
__global__ __launch_bounds__(256) void gemm_tn_mfma(const bf16* __restrict__ V, const bf16* __restrict__ Kb,
                                                    float* __restrict__ part){
    __shared__ short As[128*LP];
    __shared__ short Bs[128*LP];
    int tid = threadIdx.x;
    int bz = blockIdx.z;           // b*TNS + s
    int b = bz / TNS, s = bz % TNS;
    const bf16* Vb = V  + (long long)b*NPOS*CDIM;
    const bf16* Kc = Kb + (long long)b*NPOS*CDIM;
    int m0 = blockIdx.y * 128, n0 = blockIdx.x * 128;
    int w = tid >> 6, lane = tid & 63, lm = lane & 15, quad = lane >> 4;
    int mw = (w >> 1) * 64, nw = (w & 1) * 64;

    floatx4 z = {0.f,0.f,0.f,0.f};
    floatx4 acc[4][4];
    #pragma unroll
    for (int mi = 0; mi < 4; mi++)
        #pragma unroll
        for (int ni = 0; ni < 4; ni++) acc[mi][ni] = z;

    int r = tid & 31, cgrp = tid >> 5;

    for (int step = 0; step < 448/32; step++){
        int nb = s*448 + step*32;
        #pragma unroll
        for (int cc = 0; cc < 2; cc++){
            int ch = cgrp*8 + cc*64;
            short8 va = *(const short8*)(Vb + (long long)(nb + r)*CDIM + m0 + ch);
            short8 ka = *(const short8*)(Kc + (long long)(nb + r)*CDIM + n0 + ch);
            #pragma unroll
            for (int i = 0; i < 8; i++){
                As[(ch+i)*LP + r] = va[i];
                Bs[(ch+i)*LP + r] = ka[i];
            }
        }
        __syncthreads();
        short8 af[4], bfr[4];
        #pragma unroll
        for (int mi = 0; mi < 4; mi++)
            af[mi] = *(const short8*)&As[(mw + mi*16 + lm)*LP + quad*8];
        #pragma unroll
        for (int ni = 0; ni < 4; ni++)
            bfr[ni] = *(const short8*)&Bs[(nw + ni*16 + lm)*LP + quad*8];
        #pragma unroll
        for (int mi = 0; mi < 4; mi++)
            #pragma unroll
            for (int ni = 0; ni < 4; ni++)
                acc[mi][ni] = __builtin_amdgcn_mfma_f32_16x16x32_bf16(af[mi], bfr[ni], acc[mi][ni], 0, 0, 0);
        __syncthreads();
    }

    float* pb = part + (long long)bz * CDIM * CDIM;
    #pragma unroll
    for (int ni = 0; ni < 4; ni++){
        int cg = n0 + nw + ni*16 + lm;
        #pragma unroll
        for (int mi = 0; mi < 4; mi++){
            #pragma unroll
            for (int rr = 0; rr < 4; rr++){
                int rg = m0 + mw + mi*16 + quad*4 + rr;
                pb[(long long)rg*CDIM + cg] = acc[mi][ni][rr];
            }
        }
    }
}

__global__ __launch_bounds__(256) void ctx_reduce(const float* __restrict__ part, bf16* __restrict__ ctxb){
    long long idx = (long long)blockIdx.x*256 + threadIdx.x;
    int b = (int)(idx >> 16);
    int rem = (int)(idx & 65535);
    float s = 0.f;
    #pragma unroll
    for (int sp = 0; sp < TNS; sp++)
        s += part[((long long)(b*TNS+sp) << 16) + rem];
    ctxb[idx] = __float2bfloat16(s);
}

// ---------------- LayerNorm: one wave per row ----------------
DI void st4o(float* p, long long i, float a, float b, float c, float d){
    float4 v = make_float4(a,b,c,d); *(float4*)(p + i) = v;
}
DI void st4o(bf16* p, long long i, float a, float b, float c, float d){
    union { unsigned long long u; unsigned short us[4]; } pk;
    pk.us[0]=bfbits(a); pk.us[1]=bfbits(b); pk.us[2]=bfbits(c); pk.us[3]=bfbits(d);
    *(unsigned long long*)(p + i) = pk.u;
}
template<typename TOUT>
__global__ __launch_bounds__(256) void ln4_kernel(const float* __restrict__ x, const float* __restrict__ g,
                                                  const float* __restrict__ b, TOUT* __restrict__ y){
    int wv = threadIdx.x >> 6, lane = threadIdx.x & 63;
    long long row = (long long)blockIdx.x*4 + wv;
    float4 v = *(const float4*)(x + row*256 + lane*4);
    float s  = v.x + v.y + v.z + v.w;
    float ss = v.x*v.x + v.y*v.y + v.z*v.z + v.w*v.w;
    #pragma unroll
    for (int off = 32; off > 0; off >>= 1){
        s  += __shfl_down(s,  off);
        ss += __shfl_down(ss, off);
    }
    s = __shfl(s, 0); ss = __shfl(ss, 0);
    float mean = s * (1.f/256.f);
    float var  = ss * (1.f/256.f) - mean*mean;
    float inv  = rsqrtf(var + 1e-5f);
    float4 gv = *(const float4*)(g + lane*4);
    float4 bv = *(const float4*)(b + lane*4);
    st4o(y, row*256 + lane*4,
         (v.x-mean)*inv*gv.x + bv.x, (v.y-mean)*inv*gv.y + bv.y,
         (v.z-mean)*inv*gv.z + bv.z, (v.w-mean)*inv*gv.w + bv.w);
}

// ---------------- column softmax over N (k = cols 0..255 of KQ[.,512]) ----------------
// NOTE: k bias omitted upstream — softmax over N is invariant to per-column constants.
__global__ __launch_bounds__(256) void colsm_p1(const float* __restrict__ x, float* __restrict__ lmax, float* __restrict__ lsum){
    int b = blockIdx.x / NCHUNK, ch = blockIdx.x % NCHUNK;
    int c = threadIdx.x;
    const float* base = x + ((long long)b*NPOS + ch*64)*512 + c;
    float m = -1e30f;
    for (int r = 0; r < 64; r++) m = fmaxf(m, base[(long long)r*512]);
    float s = 0.f;
    for (int r = 0; r < 64; r++) s += expf(base[(long long)r*512] - m);
    lmax[(long long)blockIdx.x*CDIM + c] = m;
    lsum[(long long)blockIdx.x*CDIM + c] = s;
}
__global__ __launch_bounds__(256) void colsm_p2(const float* __restrict__ lmax, const float* __restrict__ lsum,
                                                float* __restrict__ gmax, float* __restrict__ ginv){
    int b = blockIdx.x; int c = threadIdx.x;
    float g = -1e30f;
    for (int ch = 0; ch < NCHUNK; ch++) g = fmaxf(g, lmax[((long long)b*NCHUNK+ch)*CDIM + c]);
    float s = 0.f;
    for (int ch = 0; ch < NCHUNK; ch++)
        s += lsum[((long long)b*NCHUNK+ch)*CDIM + c] * expf(lmax[((long long)b*NCHUNK+ch)*CDIM + c] - g);
    gmax[b*CDIM + c] = g; ginv[b*CDIM + c] = 1.f / s;
}
__global__ __launch_bounds__(256) void colsm_p3(const float* __restrict__ x, bf16* __restrict__ y,
                                                const float* __restrict__ gmax, const float* __restrict__ ginv){
    long long idx = (long long)blockIdx.x*256 + threadIdx.x;
    int c = (int)(idx & 255);
    long long row = idx >> 8;
    int b = (int)(row / NPOS);
    y[idx] = __float2bfloat16(expf(x[row*512 + c] - gmax[b*CDIM + c]) * ginv[b*CDIM + c]);
}

// ---------------- row softmax (q = cols 256..511 of KQ) + bias, wave-per-row ----------------
__global__ __launch_bounds__(256) void rowsm4b_kernel(const float* __restrict__ x, const float* __restrict__ bias,
                                                      bf16* __restrict__ y){
    int wv = threadIdx.x >> 6, lane = threadIdx.x & 63;
    long long row = (long long)blockIdx.x*4 + wv;
    float4 v = *(const float4*)(x + row*512 + 256 + lane*4);
    float4 bb = *(const float4*)(bias + lane*4);
    v.x += bb.x; v.y += bb.y; v.z += bb.z; v.w += bb.w;
    float m = fmaxf(fmaxf(v.x, v.y), fmaxf(v.z, v.w));
    #pragma unroll
    for (int off = 32; off > 0; off >>= 1) m = fmaxf(m, __shfl_down(m, off));
    m = __shfl(m, 0);
    float e0 = expf(v.x - m), e1 = expf(v.y - m), e2 = expf(v.z - m), e3 = expf(v.w - m);
    float s = e0 + e1 + e2 + e3;
    #pragma unroll
    for (int off = 32; off > 0; off >>= 1) s += __shfl_down(s, off);
    s = __shfl(s, 0);
    float inv = 1.f / s;
    st4o(y, row*256 + lane*4, e0*inv, e1*inv, e2*inv, e3*inv);
}

// ---------------- fused dwconv3x3 + skip + LN + GELU, LDS-tiled, XCD-swizzled ----------------
__global__ __launch_bounds__(256) void dwconv_ln_gelu_kernel(const bf16* __restrict__ f, const float* __restrict__ wT,
        const float* __restrict__ db, const float* __restrict__ lg, const float* __restrict__ lb, bf16* __restrict__ out){
    __shared__ short Ls[18*1024];
    __shared__ float r1[2][2][128], r2[2][2][128];
    int tid = threadIdx.x;
    // XCD swizzle: consecutive blockIdx -> different batch images (round-robin XCD => each
    // XCD works one image => halo rows hit its private L2).
    int b = blockIdx.x & 7;
    int rem = blockIdx.x >> 3;              // 0..783
    int h = rem / 14, w0 = (rem % 14) * 4;
    const bf16* fb = f + (long long)b * NPOS * HIDD;

    #pragma unroll
    for (int j = 0; j < 9; j++){
        int idx = j*256 + tid;
        int rc = idx >> 7, chunk = idx & 127;
        int row = rc / 6, col = rc % 6;
        int hy = h - 1 + row, wx = w0 - 1 + col;
        uint4 v = {0,0,0,0};
        if (hy >= 0 && hy < HH && wx >= 0 && wx < WW)
            v = *(const uint4*)(fb + (long long)(hy*WW + wx)*HIDD + chunk*8);
        *(uint4*)&Ls[rc*1024 + chunk*8] = v;
    }
    __syncthreads();

    int ph = tid >> 7, ct = tid & 127;
    int c0 = ct * 8;
    float sv[2][8];
    {
        float4 d0 = *(const float4*)(db + c0);
        float4 d1 = *(const float4*)(db + c0 + 4);
        #pragma unroll
        for (int pp = 0; pp < 2; pp++){
            sv[pp][0]=d0.x; sv[pp][1]=d0.y; sv[pp][2]=d0.z; sv[pp][3]=d0.w;
            sv[pp][4]=d1.x; sv[pp][5]=d1.y; sv[pp][6]=d1.z; sv[pp][7]=d1.w;
        }
    }
    #pragma unroll
    for (int tap = 0; tap < 9; tap++){
        int ky = tap / 3, kx = tap % 3;
        float4 w0v = *(const float4*)(wT + tap*1024 + c0);
        float4 w1v = *(const float4*)(wT + tap*1024 + c0 + 4);
        float wv[8] = {w0v.x,w0v.y,w0v.z,w0v.w,w1v.x,w1v.y,w1v.z,w1v.w};
        #pragma unroll
        for (int pp = 0; pp < 2; pp++){
            int pos_local = 2*ph + pp;
            short8 val = *(const short8*)&Ls[(ky*6 + pos_local + kx)*1024 + c0];
            #pragma unroll
            for (int i = 0; i < 8; i++){
                float fv = bu((unsigned short)val[i]);
                sv[pp][i] += fv * wv[i];
                if (tap == 4) sv[pp][i] += fv;
            }
        }
    }
    #pragma unroll
    for (int pp = 0; pp < 2; pp++){
        float s = 0.f, ss = 0.f;
        #pragma unroll
        for (int i = 0; i < 8; i++){ s += sv[pp][i]; ss += sv[pp][i]*sv[pp][i]; }
        r1[ph][pp][ct] = s; r2[ph][pp][ct] = ss;
    }
    __syncthreads();
    for (int st = 64; st > 0; st >>= 1){
        if (ct < st){
            #pragma unroll
            for (int pp = 0; pp < 2; pp++){
                r1[ph][pp][ct] += r1[ph][pp][ct+st];
                r2[ph][pp][ct] += r2[ph][pp][ct+st];
            }
        }
        __syncthreads();
    }
    float4 g0 = *(const float4*)(lg + c0), g1 = *(const float4*)(lg + c0 + 4);
    float4 b0 = *(const float4*)(lb + c0), b1 = *(const float4*)(lb + c0 + 4);
    float gg[8] = {g0.x,g0.y,g0.z,g0.w,g1.x,g1.y,g1.z,g1.w};
    float bb[8] = {b0.x,b0.y,b0.z,b0.w,b1.x,b1.y,b1.z,b1.w};
    #pragma unroll
    for (int pp = 0; pp < 2; pp++){
        int pos_local = 2*ph + pp;
        long long n = (long long)b*NPOS + h*WW + (w0 + pos_local);
        float mean = r1[ph][pp][0] * (1.f/HIDD);
        float var  = r2[ph][pp][0] * (1.f/HIDD) - mean*mean;
        float inv  = rsqrtf(var + 1e-5f);
        union { uint4 u; unsigned short us[8]; } ov;
        #pragma unroll
        for (int i = 0; i < 8; i++){
            float o = (sv[pp][i]-mean)*inv*gg[i] + bb[i];
            ov.us[i] = bfbits(gelu_exact(o));
        }
        *(uint4*)(out + n*HIDD + c0) = ov.u;
    }
}

// ---------------- channel-attn: per-channel sum-sq over N ----------------
__global__ __launch_bounds__(256) void ssq_p1(const bf16* __restrict__ qkv, float* __restrict__ lss){
    __shared__ float red[4][64][8];
    int b = blockIdx.x / NCHUNK, ch = blockIdx.x % NCHUNK;
    int tid = threadIdx.x;
    int col = (tid & 63) * 8;
    int rg = tid >> 6;
    float s[8] = {0,0,0,0,0,0,0,0};
    for (int r = rg*16; r < rg*16 + 16; r++){
        long long row = (long long)(b*NPOS + ch*64 + r);
        union { uint4 u; unsigned short us[8]; } v;
        v.u = *(const uint4*)(qkv + row*768 + col);
        #pragma unroll
        for (int i = 0; i < 8; i++){ float f = bu(v.us[i]); s[i] += f*f; }
    }
    #pragma unroll
    for (int i = 0; i < 8; i++) red[rg][tid & 63][i] = s[i];
    __syncthreads();
    if (tid < 64){
        #pragma unroll
        for (int i = 0; i < 8; i++){
            float t = red[0][tid][i] + red[1][tid][i] + red[2][tid][i] + red[3][tid][i];
            lss[(long long)blockIdx.x*512 + tid*8 + i] = t;
        }
    }
}
__global__ __launch_bounds__(256) void ssq_p2(const float* __restrict__ lss, float* __restrict__ invn){
    int b = blockIdx.x; int c = blockIdx.y*256 + threadIdx.x;
    float s = 0.f;
    for (int ch = 0; ch < NCHUNK; ch++) s += lss[((long long)b*NCHUNK+ch)*512 + c];
    invn[b*512 + c] = 1.f / fmaxf(sqrtf(s), 1e-12f);
}

// ---------------- channel-attn QK partials ----------------
__global__ __launch_bounds__(256) void chanattn_qk_part(const bf16* __restrict__ qkv, const float* __restrict__ invn,
                                                        float* __restrict__ part){
    __shared__ float qs[64][36];
    __shared__ float ks[64][36];
    int bz = blockIdx.x;               // (b*8+hh)*TNS + s
    int bh = bz / TNS, s = bz % TNS;
    int b = bh >> 3, hh = bh & 7;
    int tid = threadIdx.x;
    int d = tid >> 3, e0 = (tid & 7) * 4;
    int sr = tid >> 2, sc8 = (tid & 3) * 8;
    float invq[8], invk[8];
    {
        float4 a0 = *(const float4*)(invn + b*512 + hh*32 + sc8);
        float4 a1 = *(const float4*)(invn + b*512 + hh*32 + sc8 + 4);
        float4 b0 = *(const float4*)(invn + b*512 + 256 + hh*32 + sc8);
        float4 b1 = *(const float4*)(invn + b*512 + 256 + hh*32 + sc8 + 4);
        invq[0]=a0.x; invq[1]=a0.y; invq[2]=a0.z; invq[3]=a0.w;
        invq[4]=a1.x; invq[5]=a1.y; invq[6]=a1.z; invq[7]=a1.w;
        invk[0]=b0.x; invk[1]=b0.y; invk[2]=b0.z; invk[3]=b0.w;
        invk[4]=b1.x; invk[5]=b1.y; invk[6]=b1.z; invk[7]=b1.w;
    }
    float acc[4] = {0.f,0.f,0.f,0.f};
    for (int it = 0; it < 7; it++){
        int n0 = s*448 + it*64;
        {
            long long rowb = (long long)(b*NPOS + n0 + sr) * 768;
            union { uint4 u; unsigned short us[8]; } qv, kv;
            qv.u = *(const uint4*)(qkv + rowb + hh*32 + sc8);
            kv.u = *(const uint4*)(qkv + rowb + 256 + hh*32 + sc8);
            #pragma unroll
            for (int i = 0; i < 8; i++){
                qs[sr][sc8+i] = bu(qv.us[i]) * invq[i];
                ks[sr][sc8+i] = bu(kv.us[i]) * invk[i];
            }
        }
        __syncthreads();
        #pragma unroll 4
        for (int r = 0; r < 64; r++){
            float qv = qs[r][d];
            #pragma unroll
            for (int j = 0; j < 4; j++) acc[j] += qv * ks[r][e0+j];
        }
        __syncthreads();
    }
    #pragma unroll
    for (int j = 0; j < 4; j++)
        part[(long long)bz*1024 + d*32 + e0 + j] = acc[j];
}
__global__ __launch_bounds__(256) void chanattn_qk_fin(const float* __restrict__ part, const float* __restrict__ temp,
                                                       float* __restrict__ attn){
    __shared__ float att_s[32][33];
    int bh = blockIdx.x;
    int hh = bh & 7;
    int tid = threadIdx.x;
    int d = tid >> 3, e0 = (tid & 7) * 4;
    float t = temp[hh];
    #pragma unroll
    for (int j = 0; j < 4; j++){
        float s = 0.f;
        for (int sp = 0; sp < TNS; sp++)
            s += part[((long long)bh*TNS + sp)*1024 + d*32 + e0 + j];
        att_s[d][e0+j] = s * t;
    }
    __syncthreads();
    if (tid < 32){
        float m = -1e30f;
        for (int e = 0; e < 32; e++) m = fmaxf(m, att_s[tid][e]);
        float s = 0.f;
        for (int e = 0; e < 32; e++){ float ev = expf(att_s[tid][e] - m); att_s[tid][e] = ev; s += ev; }
        float inv = 1.f / s;
        for (int e = 0; e < 32; e++) att_s[tid][e] *= inv;
    }
    __syncthreads();
    #pragma unroll
    for (int j = 0; j < 4; j++)
        attn[(long long)bh*1024 + d*32 + e0 + j] = att_s[d][e0+j];
}

// ---------------- combined weight: W_b[o][h*32+e] = sum_d capw[o][h*32+d]*attn[b][h][d][e] ----------------
__global__ __launch_bounds__(256) void wcomb_kernel(const float* __restrict__ capw, const float* __restrict__ attn,
                                                    bf16* __restrict__ Wb){
    __shared__ float at_s[8192];
    int b = blockIdx.x, og = blockIdx.y;
    int tid = threadIdx.x;
    #pragma unroll
    for (int j = 0; j < 8; j++)
        *(float4*)&at_s[tid*32 + j*4] = *(const float4*)(attn + (long long)b*8192 + tid*32 + j*4);
    __syncthreads();
    int o = og*32 + (tid & 31);
    int h = tid >> 5;
    float acc[32];
    #pragma unroll
    for (int e = 0; e < 32; e++) acc[e] = 0.f;
    for (int d = 0; d < 32; d++){
        float w = capw[(long long)o*256 + h*32 + d];
        const float* ar = &at_s[h*1024 + d*32];
        #pragma unroll
        for (int eq = 0; eq < 8; eq++){
            float4 av = *(const float4*)(ar + eq*4);
            acc[eq*4+0] += w*av.x; acc[eq*4+1] += w*av.y;
            acc[eq*4+2] += w*av.z; acc[eq*4+3] += w*av.w;
        }
    }
    bf16* dst = Wb + (long long)b*65536 + (long long)o*256 + h*32;
    #pragma unroll
    for (int eq = 0; eq < 4; eq++){
        union { uint4 u; unsigned short us[8]; } p;
        #pragma unroll
        for (int i = 0; i < 8; i++) p.us[i] = bfbits(acc[eq*8+i]);
        *(uint4*)(dst + eq*8) = p.u;
    }
}

// ---------------- orchestration ----------------
extern "C" void kernel_launch(void* const* d_in, const int* in_sizes, int n_in,
                              void* d_out, int out_size, void* d_ws, size_t ws_size,
                              hipStream_t stream){
    const float* x     = (const float*)d_in[0];
    const float* ln1g  = (const float*)d_in[3];
    const float* ln1b  = (const float*)d_in[4];
    const float* eakw  = (const float*)d_in[5];
    const float* eaqw  = (const float*)d_in[7];
    const float* eaqb  = (const float*)d_in[8];
    const float* eavw  = (const float*)d_in[9];
    const float* eavb  = (const float*)d_in[10];
    const float* earw  = (const float*)d_in[11];
    const float* earb  = (const float*)d_in[12];
    const float* ln2g  = (const float*)d_in[13];
    const float* ln2b  = (const float*)d_in[14];
    const float* m1w1  = (const float*)d_in[15];
    const float* m1b1  = (const float*)d_in[16];
    const float* m1dww = (const float*)d_in[17];
    const float* m1dwb = (const float*)d_in[18];
    const float* m1lg  = (const float*)d_in[19];
    const float* m1lb  = (const float*)d_in[20];
    const float* m1w2  = (const float*)d_in[21];
    const float* m1b2  = (const float*)d_in[22];
    const float* ln3g  = (const float*)d_in[23];
    const float* ln3b  = (const float*)d_in[24];
    const float* catemp= (const float*)d_in[25];
    const float* caqkvw= (const float*)d_in[26];
    const float* capw  = (const float*)d_in[27];
    const float* capb  = (const float*)d_in[28];
    const float* ln4g  = (const float*)d_in[29];
    const float* ln4b  = (const float*)d_in[30];
    const float* m2w1  = (const float*)d_in[31];
    const float* m2b1  = (const float*)d_in[32];
    const float* m2dww = (const float*)d_in[33];
    const float* m2dwb = (const float*)d_in[34];
    const float* m2lg  = (const float*)d_in[35];
    const float* m2lb  = (const float*)d_in[36];
    const float* m2w2  = (const float*)d_in[37];
    const float* m2b2  = (const float*)d_in[38];

    char* base = (char*)d_ws;
    auto alloc = [&](size_t nbytes){ char* p = base; base += (nbytes + 255) & ~(size_t)255; return p; };
    constexpr size_t SZ = (size_t)MTOT*CDIM*4;
    float* R  = (float*)alloc(SZ);
    float* A0 = (float*)alloc(SZ);
    float* A1 = (float*)alloc(SZ);
    float* B0 = (float*)alloc(SZ);
    float* B1 = (float*)alloc(SZ);
    bf16* A0b  = (bf16*)A0;                 // s1: ln1 out, then (after kq/v GEMMs) k-softmax bf16
    bf16* kb   = (bf16*)A0;                 //     same region, second life
    bf16* qb   = A0b + (size_t)MTOT*CDIM;   // s1: q softmax out (second half A0)
    bf16* vb   = (bf16*)A1;                 // s1: v bf16
    float* KQ  = B0;                        // s1: fused k|q f32 [MTOT,512] spans B0..B1
    bf16* attb = (bf16*)B0;                 // s1: att out (KQ dead)
    bf16* l2b  = (bf16*)A1;                 // s2: ln2 out
    bf16* F    = (bf16*)B0;                 // s2/s4: fc1 out
    bf16* G    = (bf16*)A0;                 // s2/s4: dwconv out
    bf16* l3b  = (bf16*)B0;                 // s3: ln3 out
    bf16* Qb   = (bf16*)A0;                 // s3: qkv
    bf16* l4b  = (bf16*)A0;                 // s4: ln4 out
    bf16* ctxb = (bf16*)alloc((size_t)BATCH*CDIM*CDIM*2);
    float* lmax = (float*)alloc((size_t)BATCH*NCHUNK*CDIM*4);
    float* lsum = (float*)alloc((size_t)BATCH*NCHUNK*CDIM*4);
    float* gmax = (float*)alloc((size_t)BATCH*CDIM*4);
    float* ginv = (float*)alloc((size_t)BATCH*CDIM*4);
    float* lss  = (float*)alloc((size_t)BATCH*NCHUNK*512*4);
    float* invn = (float*)alloc((size_t)BATCH*512*4);
    float* attnb= (float*)alloc((size_t)BATCH*8*32*32*4);
    float* ptn  = (float*)alloc((size_t)BATCH*TNS*CDIM*CDIM*4);
    float* pqk  = (float*)alloc((size_t)BATCH*8*TNS*1024*4);
    bf16* wbuf  = (bf16*)alloc((size_t)1572864*2);
    float* wT1  = (float*)alloc((size_t)9216*4);
    float* wT2  = (float*)alloc((size_t)9216*4);
    bf16* Wcb   = (bf16*)alloc((size_t)BATCH*CDIM*CDIM*2);

    bf16* kqw_b    = wbuf;                  // [512,256]: rows 0-255 k, 256-511 q
    bf16* eavw_b   = wbuf + 131072;
    bf16* earw_b   = wbuf + 196608;
    bf16* m1w1_b   = wbuf + 262144;
    bf16* m1w2_b   = wbuf + 524288;
    bf16* caqkvw_b = wbuf + 786432;
    bf16* m2w1_b   = wbuf + 1048576;
    bf16* m2w2_b   = wbuf + 1310720;

    dim3 blk(256);
    constexpr int MB = MTOT/128;            // 196
    long long sA1 = (long long)NPOS*CDIM;
    long long sB1 = (long long)CDIM*CDIM;

    // ---- weight prep ----
    {
        WArgs wa;
        const float* srcs[10] = {eakw, eaqw, eavw, earw, m1w1, m1w2, caqkvw, m2w1, m2w2, m2w2};
        bf16* dsts[10] = {kqw_b, kqw_b + 65536, eavw_b, earw_b, m1w1_b, m1w2_b, caqkvw_b, m2w1_b, m2w2_b, m2w2_b};
        int ns[10] = {65536, 65536, 65536, 65536, 262144, 262144, 196608, 262144, 262144, 0};
        for (int i = 0; i < 10; i++){ wa.src[i]=srcs[i]; wa.dst[i]=dsts[i]; wa.n[i]=ns[i]; }
        wcvt_kernel<<<dim3(128,10), blk, 0, stream>>>(wa);
        wtrans_kernel<<<dim3(36,2), blk, 0, stream>>>(m1dww, m2dww, wT1, wT2);
    }

    // ---- Stage 1: EfficientAttention ----
    ln4_kernel<bf16><<<MTOT/4, blk, 0, stream>>>(x, ln1g, ln1b, A0b);
    mfma_gemm<float><<<dim3(4,MB,1), blk, 0, stream>>>(A0b, kqw_b, nullptr, nullptr, KQ, MTOT, 512, 256, 256, 0,0,0,0); // k|q (k bias dropped: softmax-N invariant; q bias added in rowsm)
    mfma_gemm<bf16><<<dim3(2,MB,1), blk, 0, stream>>>(A0b, eavw_b, eavb, nullptr, vb, MTOT, 256, 256, 256, 0,0,0,0);
    rowsm4b_kernel<<<MTOT/4, blk, 0, stream>>>(KQ, eaqb, qb);
    colsm_p1<<<BATCH*NCHUNK, blk, 0, stream>>>(KQ, lmax, lsum);
    colsm_p2<<<BATCH, blk, 0, stream>>>(lmax, lsum, gmax, ginv);
    colsm_p3<<<MTOT, blk, 0, stream>>>(KQ, kb, gmax, ginv);             // kb overwrites dead ln1-out region
    gemm_tn_mfma<<<dim3(2,2,BATCH*TNS), blk, 0, stream>>>(vb, kb, ptn);
    ctx_reduce<<<(BATCH*65536)/256, blk, 0, stream>>>(ptn, ctxb);
    mfma_gemm<bf16><<<dim3(2,25,BATCH), blk, 0, stream>>>(qb, ctxb, nullptr, nullptr, attb,
            NPOS, 256, 256, 256, sA1, sB1, sA1, 0);
    mfma_gemm<float><<<dim3(2,MB,1), blk, 0, stream>>>(attb, earw_b, earb, x, R, MTOT, 256, 256, 256, 0,0,0,0);

    // ---- Stage 2: MixFFN #1 ----
    ln4_kernel<bf16><<<MTOT/4, blk, 0, stream>>>(R, ln2g, ln2b, l2b);
    mfma_gemm<bf16><<<dim3(8,MB,1), blk, 0, stream>>>(l2b, m1w1_b, m1b1, nullptr, F, MTOT, 1024, 256, 256, 0,0,0,0);
    dwconv_ln_gelu_kernel<<<BATCH*HH*14, blk, 0, stream>>>(F, wT1, m1dwb, m1lg, m1lb, G);
    mfma_gemm<float><<<dim3(2,MB,1), blk, 0, stream>>>(G, m1w2_b, m1b2, R, R, MTOT, 256, 1024, 1024, 0,0,0,0);

    // ---- Stage 3: ChannelAttention ----
    ln4_kernel<bf16><<<MTOT/4, blk, 0, stream>>>(R, ln3g, ln3b, l3b);
    mfma_gemm<bf16><<<dim3(6,MB,1), blk, 0, stream>>>(l3b, caqkvw_b, nullptr, nullptr, Qb, MTOT, 768, 256, 256, 0,0,0,0);
    ssq_p1<<<BATCH*NCHUNK, blk, 0, stream>>>(Qb, lss);
    ssq_p2<<<dim3(BATCH,2), blk, 0, stream>>>(lss, invn);
    chanattn_qk_part<<<BATCH*8*TNS, blk, 0, stream>>>(Qb, invn, pqk);
    chanattn_qk_fin<<<BATCH*8, blk, 0, stream>>>(pqk, catemp, attnb);
    wcomb_kernel<<<dim3(BATCH,8), blk, 0, stream>>>(capw, attnb, Wcb);
    mfma_gemm<float><<<dim3(2,25,BATCH), blk, 0, stream>>>(Qb + 512, Wcb, capb, R, R,
            NPOS, 256, 256, 768, (long long)NPOS*768, sB1, sA1, sA1);

    // ---- Stage 4: MixFFN #2 ----
    ln4_kernel<bf16><<<MTOT/4, blk, 0, stream>>>(R, ln4g, ln4b, l4b);
    mfma_gemm<bf16><<<dim3(8,MB,1), blk, 0, stream>>>(l4b, m2w1_b, m2b1, nullptr, F, MTOT, 1024, 256, 256, 0,0,0,0);
    dwconv_ln_gelu_kernel<<<BATCH*HH*14, blk, 0, stream>>>(F, wT2, m2dwb, m2lg, m2lb, G);
    mfma_gemm<float><<<dim3(2,MB,1), blk, 0, stream>>>(G, m2w2_b, m2b2, R, (float*)d_out, MTOT, 256, 1024, 1024, 0,0,0,0);
}

// Round 3
// 565.955 us; speedup vs baseline: 1.4189x; 1.0612x over previous
//
#include <hip/hip_runtime.h>
#include <hip/hip_bf16.h>

typedef __hip_bfloat16 bf16;
typedef __attribute__((ext_vector_type(8))) short short8;
typedef __attribute__((ext_vector_type(4))) float floatx4;

#define DI __device__ __forceinline__

DI unsigned short bfbits(float f){
    bf16 h = __float2bfloat16(f);
    return *reinterpret_cast<unsigned short*>(&h);
}
DI float bu(unsigned short u){
    union { unsigned int i; float f; } x; x.i = ((unsigned int)u) << 16; return x.f;
}

// exact-GELU via A&S 7.1.26 erf approx: |erf err| <= 1.5e-7 (<< bf16 noise).
// ~16 VALU insts vs ~90 for libm erff (which was ~60% of dwconv's VALU).
DI float gelu_exact(float x){
    float z = fabsf(x) * 0.70710678118654752f;          // |x|/sqrt(2)
    float t = __builtin_amdgcn_rcpf(fmaf(0.3275911f, z, 1.f));
    float p = t * fmaf(t, fmaf(t, fmaf(t, fmaf(t, 1.061405429f, -1.453152027f),
                    1.421413741f), -0.284496736f), 0.254829592f);
    float e = __expf(-z*z);
    float er = fmaf(-p, e, 1.f);                        // erf(z), z>=0
    er = copysignf(er, x);
    return 0.5f * x * (1.f + er);
}

// direct global->LDS 16B load (m97 trick). lds dest: wave-uniform base + lane*16.
DI void gload16(const void* g, void* l){
    __builtin_amdgcn_global_load_lds(
        (const __attribute__((address_space(1))) unsigned int*)g,
        (__attribute__((address_space(3))) unsigned int*)l,
        16, 0, 0);
}

static constexpr int BATCH = 8;
static constexpr int HH = 56, WW = 56;
static constexpr int NPOS = HH * WW;        // 3136
static constexpr int CDIM = 256;
static constexpr int HIDD = 1024;
static constexpr int MTOT = BATCH * NPOS;   // 25088
static constexpr int NCHUNK = 49;           // 3136 / 64
static constexpr int LP = 40;               // LDS pitch for tn gemm (shorts)
static constexpr int TNS = 7;               // split-K for ctx TN gemm

// ---------------- weight f32 -> bf16 pre-convert ----------------
struct WArgs {
    const float* src[10];
    bf16* dst[10];
    int n[10];
};
__global__ __launch_bounds__(256) void wcvt_kernel(WArgs a){
    int wid = blockIdx.y;
    int i = (blockIdx.x*256 + threadIdx.x) * 8;
    if (i >= a.n[wid]) return;
    const float* s = a.src[wid] + i;
    float4 f0 = *(const float4*)(s);
    float4 f1 = *(const float4*)(s + 4);
    union { uint4 u; unsigned short us[8]; } p;
    p.us[0]=bfbits(f0.x); p.us[1]=bfbits(f0.y); p.us[2]=bfbits(f0.z); p.us[3]=bfbits(f0.w);
    p.us[4]=bfbits(f1.x); p.us[5]=bfbits(f1.y); p.us[6]=bfbits(f1.z); p.us[7]=bfbits(f1.w);
    *(uint4*)(a.dst[wid] + i) = p.u;
}

__global__ __launch_bounds__(256) void wtrans_kernel(const float* __restrict__ w1, const float* __restrict__ w2,
                                                     float* __restrict__ t1, float* __restrict__ t2){
    int i = blockIdx.x*256 + threadIdx.x;   // 0..9215
    const float* w = blockIdx.y ? w2 : w1;
    float* t = blockIdx.y ? t2 : t1;
    int tap = i >> 10, c = i & 1023;
    t[i] = w[c*9 + tap];
}

// ---------------- MFMA bf16 GEMM (NT), global_load_lds staging, 2-phase dbuf ----------------
// LDS: two 16 KB buffers {A 8KB | B 8KB}. K-loop is min-2-phase (T3): issue next
// K-step's global_load_lds BEFORE current step's ds_read+MFMA, ONE barrier per step
// (barrier's vmcnt(0) drain lands after the loads overlapped with compute).
// Critical for the N=256 GEMMs which run at only ~1.5 blocks/CU (no cross-block TLP).
// XCD-bijective tile swizzle (m204) for A-panel L2 reuse; LDS-transpose epilogue with
// 128B-contiguous wide stores for both f32 and bf16 outputs.
template<typename TC>
__global__ __launch_bounds__(256) void mfma_gemm(
    const bf16* __restrict__ A, const bf16* __restrict__ Bw,
    const float* __restrict__ bias, const float* __restrict__ addend,
    TC* __restrict__ C, int M, int N, int K, int lda,
    long long strA, long long strB, long long strC, long long strAdd)
{
    __shared__ __align__(16) float smemf[8192];   // 32 KB: 2x {A 4096 shorts | B 4096 shorts}
    short* S = (short*)smemf;
    int tid = threadIdx.x;
    int bz = blockIdx.z;
    A  += (long long)bz * strA;
    Bw += (long long)bz * strB;
    C  += (long long)bz * strC;
    if (addend) addend += (long long)bz * strAdd;

    // --- bijective XCD chunk swizzle (m204) over the (x,y) tile space ---
    int gx = gridDim.x;
    int nwg = gx * gridDim.y;
    int bidl = blockIdx.y * gx + blockIdx.x;
    int qq = nwg >> 3, rr = nwg & 7;
    int xcd = bidl & 7, ixx = bidl >> 3;
    int tile = (xcd < rr) ? (xcd*(qq+1) + ixx) : (rr*(qq+1) + (xcd-rr)*qq + ixx);
    int n0 = (tile % gx) * 128, m0 = (tile / gx) * 128;

    int w = tid >> 6, lane = tid & 63, lm = lane & 15, quad = lane >> 4;
    int mw = (w >> 1) * 64, nw = (w & 1) * 64;

    // staging: wave w issues instructions t=2w,2w+1; lane covers chunk t*64+lane.
    int c0 = w*128 + lane, c1 = c0 + 64;
    int ar0 = c0 >> 2, ac0 = (c0 & 3) ^ (ar0 & 3);
    int ar1 = c1 >> 2, ac1 = (c1 & 3) ^ (ar1 & 3);
    int rgA0 = m0 + ar0; if (rgA0 > M-1) rgA0 = M-1;
    int rgA1 = m0 + ar1; if (rgA1 > M-1) rgA1 = M-1;
    short* aL0 = S + (2*w+0)*512;
    short* aL1 = S + (2*w+1)*512;
    short* bL0 = S + 4096 + (2*w+0)*512;
    short* bL1 = S + 4096 + (2*w+1)*512;
    const bf16* Arow0 = A + (long long)rgA0*lda + ac0*8;
    const bf16* Arow1 = A + (long long)rgA1*lda + ac1*8;
    const bf16* Brow0 = Bw + (long long)(n0+ar0)*K + ac0*8;
    const bf16* Brow1 = Bw + (long long)(n0+ar1)*K + ac1*8;

    floatx4 z = {0.f, 0.f, 0.f, 0.f};
    floatx4 acc[4][4];
    #pragma unroll
    for (int mi = 0; mi < 4; mi++)
        #pragma unroll
        for (int ni = 0; ni < 4; ni++) acc[mi][ni] = z;

    int sq = quad ^ (lm & 3);   // read-side swizzle (row&3 == lm&3 for all fragment rows)

    auto STAGE = [&](int k0, int poff){
        gload16(Arow0 + k0, aL0 + poff);
        gload16(Arow1 + k0, aL1 + poff);
        gload16(Brow0 + k0, bL0 + poff);
        gload16(Brow1 + k0, bL1 + poff);
    };

    STAGE(0, 0);
    __syncthreads();                 // drains prologue loads
    int NS = K >> 5;
    for (int st = 0; st < NS; st++){
        int poff = (st & 1) << 13;                       // 0 / 8192 shorts
        if (st + 1 < NS) STAGE((st+1)*32, poff ^ 8192);  // prefetch into other buffer
        short8 af[4], bfr[4];
        #pragma unroll
        for (int mi = 0; mi < 4; mi++)
            af[mi] = *(const short8*)&S[poff + (((mw + mi*16 + lm)<<2) + sq)*8];
        #pragma unroll
        for (int ni = 0; ni < 4; ni++)
            bfr[ni] = *(const short8*)&S[poff + 4096 + (((nw + ni*16 + lm)<<2) + sq)*8];
        #pragma unroll
        for (int mi = 0; mi < 4; mi++)
            #pragma unroll
            for (int ni = 0; ni < 4; ni++)
                acc[mi][ni] = __builtin_amdgcn_mfma_f32_16x16x32_bf16(af[mi], bfr[ni], acc[mi][ni], 0, 0, 0);
        __syncthreads();             // one barrier per K-step: readers done + prefetch landed
    }

    // --- epilogue: per-wave transpose through LDS, wide contiguous stores ---
    // After the final __syncthreads() no wave touches the tiles again; each wave uses
    // its private scratch strip (stride 68 f32 => balanced banks). A wave's DS ops
    // complete in order, so no barrier is needed between write and read-back.
    float bvv[4];
    #pragma unroll
    for (int ni = 0; ni < 4; ni++)
        bvv[ni] = bias ? bias[n0 + nw + ni*16 + lm] : 0.f;
    float* esc = smemf + w*1088;            // 16 rows x 68 floats per wave
    int rl0 = lane >> 3;                    // 0..7
    #pragma unroll
    for (int mi = 0; mi < 4; mi++){
        #pragma unroll
        for (int ni = 0; ni < 4; ni++)
            #pragma unroll
            for (int r = 0; r < 4; r++)
                esc[(quad*4 + r)*68 + ni*16 + lm] = acc[mi][ni][r] + bvv[ni];
        #pragma unroll
        for (int p = 0; p < 2; p++){
            int rloc = p*8 + rl0;
            int rg = m0 + mw + mi*16 + rloc;
            if (rg < M){
                if constexpr (sizeof(TC) == 2){
                    int cl = (lane & 7) * 8;        // 8 lanes x 8 bf16 = 128B/row
                    float4 u0 = *(const float4*)&esc[rloc*68 + cl];
                    float4 u1 = *(const float4*)&esc[rloc*68 + cl + 4];
                    if (addend){
                        long long ai = (long long)rg*N + (n0 + nw + cl);
                        float4 a0 = *(const float4*)(addend + ai);
                        float4 a1 = *(const float4*)(addend + ai + 4);
                        u0.x+=a0.x; u0.y+=a0.y; u0.z+=a0.z; u0.w+=a0.w;
                        u1.x+=a1.x; u1.y+=a1.y; u1.z+=a1.z; u1.w+=a1.w;
                    }
                    union { uint4 u; unsigned short us[8]; } pk;
                    pk.us[0]=bfbits(u0.x); pk.us[1]=bfbits(u0.y); pk.us[2]=bfbits(u0.z); pk.us[3]=bfbits(u0.w);
                    pk.us[4]=bfbits(u1.x); pk.us[5]=bfbits(u1.y); pk.us[6]=bfbits(u1.z); pk.us[7]=bfbits(u1.w);
                    *(uint4*)(C + (long long)rg*N + (n0 + nw + cl)) = pk.u;
                } else {
                    int cl4 = (lane & 7) * 4;       // 8 lanes x 4 f32 = 128B per half-row
                    long long co = (long long)rg*N + (n0 + nw);
                    float4 u0 = *(const float4*)&esc[rloc*68 + cl4];
                    float4 u1 = *(const float4*)&esc[rloc*68 + 32 + cl4];
                    if (addend){
                        float4 a0 = *(const float4*)(addend + co + cl4);
                        float4 a1 = *(const float4*)(addend + co + 32 + cl4);
                        u0.x+=a0.x; u0.y+=a0.y; u0.z+=a0.z; u0.w+=a0.w;
                        u1.x+=a1.x; u1.y+=a1.y; u1.z+=a1.z; u1.w+=a1.w;
                    }
                    *(float4*)(C + co + cl4) = u0;
                    *(float4*)(C + co + 32 + cl4) = u1;
                }
            }
        }
    }
}

// ---------------- MFMA bf16 TN GEMM: part[s][vc][kc] = sum_{n in split s} V[n,vc]*K[n,kc] ----------------
__global__ __launch_bounds__(256) void gemm_tn_mfma(const bf16* __restrict__ V, const bf16* __restrict__ Kb,
                                                    float* __restrict__ part){
    __shared__ short As[128*LP];
    __shared__ short Bs[128*LP];
    int tid = threadIdx.x;
    int bz = blockIdx.z;           // b*TNS + s
    int b = bz / TNS, s = bz % TNS;
    const bf16* Vb = V  + (long long)b*NPOS*CDIM;
    const bf16* Kc = Kb + (long long)b*NPOS*CDIM;
    int m0 = blockIdx.y * 128, n0 = blockIdx.x * 128;
    int w = tid >> 6, lane = tid & 63, lm = lane & 15, quad = lane >> 4;
    int mw = (w >> 1) * 64, nw = (w & 1) * 64;

    floatx4 z = {0.f,0.f,0.f,0.f};
    floatx4 acc[4][4];
    #pragma unroll
    for (int mi = 0; mi < 4; mi++)
        #pragma unroll
        for (int ni = 0; ni < 4; ni++) acc[mi][ni] = z;

    int r = tid & 31, cgrp = tid >> 5;

    for (int step = 0; step < 448/32; step++){
        int nb = s*448 + step*32;
        #pragma unroll
        for (int cc = 0; cc < 2; cc++){
            int ch = cgrp*8 + cc*64;
            short8 va = *(const short8*)(Vb + (long long)(nb + r)*CDIM + m0 + ch);
            short8 ka = *(const short8*)(Kc + (long long)(nb + r)*CDIM + n0 + ch);
            #pragma unroll
            for (int i = 0; i < 8; i++){
                As[(ch+i)*LP + r] = va[i];
                Bs[(ch+i)*LP + r] = ka[i];
            }
        }
        __syncthreads();
        short8 af[4], bfr[4];
        #pragma unroll
        for (int mi = 0; mi < 4; mi++)
            af[mi] = *(const short8*)&As[(mw + mi*16 + lm)*LP + quad*8];
        #pragma unroll
        for (int ni = 0; ni < 4; ni++)
            bfr[ni] = *(const short8*)&Bs[(nw + ni*16 + lm)*LP + quad*8];
        #pragma unroll
        for (int mi = 0; mi < 4; mi++)
            #pragma unroll
            for (int ni = 0; ni < 4; ni++)
                acc[mi][ni] = __builtin_amdgcn_mfma_f32_16x16x32_bf16(af[mi], bfr[ni], acc[mi][ni], 0, 0, 0);
        __syncthreads();
    }

    float* pb = part + (long long)bz * CDIM * CDIM;
    #pragma unroll
    for (int ni = 0; ni < 4; ni++){
        int cg = n0 + nw + ni*16 + lm;
        #pragma unroll
        for (int mi = 0; mi < 4; mi++){
            #pragma unroll
            for (int rr = 0; rr < 4; rr++){
                int rg = m0 + mw + mi*16 + quad*4 + rr;
                pb[(long long)rg*CDIM + cg] = acc[mi][ni][rr];
            }
        }
    }
}

__global__ __launch_bounds__(256) void ctx_reduce(const float* __restrict__ part, bf16* __restrict__ ctxb){
    long long idx = (long long)blockIdx.x*256 + threadIdx.x;
    int b = (int)(idx >> 16);
    int rem = (int)(idx & 65535);
    float s = 0.f;
    #pragma unroll
    for (int sp = 0; sp < TNS; sp++)
        s += part[((long long)(b*TNS+sp) << 16) + rem];
    ctxb[idx] = __float2bfloat16(s);
}

// ---------------- LayerNorm: one wave per row ----------------
DI void st4o(float* p, long long i, float a, float b, float c, float d){
    float4 v = make_float4(a,b,c,d); *(float4*)(p + i) = v;
}
DI void st4o(bf16* p, long long i, float a, float b, float c, float d){
    union { unsigned long long u; unsigned short us[4]; } pk;
    pk.us[0]=bfbits(a); pk.us[1]=bfbits(b); pk.us[2]=bfbits(c); pk.us[3]=bfbits(d);
    *(unsigned long long*)(p + i) = pk.u;
}
template<typename TOUT>
__global__ __launch_bounds__(256) void ln4_kernel(const float* __restrict__ x, const float* __restrict__ g,
                                                  const float* __restrict__ b, TOUT* __restrict__ y){
    int wv = threadIdx.x >> 6, lane = threadIdx.x & 63;
    long long row = (long long)blockIdx.x*4 + wv;
    float4 v = *(const float4*)(x + row*256 + lane*4);
    float s  = v.x + v.y + v.z + v.w;
    float ss = v.x*v.x + v.y*v.y + v.z*v.z + v.w*v.w;
    #pragma unroll
    for (int off = 32; off > 0; off >>= 1){
        s  += __shfl_down(s,  off);
        ss += __shfl_down(ss, off);
    }
    s = __shfl(s, 0); ss = __shfl(ss, 0);
    float mean = s * (1.f/256.f);
    float var  = ss * (1.f/256.f) - mean*mean;
    float inv  = rsqrtf(var + 1e-5f);
    float4 gv = *(const float4*)(g + lane*4);
    float4 bv = *(const float4*)(b + lane*4);
    st4o(y, row*256 + lane*4,
         (v.x-mean)*inv*gv.x + bv.x, (v.y-mean)*inv*gv.y + bv.y,
         (v.z-mean)*inv*gv.z + bv.z, (v.w-mean)*inv*gv.w + bv.w);
}

// ---------------- column softmax over N (k = cols 0..255 of KQ[.,512]) ----------------
// NOTE: k bias omitted upstream — softmax over N is invariant to per-column constants.
__global__ __launch_bounds__(256) void colsm_p1(const float* __restrict__ x, float* __restrict__ lmax, float* __restrict__ lsum){
    int b = blockIdx.x / NCHUNK, ch = blockIdx.x % NCHUNK;
    int c = threadIdx.x;
    const float* base = x + ((long long)b*NPOS + ch*64)*512 + c;
    float m = -1e30f;
    for (int r = 0; r < 64; r++) m = fmaxf(m, base[(long long)r*512]);
    float s = 0.f;
    for (int r = 0; r < 64; r++) s += expf(base[(long long)r*512] - m);
    lmax[(long long)blockIdx.x*CDIM + c] = m;
    lsum[(long long)blockIdx.x*CDIM + c] = s;
}
__global__ __launch_bounds__(256) void colsm_p2(const float* __restrict__ lmax, const float* __restrict__ lsum,
                                                float* __restrict__ gmax, float* __restrict__ ginv){
    int b = blockIdx.x; int c = threadIdx.x;
    float g = -1e30f;
    for (int ch = 0; ch < NCHUNK; ch++) g = fmaxf(g, lmax[((long long)b*NCHUNK+ch)*CDIM + c]);
    float s = 0.f;
    for (int ch = 0; ch < NCHUNK; ch++)
        s += lsum[((long long)b*NCHUNK+ch)*CDIM + c] * expf(lmax[((long long)b*NCHUNK+ch)*CDIM + c] - g);
    gmax[b*CDIM + c] = g; ginv[b*CDIM + c] = 1.f / s;
}
__global__ __launch_bounds__(256) void colsm_p3(const float* __restrict__ x, bf16* __restrict__ y,
                                                const float* __restrict__ gmax, const float* __restrict__ ginv){
    long long idx = (long long)blockIdx.x*256 + threadIdx.x;
    int c = (int)(idx & 255);
    long long row = idx >> 8;
    int b = (int)(row / NPOS);
    y[idx] = __float2bfloat16(expf(x[row*512 + c] - gmax[b*CDIM + c]) * ginv[b*CDIM + c]);
}

// ---------------- row softmax (q = cols 256..511 of KQ) + bias, wave-per-row ----------------
__global__ __launch_bounds__(256) void rowsm4b_kernel(const float* __restrict__ x, const float* __restrict__ bias,
                                                      bf16* __restrict__ y){
    int wv = threadIdx.x >> 6, lane = threadIdx.x & 63;
    long long row = (long long)blockIdx.x*4 + wv;
    float4 v = *(const float4*)(x + row*512 + 256 + lane*4);
    float4 bb = *(const float4*)(bias + lane*4);
    v.x += bb.x; v.y += bb.y; v.z += bb.z; v.w += bb.w;
    float m = fmaxf(fmaxf(v.x, v.y), fmaxf(v.z, v.w));
    #pragma unroll
    for (int off = 32; off > 0; off >>= 1) m = fmaxf(m, __shfl_down(m, off));
    m = __shfl(m, 0);
    float e0 = expf(v.x - m), e1 = expf(v.y - m), e2 = expf(v.z - m), e3 = expf(v.w - m);
    float s = e0 + e1 + e2 + e3;
    #pragma unroll
    for (int off = 32; off > 0; off >>= 1) s += __shfl_down(s, off);
    s = __shfl(s, 0);
    float inv = 1.f / s;
    st4o(y, row*256 + lane*4, e0*inv, e1*inv, e2*inv, e3*inv);
}

// ---------------- fused dwconv3x3 + skip + LN + GELU, LDS-tiled, XCD-swizzled ----------------
// LN reduction: partials aliased into the (dead-after-conv) halo tile -> LDS 36.9 KB
// (4 blocks/CU, was 3), and a wave-shuffle reduce: 4 barriers total (was 9).
__global__ __launch_bounds__(256) void dwconv_ln_gelu_kernel(const bf16* __restrict__ f, const float* __restrict__ wT,
        const float* __restrict__ db, const float* __restrict__ lg, const float* __restrict__ lb, bf16* __restrict__ out){
    __shared__ short Ls[18*1024];           // 36 KB halo tile; reused post-conv for LN partials
    int tid = threadIdx.x;
    // XCD swizzle: consecutive blockIdx -> different batch images (round-robin XCD => each
    // XCD works one image => halo rows hit its private L2).
    int b = blockIdx.x & 7;
    int rem = blockIdx.x >> 3;              // 0..783
    int h = rem / 14, w0 = (rem % 14) * 4;
    const bf16* fb = f + (long long)b * NPOS * HIDD;

    #pragma unroll
    for (int j = 0; j < 9; j++){
        int idx = j*256 + tid;
        int rc = idx >> 7, chunk = idx & 127;
        int row = rc / 6, col = rc % 6;
        int hy = h - 1 + row, wx = w0 - 1 + col;
        uint4 v = {0,0,0,0};
        if (hy >= 0 && hy < HH && wx >= 0 && wx < WW)
            v = *(const uint4*)(fb + (long long)(hy*WW + wx)*HIDD + chunk*8);
        *(uint4*)&Ls[rc*1024 + chunk*8] = v;
    }
    __syncthreads();

    int ph = tid >> 7, ct = tid & 127;
    int c0 = ct * 8;
    float sv[2][8];
    {
        float4 d0 = *(const float4*)(db + c0);
        float4 d1 = *(const float4*)(db + c0 + 4);
        #pragma unroll
        for (int pp = 0; pp < 2; pp++){
            sv[pp][0]=d0.x; sv[pp][1]=d0.y; sv[pp][2]=d0.z; sv[pp][3]=d0.w;
            sv[pp][4]=d1.x; sv[pp][5]=d1.y; sv[pp][6]=d1.z; sv[pp][7]=d1.w;
        }
    }
    #pragma unroll
    for (int tap = 0; tap < 9; tap++){
        int ky = tap / 3, kx = tap % 3;
        float4 w0v = *(const float4*)(wT + tap*1024 + c0);
        float4 w1v = *(const float4*)(wT + tap*1024 + c0 + 4);
        float wv[8] = {w0v.x,w0v.y,w0v.z,w0v.w,w1v.x,w1v.y,w1v.z,w1v.w};
        #pragma unroll
        for (int pp = 0; pp < 2; pp++){
            int pos_local = 2*ph + pp;
            short8 val = *(const short8*)&Ls[(ky*6 + pos_local + kx)*1024 + c0];
            #pragma unroll
            for (int i = 0; i < 8; i++){
                float fv = bu((unsigned short)val[i]);
                sv[pp][i] += fv * wv[i];
                if (tap == 4) sv[pp][i] += fv;
            }
        }
    }
    // --- LN reduce over 1024 ch: alias partials into dead Ls ---
    float* rr = (float*)Ls;                 // [0..511]=sum, [512..1023]=sumsq, [1024..1031]=result
    __syncthreads();                        // all waves done READING Ls
    #pragma unroll
    for (int pp = 0; pp < 2; pp++){
        float s = 0.f, ss = 0.f;
        #pragma unroll
        for (int i = 0; i < 8; i++){ s += sv[pp][i]; ss += sv[pp][i]*sv[pp][i]; }
        rr[(ph*2+pp)*128 + ct] = s;
        rr[512 + (ph*2+pp)*128 + ct] = ss;
    }
    __syncthreads();
    {
        int wv = tid >> 6, ln = tid & 63;   // wave wv reduces group g=wv (== ph*2+pp)
        float s  = rr[wv*128 + ln]       + rr[wv*128 + ln + 64];
        float ss = rr[512 + wv*128 + ln] + rr[512 + wv*128 + ln + 64];
        #pragma unroll
        for (int off = 32; off > 0; off >>= 1){
            s  += __shfl_down(s,  off);
            ss += __shfl_down(ss, off);
        }
        if (ln == 0){ rr[1024 + wv] = s; rr[1028 + wv] = ss; }
    }
    __syncthreads();
    float4 g0 = *(const float4*)(lg + c0), g1 = *(const float4*)(lg + c0 + 4);
    float4 b0 = *(const float4*)(lb + c0), b1 = *(const float4*)(lb + c0 + 4);
    float gg[8] = {g0.x,g0.y,g0.z,g0.w,g1.x,g1.y,g1.z,g1.w};
    float bb[8] = {b0.x,b0.y,b0.z,b0.w,b1.x,b1.y,b1.z,b1.w};
    #pragma unroll
    for (int pp = 0; pp < 2; pp++){
        int pos_local = 2*ph + pp;
        long long n = (long long)b*NPOS + h*WW + (w0 + pos_local);
        float mean = rr[1024 + ph*2+pp] * (1.f/HIDD);
        float var  = rr[1028 + ph*2+pp] * (1.f/HIDD) - mean*mean;
        float inv  = rsqrtf(var + 1e-5f);
        union { uint4 u; unsigned short us[8]; } ov;
        #pragma unroll
        for (int i = 0; i < 8; i++){
            float o = (sv[pp][i]-mean)*inv*gg[i] + bb[i];
            ov.us[i] = bfbits(gelu_exact(o));
        }
        *(uint4*)(out + n*HIDD + c0) = ov.u;
    }
}

// ---------------- channel-attn: per-channel sum-sq over N ----------------
__global__ __launch_bounds__(256) void ssq_p1(const bf16* __restrict__ qkv, float* __restrict__ lss){
    __shared__ float red[4][64][8];
    int b = blockIdx.x / NCHUNK, ch = blockIdx.x % NCHUNK;
    int tid = threadIdx.x;
    int col = (tid & 63) * 8;
    int rg = tid >> 6;
    float s[8] = {0,0,0,0,0,0,0,0};
    for (int r = rg*16; r < rg*16 + 16; r++){
        long long row = (long long)(b*NPOS + ch*64 + r);
        union { uint4 u; unsigned short us[8]; } v;
        v.u = *(const uint4*)(qkv + row*768 + col);
        #pragma unroll
        for (int i = 0; i < 8; i++){ float f = bu(v.us[i]); s[i] += f*f; }
    }
    #pragma unroll
    for (int i = 0; i < 8; i++) red[rg][tid & 63][i] = s[i];
    __syncthreads();
    if (tid < 64){
        #pragma unroll
        for (int i = 0; i < 8; i++){
            float t = red[0][tid][i] + red[1][tid][i] + red[2][tid][i] + red[3][tid][i];
            lss[(long long)blockIdx.x*512 + tid*8 + i] = t;
        }
    }
}
__global__ __launch_bounds__(256) void ssq_p2(const float* __restrict__ lss, float* __restrict__ invn){
    int b = blockIdx.x; int c = blockIdx.y*256 + threadIdx.x;
    float s = 0.f;
    for (int ch = 0; ch < NCHUNK; ch++) s += lss[((long long)b*NCHUNK+ch)*512 + c];
    invn[b*512 + c] = 1.f / fmaxf(sqrtf(s), 1e-12f);
}

// ---------------- channel-attn QK partials ----------------
__global__ __launch_bounds__(256) void chanattn_qk_part(const bf16* __restrict__ qkv, const float* __restrict__ invn,
                                                        float* __restrict__ part){
    __shared__ float qs[64][36];
    __shared__ float ks[64][36];
    int bz = blockIdx.x;               // (b*8+hh)*TNS + s
    int bh = bz / TNS, s = bz % TNS;
    int b = bh >> 3, hh = bh & 7;
    int tid = threadIdx.x;
    int d = tid >> 3, e0 = (tid & 7) * 4;
    int sr = tid >> 2, sc8 = (tid & 3) * 8;
    float invq[8], invk[8];
    {
        float4 a0 = *(const float4*)(invn + b*512 + hh*32 + sc8);
        float4 a1 = *(const float4*)(invn + b*512 + hh*32 + sc8 + 4);
        float4 b0 = *(const float4*)(invn + b*512 + 256 + hh*32 + sc8);
        float4 b1 = *(const float4*)(invn + b*512 + 256 + hh*32 + sc8 + 4);
        invq[0]=a0.x; invq[1]=a0.y; invq[2]=a0.z; invq[3]=a0.w;
        invq[4]=a1.x; invq[5]=a1.y; invq[6]=a1.z; invq[7]=a1.w;
        invk[0]=b0.x; invk[1]=b0.y; invk[2]=b0.z; invk[3]=b0.w;
        invk[4]=b1.x; invk[5]=b1.y; invk[6]=b1.z; invk[7]=b1.w;
    }
    float acc[4] = {0.f,0.f,0.f,0.f};
    for (int it = 0; it < 7; it++){
        int n0 = s*448 + it*64;
        {
            long long rowb = (long long)(b*NPOS + n0 + sr) * 768;
            union { uint4 u; unsigned short us[8]; } qv, kv;
            qv.u = *(const uint4*)(qkv + rowb + hh*32 + sc8);
            kv.u = *(const uint4*)(qkv + rowb + 256 + hh*32 + sc8);
            #pragma unroll
            for (int i = 0; i < 8; i++){
                qs[sr][sc8+i] = bu(qv.us[i]) * invq[i];
                ks[sr][sc8+i] = bu(kv.us[i]) * invk[i];
            }
        }
        __syncthreads();
        #pragma unroll 4
        for (int r = 0; r < 64; r++){
            float qv = qs[r][d];
            #pragma unroll
            for (int j = 0; j < 4; j++) acc[j] += qv * ks[r][e0+j];
        }
        __syncthreads();
    }
    #pragma unroll
    for (int j = 0; j < 4; j++)
        part[(long long)bz*1024 + d*32 + e0 + j] = acc[j];
}
__global__ __launch_bounds__(256) void chanattn_qk_fin(const float* __restrict__ part, const float* __restrict__ temp,
                                                       float* __restrict__ attn){
    __shared__ float att_s[32][33];
    int bh = blockIdx.x;
    int hh = bh & 7;
    int tid = threadIdx.x;
    int d = tid >> 3, e0 = (tid & 7) * 4;
    float t = temp[hh];
    #pragma unroll
    for (int j = 0; j < 4; j++){
        float s = 0.f;
        for (int sp = 0; sp < TNS; sp++)
            s += part[((long long)bh*TNS + sp)*1024 + d*32 + e0 + j];
        att_s[d][e0+j] = s * t;
    }
    __syncthreads();
    if (tid < 32){
        float m = -1e30f;
        for (int e = 0; e < 32; e++) m = fmaxf(m, att_s[tid][e]);
        float s = 0.f;
        for (int e = 0; e < 32; e++){ float ev = expf(att_s[tid][e] - m); att_s[tid][e] = ev; s += ev; }
        float inv = 1.f / s;
        for (int e = 0; e < 32; e++) att_s[tid][e] *= inv;
    }
    __syncthreads();
    #pragma unroll
    for (int j = 0; j < 4; j++)
        attn[(long long)bh*1024 + d*32 + e0 + j] = att_s[d][e0+j];
}

// ---------------- combined weight: W_b[o][h*32+e] = sum_d capw[o][h*32+d]*attn[b][h][d][e] ----------------
__global__ __launch_bounds__(256) void wcomb_kernel(const float* __restrict__ capw, const float* __restrict__ attn,
                                                    bf16* __restrict__ Wb){
    __shared__ float at_s[8192];
    int b = blockIdx.x, og = blockIdx.y;
    int tid = threadIdx.x;
    #pragma unroll
    for (int j = 0; j < 8; j++)
        *(float4*)&at_s[tid*32 + j*4] = *(const float4*)(attn + (long long)b*8192 + tid*32 + j*4);
    __syncthreads();
    int o = og*32 + (tid & 31);
    int h = tid >> 5;
    float acc[32];
    #pragma unroll
    for (int e = 0; e < 32; e++) acc[e] = 0.f;
    for (int d = 0; d < 32; d++){
        float w = capw[(long long)o*256 + h*32 + d];
        const float* ar = &at_s[h*1024 + d*32];
        #pragma unroll
        for (int eq = 0; eq < 8; eq++){
            float4 av = *(const float4*)(ar + eq*4);
            acc[eq*4+0] += w*av.x; acc[eq*4+1] += w*av.y;
            acc[eq*4+2] += w*av.z; acc[eq*4+3] += w*av.w;
        }
    }
    bf16* dst = Wb + (long long)b*65536 + (long long)o*256 + h*32;
    #pragma unroll
    for (int eq = 0; eq < 4; eq++){
        union { uint4 u; unsigned short us[8]; } p;
        #pragma unroll
        for (int i = 0; i < 8; i++) p.us[i] = bfbits(acc[eq*8+i]);
        *(uint4*)(dst + eq*8) = p.u;
    }
}

// ---------------- orchestration ----------------
extern "C" void kernel_launch(void* const* d_in, const int* in_sizes, int n_in,
                              void* d_out, int out_size, void* d_ws, size_t ws_size,
                              hipStream_t stream){
    const float* x     = (const float*)d_in[0];
    const float* ln1g  = (const float*)d_in[3];
    const float* ln1b  = (const float*)d_in[4];
    const float* eakw  = (const float*)d_in[5];
    const float* eaqw  = (const float*)d_in[7];
    const float* eaqb  = (const float*)d_in[8];
    const float* eavw  = (const float*)d_in[9];
    const float* eavb  = (const float*)d_in[10];
    const float* earw  = (const float*)d_in[11];
    const float* earb  = (const float*)d_in[12];
    const float* ln2g  = (const float*)d_in[13];
    const float* ln2b  = (const float*)d_in[14];
    const float* m1w1  = (const float*)d_in[15];
    const float* m1b1  = (const float*)d_in[16];
    const float* m1dww = (const float*)d_in[17];
    const float* m1dwb = (const float*)d_in[18];
    const float* m1lg  = (const float*)d_in[19];
    const float* m1lb  = (const float*)d_in[20];
    const float* m1w2  = (const float*)d_in[21];
    const float* m1b2  = (const float*)d_in[22];
    const float* ln3g  = (const float*)d_in[23];
    const float* ln3b  = (const float*)d_in[24];
    const float* catemp= (const float*)d_in[25];
    const float* caqkvw= (const float*)d_in[26];
    const float* capw  = (const float*)d_in[27];
    const float* capb  = (const float*)d_in[28];
    const float* ln4g  = (const float*)d_in[29];
    const float* ln4b  = (const float*)d_in[30];
    const float* m2w1  = (const float*)d_in[31];
    const float* m2b1  = (const float*)d_in[32];
    const float* m2dww = (const float*)d_in[33];
    const float* m2dwb = (const float*)d_in[34];
    const float* m2lg  = (const float*)d_in[35];
    const float* m2lb  = (const float*)d_in[36];
    const float* m2w2  = (const float*)d_in[37];
    const float* m2b2  = (const float*)d_in[38];

    char* base = (char*)d_ws;
    auto alloc = [&](size_t nbytes){ char* p = base; base += (nbytes + 255) & ~(size_t)255; return p; };
    constexpr size_t SZ = (size_t)MTOT*CDIM*4;
    float* R  = (float*)alloc(SZ);
    float* A0 = (float*)alloc(SZ);
    float* A1 = (float*)alloc(SZ);
    float* B0 = (float*)alloc(SZ);
    float* B1 = (float*)alloc(SZ);
    bf16* A0b  = (bf16*)A0;                 // s1: ln1 out, then (after kq/v GEMMs) k-softmax bf16
    bf16* kb   = (bf16*)A0;                 //     same region, second life
    bf16* qb   = A0b + (size_t)MTOT*CDIM;   // s1: q softmax out (second half A0)
    bf16* vb   = (bf16*)A1;                 // s1: v bf16
    float* KQ  = B0;                        // s1: fused k|q f32 [MTOT,512] spans B0..B1
    bf16* attb = (bf16*)B0;                 // s1: att out (KQ dead)
    bf16* l2b  = (bf16*)A1;                 // s2: ln2 out
    bf16* F    = (bf16*)B0;                 // s2/s4: fc1 out
    bf16* G    = (bf16*)A0;                 // s2/s4: dwconv out
    bf16* l3b  = (bf16*)B0;                 // s3: ln3 out
    bf16* Qb   = (bf16*)A0;                 // s3: qkv
    bf16* l4b  = (bf16*)A0;                 // s4: ln4 out
    bf16* ctxb = (bf16*)alloc((size_t)BATCH*CDIM*CDIM*2);
    float* lmax = (float*)alloc((size_t)BATCH*NCHUNK*CDIM*4);
    float* lsum = (float*)alloc((size_t)BATCH*NCHUNK*CDIM*4);
    float* gmax = (float*)alloc((size_t)BATCH*CDIM*4);
    float* ginv = (float*)alloc((size_t)BATCH*CDIM*4);
    float* lss  = (float*)alloc((size_t)BATCH*NCHUNK*512*4);
    float* invn = (float*)alloc((size_t)BATCH*512*4);
    float* attnb= (float*)alloc((size_t)BATCH*8*32*32*4);
    float* ptn  = (float*)alloc((size_t)BATCH*TNS*CDIM*CDIM*4);
    float* pqk  = (float*)alloc((size_t)BATCH*8*TNS*1024*4);
    bf16* wbuf  = (bf16*)alloc((size_t)1572864*2);
    float* wT1  = (float*)alloc((size_t)9216*4);
    float* wT2  = (float*)alloc((size_t)9216*4);
    bf16* Wcb   = (bf16*)alloc((size_t)BATCH*CDIM*CDIM*2);

    bf16* kqw_b    = wbuf;                  // [512,256]: rows 0-255 k, 256-511 q
    bf16* eavw_b   = wbuf + 131072;
    bf16* earw_b   = wbuf + 196608;
    bf16* m1w1_b   = wbuf + 262144;
    bf16* m1w2_b   = wbuf + 524288;
    bf16* caqkvw_b = wbuf + 786432;
    bf16* m2w1_b   = wbuf + 1048576;
    bf16* m2w2_b   = wbuf + 1310720;

    dim3 blk(256);
    constexpr int MB = MTOT/128;            // 196
    long long sA1 = (long long)NPOS*CDIM;
    long long sB1 = (long long)CDIM*CDIM;

    // ---- weight prep ----
    {
        WArgs wa;
        const float* srcs[10] = {eakw, eaqw, eavw, earw, m1w1, m1w2, caqkvw, m2w1, m2w2, m2w2};
        bf16* dsts[10] = {kqw_b, kqw_b + 65536, eavw_b, earw_b, m1w1_b, m1w2_b, caqkvw_b, m2w1_b, m2w2_b, m2w2_b};
        int ns[10] = {65536, 65536, 65536, 65536, 262144, 262144, 196608, 262144, 262144, 0};
        for (int i = 0; i < 10; i++){ wa.src[i]=srcs[i]; wa.dst[i]=dsts[i]; wa.n[i]=ns[i]; }
        wcvt_kernel<<<dim3(128,10), blk, 0, stream>>>(wa);
        wtrans_kernel<<<dim3(36,2), blk, 0, stream>>>(m1dww, m2dww, wT1, wT2);
    }

    // ---- Stage 1: EfficientAttention ----
    ln4_kernel<bf16><<<MTOT/4, blk, 0, stream>>>(x, ln1g, ln1b, A0b);
    mfma_gemm<float><<<dim3(4,MB,1), blk, 0, stream>>>(A0b, kqw_b, nullptr, nullptr, KQ, MTOT, 512, 256, 256, 0,0,0,0); // k|q (k bias dropped: softmax-N invariant; q bias added in rowsm)
    mfma_gemm<bf16><<<dim3(2,MB,1), blk, 0, stream>>>(A0b, eavw_b, eavb, nullptr, vb, MTOT, 256, 256, 256, 0,0,0,0);
    rowsm4b_kernel<<<MTOT/4, blk, 0, stream>>>(KQ, eaqb, qb);
    colsm_p1<<<BATCH*NCHUNK, blk, 0, stream>>>(KQ, lmax, lsum);
    colsm_p2<<<BATCH, blk, 0, stream>>>(lmax, lsum, gmax, ginv);
    colsm_p3<<<MTOT, blk, 0, stream>>>(KQ, kb, gmax, ginv);             // kb overwrites dead ln1-out region
    gemm_tn_mfma<<<dim3(2,2,BATCH*TNS), blk, 0, stream>>>(vb, kb, ptn);
    ctx_reduce<<<(BATCH*65536)/256, blk, 0, stream>>>(ptn, ctxb);
    mfma_gemm<bf16><<<dim3(2,25,BATCH), blk, 0, stream>>>(qb, ctxb, nullptr, nullptr, attb,
            NPOS, 256, 256, 256, sA1, sB1, sA1, 0);
    mfma_gemm<float><<<dim3(2,MB,1), blk, 0, stream>>>(attb, earw_b, earb, x, R, MTOT, 256, 256, 256, 0,0,0,0);

    // ---- Stage 2: MixFFN #1 ----
    ln4_kernel<bf16><<<MTOT/4, blk, 0, stream>>>(R, ln2g, ln2b, l2b);
    mfma_gemm<bf16><<<dim3(8,MB,1), blk, 0, stream>>>(l2b, m1w1_b, m1b1, nullptr, F, MTOT, 1024, 256, 256, 0,0,0,0);
    dwconv_ln_gelu_kernel<<<BATCH*HH*14, blk, 0, stream>>>(F, wT1, m1dwb, m1lg, m1lb, G);
    mfma_gemm<float><<<dim3(2,MB,1), blk, 0, stream>>>(G, m1w2_b, m1b2, R, R, MTOT, 256, 1024, 1024, 0,0,0,0);

    // ---- Stage 3: ChannelAttention ----
    ln4_kernel<bf16><<<MTOT/4, blk, 0, stream>>>(R, ln3g, ln3b, l3b);
    mfma_gemm<bf16><<<dim3(6,MB,1), blk, 0, stream>>>(l3b, caqkvw_b, nullptr, nullptr, Qb, MTOT, 768, 256, 256, 0,0,0,0);
    ssq_p1<<<BATCH*NCHUNK, blk, 0, stream>>>(Qb, lss);
    ssq_p2<<<dim3(BATCH,2), blk, 0, stream>>>(lss, invn);
    chanattn_qk_part<<<BATCH*8*TNS, blk, 0, stream>>>(Qb, invn, pqk);
    chanattn_qk_fin<<<BATCH*8, blk, 0, stream>>>(pqk, catemp, attnb);
    wcomb_kernel<<<dim3(BATCH,8), blk, 0, stream>>>(capw, attnb, Wcb);
    mfma_gemm<float><<<dim3(2,25,BATCH), blk, 0, stream>>>(Qb + 512, Wcb, capb, R, R,
            NPOS, 256, 256, 768, (long long)NPOS*768, sB1, sA1, sA1);

    // ---- Stage 4: MixFFN #2 ----
    ln4_kernel<bf16><<<MTOT/4, blk, 0, stream>>>(R, ln4g, ln4b, l4b);
    mfma_gemm<bf16><<<dim3(8,MB,1), blk, 0, stream>>>(l4b, m2w1_b, m2b1, nullptr, F, MTOT, 1024, 256, 256, 0,0,0,0);
    dwconv_ln_gelu_kernel<<<BATCH*HH*14, blk, 0, stream>>>(F, wT2, m2dwb, m2lg, m2lb, G);
    mfma_gemm<float><<<dim3(2,MB,1), blk, 0, stream>>>(G, m2w2_b, m2b2, R, (float*)d_out, MTOT, 256, 1024, 1024, 0,0,0,0);
}

// Round 4
// 551.468 us; speedup vs baseline: 1.4561x; 1.0263x over previous
//
#include <hip/hip_runtime.h>
#include <hip/hip_bf16.h>

typedef __hip_bfloat16 bf16;
typedef __attribute__((ext_vector_type(8))) short short8;
typedef __attribute__((ext_vector_type(4))) float floatx4;

#define DI __device__ __forceinline__

DI unsigned short bfbits(float f){
    bf16 h = __float2bfloat16(f);
    return *reinterpret_cast<unsigned short*>(&h);
}
DI float bu(unsigned short u){
    union { unsigned int i; float f; } x; x.i = ((unsigned int)u) << 16; return x.f;
}

// exact-GELU via A&S 7.1.26 erf approx: |erf err| <= 1.5e-7 (<< bf16 noise).
DI float gelu_exact(float x){
    float z = fabsf(x) * 0.70710678118654752f;          // |x|/sqrt(2)
    float t = __builtin_amdgcn_rcpf(fmaf(0.3275911f, z, 1.f));
    float p = t * fmaf(t, fmaf(t, fmaf(t, fmaf(t, 1.061405429f, -1.453152027f),
                    1.421413741f), -0.284496736f), 0.254829592f);
    float e = __expf(-z*z);
    float er = fmaf(-p, e, 1.f);                        // erf(z), z>=0
    er = copysignf(er, x);
    return 0.5f * x * (1.f + er);
}

// direct global->LDS 16B load (m97 trick). lds dest: wave-uniform base + lane*16.
DI void gload16(const void* g, void* l){
    __builtin_amdgcn_global_load_lds(
        (const __attribute__((address_space(1))) unsigned int*)g,
        (__attribute__((address_space(3))) unsigned int*)l,
        16, 0, 0);
}

static constexpr int BATCH = 8;
static constexpr int HH = 56, WW = 56;
static constexpr int NPOS = HH * WW;        // 3136
static constexpr int CDIM = 256;
static constexpr int HIDD = 1024;
static constexpr int MTOT = BATCH * NPOS;   // 25088
static constexpr int NCHUNK = 49;           // 3136 / 64
static constexpr int LP = 40;               // LDS pitch for tn gemm (shorts)
static constexpr int TNS = 7;               // split-K for ctx TN gemm

// ---------------- weight f32 -> bf16 pre-convert ----------------
struct WArgs {
    const float* src[10];
    bf16* dst[10];
    int n[10];
};
__global__ __launch_bounds__(256) void wcvt_kernel(WArgs a){
    int wid = blockIdx.y;
    int i = (blockIdx.x*256 + threadIdx.x) * 8;
    if (i >= a.n[wid]) return;
    const float* s = a.src[wid] + i;
    float4 f0 = *(const float4*)(s);
    float4 f1 = *(const float4*)(s + 4);
    union { uint4 u; unsigned short us[8]; } p;
    p.us[0]=bfbits(f0.x); p.us[1]=bfbits(f0.y); p.us[2]=bfbits(f0.z); p.us[3]=bfbits(f0.w);
    p.us[4]=bfbits(f1.x); p.us[5]=bfbits(f1.y); p.us[6]=bfbits(f1.z); p.us[7]=bfbits(f1.w);
    *(uint4*)(a.dst[wid] + i) = p.u;
}

__global__ __launch_bounds__(256) void wtrans_kernel(const float* __restrict__ w1, const float* __restrict__ w2,
                                                     float* __restrict__ t1, float* __restrict__ t2){
    int i = blockIdx.x*256 + threadIdx.x;   // 0..9215
    const float* w = blockIdx.y ? w2 : w1;
    float* t = blockIdx.y ? t2 : t1;
    int tap = i >> 10, c = i & 1023;
    t[i] = w[c*9 + tap];
}

// ---------------- MFMA bf16 GEMM (NT), global_load_lds staging, 2-phase dbuf ----------------
template<typename TC>
__global__ __launch_bounds__(256) void mfma_gemm(
    const bf16* __restrict__ A, const bf16* __restrict__ Bw,
    const float* __restrict__ bias, const float* __restrict__ addend,
    TC* __restrict__ C, int M, int N, int K, int lda,
    long long strA, long long strB, long long strC, long long strAdd)
{
    __shared__ __align__(16) float smemf[8192];   // 32 KB: 2x {A 4096 shorts | B 4096 shorts}
    short* S = (short*)smemf;
    int tid = threadIdx.x;
    int bz = blockIdx.z;
    A  += (long long)bz * strA;
    Bw += (long long)bz * strB;
    C  += (long long)bz * strC;
    if (addend) addend += (long long)bz * strAdd;

    // --- bijective XCD chunk swizzle (m204) over the (x,y) tile space ---
    int gx = gridDim.x;
    int nwg = gx * gridDim.y;
    int bidl = blockIdx.y * gx + blockIdx.x;
    int qq = nwg >> 3, rr = nwg & 7;
    int xcd = bidl & 7, ixx = bidl >> 3;
    int tile = (xcd < rr) ? (xcd*(qq+1) + ixx) : (rr*(qq+1) + (xcd-rr)*qq + ixx);
    int n0 = (tile % gx) * 128, m0 = (tile / gx) * 128;

    int w = tid >> 6, lane = tid & 63, lm = lane & 15, quad = lane >> 4;
    int mw = (w >> 1) * 64, nw = (w & 1) * 64;

    // staging: wave w issues instructions t=2w,2w+1; lane covers chunk t*64+lane.
    int c0 = w*128 + lane, c1 = c0 + 64;
    int ar0 = c0 >> 2, ac0 = (c0 & 3) ^ (ar0 & 3);
    int ar1 = c1 >> 2, ac1 = (c1 & 3) ^ (ar1 & 3);
    int rgA0 = m0 + ar0; if (rgA0 > M-1) rgA0 = M-1;
    int rgA1 = m0 + ar1; if (rgA1 > M-1) rgA1 = M-1;
    short* aL0 = S + (2*w+0)*512;
    short* aL1 = S + (2*w+1)*512;
    short* bL0 = S + 4096 + (2*w+0)*512;
    short* bL1 = S + 4096 + (2*w+1)*512;
    const bf16* Arow0 = A + (long long)rgA0*lda + ac0*8;
    const bf16* Arow1 = A + (long long)rgA1*lda + ac1*8;
    const bf16* Brow0 = Bw + (long long)(n0+ar0)*K + ac0*8;
    const bf16* Brow1 = Bw + (long long)(n0+ar1)*K + ac1*8;

    floatx4 z = {0.f, 0.f, 0.f, 0.f};
    floatx4 acc[4][4];
    #pragma unroll
    for (int mi = 0; mi < 4; mi++)
        #pragma unroll
        for (int ni = 0; ni < 4; ni++) acc[mi][ni] = z;

    int sq = quad ^ (lm & 3);   // read-side swizzle (row&3 == lm&3 for all fragment rows)

    auto STAGE = [&](int k0, int poff){
        gload16(Arow0 + k0, aL0 + poff);
        gload16(Arow1 + k0, aL1 + poff);
        gload16(Brow0 + k0, bL0 + poff);
        gload16(Brow1 + k0, bL1 + poff);
    };

    STAGE(0, 0);
    __syncthreads();                 // drains prologue loads
    int NS = K >> 5;
    for (int st = 0; st < NS; st++){
        int poff = (st & 1) << 13;                       // 0 / 8192 shorts
        if (st + 1 < NS) STAGE((st+1)*32, poff ^ 8192);  // prefetch into other buffer
        short8 af[4], bfr[4];
        #pragma unroll
        for (int mi = 0; mi < 4; mi++)
            af[mi] = *(const short8*)&S[poff + (((mw + mi*16 + lm)<<2) + sq)*8];
        #pragma unroll
        for (int ni = 0; ni < 4; ni++)
            bfr[ni] = *(const short8*)&S[poff + 4096 + (((nw + ni*16 + lm)<<2) + sq)*8];
        #pragma unroll
        for (int mi = 0; mi < 4; mi++)
            #pragma unroll
            for (int ni = 0; ni < 4; ni++)
                acc[mi][ni] = __builtin_amdgcn_mfma_f32_16x16x32_bf16(af[mi], bfr[ni], acc[mi][ni], 0, 0, 0);
        __syncthreads();             // one barrier per K-step: readers done + prefetch landed
    }

    // --- epilogue: per-wave transpose through LDS, wide contiguous stores ---
    float bvv[4];
    #pragma unroll
    for (int ni = 0; ni < 4; ni++)
        bvv[ni] = bias ? bias[n0 + nw + ni*16 + lm] : 0.f;
    float* esc = smemf + w*1088;            // 16 rows x 68 floats per wave
    int rl0 = lane >> 3;                    // 0..7
    #pragma unroll
    for (int mi = 0; mi < 4; mi++){
        #pragma unroll
        for (int ni = 0; ni < 4; ni++)
            #pragma unroll
            for (int r = 0; r < 4; r++)
                esc[(quad*4 + r)*68 + ni*16 + lm] = acc[mi][ni][r] + bvv[ni];
        #pragma unroll
        for (int p = 0; p < 2; p++){
            int rloc = p*8 + rl0;
            int rg = m0 + mw + mi*16 + rloc;
            if (rg < M){
                if constexpr (sizeof(TC) == 2){
                    int cl = (lane & 7) * 8;        // 8 lanes x 8 bf16 = 128B/row
                    float4 u0 = *(const float4*)&esc[rloc*68 + cl];
                    float4 u1 = *(const float4*)&esc[rloc*68 + cl + 4];
                    if (addend){
                        long long ai = (long long)rg*N + (n0 + nw + cl);
                        float4 a0 = *(const float4*)(addend + ai);
                        float4 a1 = *(const float4*)(addend + ai + 4);
                        u0.x+=a0.x; u0.y+=a0.y; u0.z+=a0.z; u0.w+=a0.w;
                        u1.x+=a1.x; u1.y+=a1.y; u1.z+=a1.z; u1.w+=a1.w;
                    }
                    union { uint4 u; unsigned short us[8]; } pk;
                    pk.us[0]=bfbits(u0.x); pk.us[1]=bfbits(u0.y); pk.us[2]=bfbits(u0.z); pk.us[3]=bfbits(u0.w);
                    pk.us[4]=bfbits(u1.x); pk.us[5]=bfbits(u1.y); pk.us[6]=bfbits(u1.z); pk.us[7]=bfbits(u1.w);
                    *(uint4*)(C + (long long)rg*N + (n0 + nw + cl)) = pk.u;
                } else {
                    int cl4 = (lane & 7) * 4;       // 8 lanes x 4 f32 = 128B per half-row
                    long long co = (long long)rg*N + (n0 + nw);
                    float4 u0 = *(const float4*)&esc[rloc*68 + cl4];
                    float4 u1 = *(const float4*)&esc[rloc*68 + 32 + cl4];
                    if (addend){
                        float4 a0 = *(const float4*)(addend + co + cl4);
                        float4 a1 = *(const float4*)(addend + co + 32 + cl4);
                        u0.x+=a0.x; u0.y+=a0.y; u0.z+=a0.z; u0.w+=a0.w;
                        u1.x+=a1.x; u1.y+=a1.y; u1.z+=a1.z; u1.w+=a1.w;
                    }
                    *(float4*)(C + co + cl4) = u0;
                    *(float4*)(C + co + 32 + cl4) = u1;
                }
            }
        }
    }
}

// ---------------- MFMA bf16 TN GEMM: part[s][vc][kc] = sum_{n in split s} V[n,vc]*K[n,kc] ----------------
__global__ __launch_bounds__(256) void gemm_tn_mfma(const bf16* __restrict__ V, const bf16* __restrict__ Kb,
                                                    float* __restrict__ part){
    __shared__ short As[128*LP];
    __shared__ short Bs[128*LP];
    int tid = threadIdx.x;
    int bz = blockIdx.z;           // b*TNS + s
    int b = bz / TNS, s = bz % TNS;
    const bf16* Vb = V  + (long long)b*NPOS*CDIM;
    const bf16* Kc = Kb + (long long)b*NPOS*CDIM;
    int m0 = blockIdx.y * 128, n0 = blockIdx.x * 128;
    int w = tid >> 6, lane = tid & 63, lm = lane & 15, quad = lane >> 4;
    int mw = (w >> 1) * 64, nw = (w & 1) * 64;

    floatx4 z = {0.f,0.f,0.f,0.f};
    floatx4 acc[4][4];
    #pragma unroll
    for (int mi = 0; mi < 4; mi++)
        #pragma unroll
        for (int ni = 0; ni < 4; ni++) acc[mi][ni] = z;

    int r = tid & 31, cgrp = tid >> 5;

    for (int step = 0; step < 448/32; step++){
        int nb = s*448 + step*32;
        #pragma unroll
        for (int cc = 0; cc < 2; cc++){
            int ch = cgrp*8 + cc*64;
            short8 va = *(const short8*)(Vb + (long long)(nb + r)*CDIM + m0 + ch);
            short8 ka = *(const short8*)(Kc + (long long)(nb + r)*CDIM + n0 + ch);
            #pragma unroll
            for (int i = 0; i < 8; i++){
                As[(ch+i)*LP + r] = va[i];
                Bs[(ch+i)*LP + r] = ka[i];
            }
        }
        __syncthreads();
        short8 af[4], bfr[4];
        #pragma unroll
        for (int mi = 0; mi < 4; mi++)
            af[mi] = *(const short8*)&As[(mw + mi*16 + lm)*LP + quad*8];
        #pragma unroll
        for (int ni = 0; ni < 4; ni++)
            bfr[ni] = *(const short8*)&Bs[(nw + ni*16 + lm)*LP + quad*8];
        #pragma unroll
        for (int mi = 0; mi < 4; mi++)
            #pragma unroll
            for (int ni = 0; ni < 4; ni++)
                acc[mi][ni] = __builtin_amdgcn_mfma_f32_16x16x32_bf16(af[mi], bfr[ni], acc[mi][ni], 0, 0, 0);
        __syncthreads();
    }

    float* pb = part + (long long)bz * CDIM * CDIM;
    #pragma unroll
    for (int ni = 0; ni < 4; ni++){
        int cg = n0 + nw + ni*16 + lm;
        #pragma unroll
        for (int mi = 0; mi < 4; mi++){
            #pragma unroll
            for (int rr = 0; rr < 4; rr++){
                int rg = m0 + mw + mi*16 + quad*4 + rr;
                pb[(long long)rg*CDIM + cg] = acc[mi][ni][rr];
            }
        }
    }
}

__global__ __launch_bounds__(256) void ctx_reduce(const float* __restrict__ part, bf16* __restrict__ ctxb){
    long long idx = (long long)blockIdx.x*256 + threadIdx.x;
    int b = (int)(idx >> 16);
    int rem = (int)(idx & 65535);
    float s = 0.f;
    #pragma unroll
    for (int sp = 0; sp < TNS; sp++)
        s += part[((long long)(b*TNS+sp) << 16) + rem];
    ctxb[idx] = __float2bfloat16(s);
}

// ---------------- LayerNorm: one wave per row ----------------
DI void st4o(float* p, long long i, float a, float b, float c, float d){
    float4 v = make_float4(a,b,c,d); *(float4*)(p + i) = v;
}
DI void st4o(bf16* p, long long i, float a, float b, float c, float d){
    union { unsigned long long u; unsigned short us[4]; } pk;
    pk.us[0]=bfbits(a); pk.us[1]=bfbits(b); pk.us[2]=bfbits(c); pk.us[3]=bfbits(d);
    *(unsigned long long*)(p + i) = pk.u;
}
template<typename TOUT>
__global__ __launch_bounds__(256) void ln4_kernel(const float* __restrict__ x, const float* __restrict__ g,
                                                  const float* __restrict__ b, TOUT* __restrict__ y){
    int wv = threadIdx.x >> 6, lane = threadIdx.x & 63;
    long long row = (long long)blockIdx.x*4 + wv;
    float4 v = *(const float4*)(x + row*256 + lane*4);
    float s  = v.x + v.y + v.z + v.w;
    float ss = v.x*v.x + v.y*v.y + v.z*v.z + v.w*v.w;
    #pragma unroll
    for (int off = 32; off > 0; off >>= 1){
        s  += __shfl_down(s,  off);
        ss += __shfl_down(ss, off);
    }
    s = __shfl(s, 0); ss = __shfl(ss, 0);
    float mean = s * (1.f/256.f);
    float var  = ss * (1.f/256.f) - mean*mean;
    float inv  = rsqrtf(var + 1e-5f);
    float4 gv = *(const float4*)(g + lane*4);
    float4 bv = *(const float4*)(b + lane*4);
    st4o(y, row*256 + lane*4,
         (v.x-mean)*inv*gv.x + bv.x, (v.y-mean)*inv*gv.y + bv.y,
         (v.z-mean)*inv*gv.z + bv.z, (v.w-mean)*inv*gv.w + bv.w);
}

// ---------------- column softmax over N (k = cols 0..255 of KQ[.,512]) ----------------
// NOTE: k bias omitted upstream — softmax over N is invariant to per-column constants.
__global__ __launch_bounds__(256) void colsm_p1(const float* __restrict__ x, float* __restrict__ lmax, float* __restrict__ lsum){
    int b = blockIdx.x / NCHUNK, ch = blockIdx.x % NCHUNK;
    int c = threadIdx.x;
    const float* base = x + ((long long)b*NPOS + ch*64)*512 + c;
    float m = -1e30f;
    for (int r = 0; r < 64; r++) m = fmaxf(m, base[(long long)r*512]);
    float s = 0.f;
    for (int r = 0; r < 64; r++) s += expf(base[(long long)r*512] - m);
    lmax[(long long)blockIdx.x*CDIM + c] = m;
    lsum[(long long)blockIdx.x*CDIM + c] = s;
}
__global__ __launch_bounds__(256) void colsm_p2(const float* __restrict__ lmax, const float* __restrict__ lsum,
                                                float* __restrict__ gmax, float* __restrict__ ginv){
    int b = blockIdx.x; int c = threadIdx.x;
    float g = -1e30f;
    for (int ch = 0; ch < NCHUNK; ch++) g = fmaxf(g, lmax[((long long)b*NCHUNK+ch)*CDIM + c]);
    float s = 0.f;
    for (int ch = 0; ch < NCHUNK; ch++)
        s += lsum[((long long)b*NCHUNK+ch)*CDIM + c] * expf(lmax[((long long)b*NCHUNK+ch)*CDIM + c] - g);
    gmax[b*CDIM + c] = g; ginv[b*CDIM + c] = 1.f / s;
}

// ---------------- fused kq softmax: q row-softmax + k col-softmax apply, one pass over KQ ----------------
__global__ __launch_bounds__(256) void kqsm_kernel(const float* __restrict__ x, const float* __restrict__ bias,
                                                   const float* __restrict__ gmax, const float* __restrict__ ginv,
                                                   bf16* __restrict__ kb, bf16* __restrict__ qb){
    int wv = threadIdx.x >> 6, lane = threadIdx.x & 63;
    long long row = (long long)blockIdx.x*4 + wv;
    int b = blockIdx.x / 784;               // 784 blocks per batch (3136/4)
    // --- q row softmax (cols 256..511), bias added here ---
    float4 v = *(const float4*)(x + row*512 + 256 + lane*4);
    float4 bb = *(const float4*)(bias + lane*4);
    v.x += bb.x; v.y += bb.y; v.z += bb.z; v.w += bb.w;
    float m = fmaxf(fmaxf(v.x, v.y), fmaxf(v.z, v.w));
    #pragma unroll
    for (int off = 32; off > 0; off >>= 1) m = fmaxf(m, __shfl_down(m, off));
    m = __shfl(m, 0);
    float e0 = expf(v.x - m), e1 = expf(v.y - m), e2 = expf(v.z - m), e3 = expf(v.w - m);
    float s = e0 + e1 + e2 + e3;
    #pragma unroll
    for (int off = 32; off > 0; off >>= 1) s += __shfl_down(s, off);
    s = __shfl(s, 0);
    float inv = 1.f / s;
    st4o(qb, row*256 + lane*4, e0*inv, e1*inv, e2*inv, e3*inv);
    // --- k column softmax apply (cols 0..255) ---
    float4 kv = *(const float4*)(x + row*512 + lane*4);
    float4 gm = *(const float4*)(gmax + b*CDIM + lane*4);
    float4 gi = *(const float4*)(ginv + b*CDIM + lane*4);
    st4o(kb, row*256 + lane*4,
         expf(kv.x - gm.x)*gi.x, expf(kv.y - gm.y)*gi.y,
         expf(kv.z - gm.z)*gi.z, expf(kv.w - gm.w)*gi.w);
}

// ---------------- fused dwconv3x3 + skip + LN + GELU, direct-load (no LDS halo) ----------------
// F's 3-row working set (~344 KB) is L2-resident (FETCH_SIZE already showed halo re-reads
// never reach HBM) -> LDS staging was pure overhead (Common-mistake #7). Each thread loads
// its 3x4 uint4 neighborhood directly, convolves in registers. LDS only for the LN reduce
// (4 KB). Border blocks (~17%) take the guarded template path; interior is check-free.
template<bool G>
DI void conv_core(const bf16* __restrict__ fb, const float* __restrict__ wT,
                  int h, int pw, int c0, float* acc0, float* acc1){
    #pragma unroll
    for (int r = 0; r < 3; r++){
        int hy = h - 1 + r;
        bool rv = !G || (hy >= 0 && hy < HH);
        int hyc = G ? min(max(hy, 0), HH-1) : hy;
        float u[4][8];
        #pragma unroll
        for (int c = 0; c < 4; c++){
            int wx = pw - 1 + c;
            bool vv = rv && (!G || (wx >= 0 && wx < WW));
            int wxc = G ? min(max(wx, 0), WW-1) : wx;
            uint4 raw = *(const uint4*)(fb + (long long)(hyc*WW + wxc)*HIDD + c0);
            unsigned short* us = (unsigned short*)&raw;
            #pragma unroll
            for (int i = 0; i < 8; i++){
                float xv = bu(us[i]);
                u[c][i] = (G && !vv) ? 0.f : xv;
            }
        }
        #pragma unroll
        for (int kx = 0; kx < 3; kx++){
            float4 wA = *(const float4*)(wT + (r*3+kx)*1024 + c0);
            float4 wB = *(const float4*)(wT + (r*3+kx)*1024 + c0 + 4);
            float wv[8] = {wA.x,wA.y,wA.z,wA.w,wB.x,wB.y,wB.z,wB.w};
            #pragma unroll
            for (int i = 0; i < 8; i++){
                acc0[i] = fmaf(u[kx][i],   wv[i], acc0[i]);
                acc1[i] = fmaf(u[kx+1][i], wv[i], acc1[i]);
            }
        }
        if (r == 1){    // identity skip: + center value
            #pragma unroll
            for (int i = 0; i < 8; i++){ acc0[i] += u[1][i]; acc1[i] += u[2][i]; }
        }
    }
}

__global__ __launch_bounds__(256) void dwconv_ln_gelu_kernel(const bf16* __restrict__ f, const float* __restrict__ wT,
        const float* __restrict__ db, const float* __restrict__ lg, const float* __restrict__ lb, bf16* __restrict__ out){
    __shared__ float rs[4][128], rq[4][128], rfin[8];
    int tid = threadIdx.x;
    // XCD swizzle: consecutive blockIdx -> different batch images.
    int b = blockIdx.x & 7;
    int rem = blockIdx.x >> 3;              // 0..783
    int h = rem / 14, w0 = (rem % 14) * 4;
    const bf16* fb = f + (long long)b * NPOS * HIDD;
    int ph = tid >> 7, ct = tid & 127;
    int c0 = ct * 8;
    int pw = w0 + 2*ph;                     // first of this thread's 2 positions

    float acc0[8], acc1[8];
    {
        float4 d0 = *(const float4*)(db + c0);
        float4 d1 = *(const float4*)(db + c0 + 4);
        acc0[0]=d0.x; acc0[1]=d0.y; acc0[2]=d0.z; acc0[3]=d0.w;
        acc0[4]=d1.x; acc0[5]=d1.y; acc0[6]=d1.z; acc0[7]=d1.w;
        #pragma unroll
        for (int i = 0; i < 8; i++) acc1[i] = acc0[i];
    }
    bool interior = (h > 0) && (h < HH-1) && (w0 > 0) && (w0 < 52);
    if (interior) conv_core<false>(fb, wT, h, pw, c0, acc0, acc1);
    else          conv_core<true >(fb, wT, h, pw, c0, acc0, acc1);

    // LN partials: group g = 2*ph+pp (position within block)
    {
        float s0=0.f, q0=0.f, s1=0.f, q1=0.f;
        #pragma unroll
        for (int i = 0; i < 8; i++){
            s0 += acc0[i]; q0 += acc0[i]*acc0[i];
            s1 += acc1[i]; q1 += acc1[i]*acc1[i];
        }
        rs[2*ph][ct] = s0; rq[2*ph][ct] = q0;
        rs[2*ph+1][ct] = s1; rq[2*ph+1][ct] = q1;
    }
    __syncthreads();
    {
        int wv = tid >> 6, ln = tid & 63;   // wave wv reduces group wv
        float s = rs[wv][ln] + rs[wv][ln+64];
        float q = rq[wv][ln] + rq[wv][ln+64];
        #pragma unroll
        for (int off = 32; off > 0; off >>= 1){
            s += __shfl_down(s, off);
            q += __shfl_down(q, off);
        }
        if (ln == 0){ rfin[wv] = s; rfin[4+wv] = q; }
    }
    __syncthreads();
    float4 g0 = *(const float4*)(lg + c0), g1 = *(const float4*)(lg + c0 + 4);
    float4 b0 = *(const float4*)(lb + c0), b1 = *(const float4*)(lb + c0 + 4);
    float gg[8] = {g0.x,g0.y,g0.z,g0.w,g1.x,g1.y,g1.z,g1.w};
    float bb[8] = {b0.x,b0.y,b0.z,b0.w,b1.x,b1.y,b1.z,b1.w};
    #pragma unroll
    for (int pp = 0; pp < 2; pp++){
        int g = 2*ph + pp;
        long long n = (long long)b*NPOS + h*WW + (pw + pp);
        float mean = rfin[g] * (1.f/HIDD);
        float var  = rfin[4+g] * (1.f/HIDD) - mean*mean;
        float inv  = rsqrtf(var + 1e-5f);
        const float* ac = pp ? acc1 : acc0;
        union { uint4 u; unsigned short us[8]; } ov;
        #pragma unroll
        for (int i = 0; i < 8; i++){
            float o = (ac[i]-mean)*inv*gg[i] + bb[i];
            ov.us[i] = bfbits(gelu_exact(o));
        }
        *(uint4*)(out + n*HIDD + c0) = ov.u;
    }
}

// ---------------- channel-attn: per-channel sum-sq over N ----------------
__global__ __launch_bounds__(256) void ssq_p1(const bf16* __restrict__ qkv, float* __restrict__ lss){
    __shared__ float red[4][64][8];
    int b = blockIdx.x / NCHUNK, ch = blockIdx.x % NCHUNK;
    int tid = threadIdx.x;
    int col = (tid & 63) * 8;
    int rg = tid >> 6;
    float s[8] = {0,0,0,0,0,0,0,0};
    for (int r = rg*16; r < rg*16 + 16; r++){
        long long row = (long long)(b*NPOS + ch*64 + r);
        union { uint4 u; unsigned short us[8]; } v;
        v.u = *(const uint4*)(qkv + row*768 + col);
        #pragma unroll
        for (int i = 0; i < 8; i++){ float f = bu(v.us[i]); s[i] += f*f; }
    }
    #pragma unroll
    for (int i = 0; i < 8; i++) red[rg][tid & 63][i] = s[i];
    __syncthreads();
    if (tid < 64){
        #pragma unroll
        for (int i = 0; i < 8; i++){
            float t = red[0][tid][i] + red[1][tid][i] + red[2][tid][i] + red[3][tid][i];
            lss[(long long)blockIdx.x*512 + tid*8 + i] = t;
        }
    }
}
__global__ __launch_bounds__(256) void ssq_p2(const float* __restrict__ lss, float* __restrict__ invn){
    int b = blockIdx.x; int c = blockIdx.y*256 + threadIdx.x;
    float s = 0.f;
    for (int ch = 0; ch < NCHUNK; ch++) s += lss[((long long)b*NCHUNK+ch)*512 + c];
    invn[b*512 + c] = 1.f / fmaxf(sqrtf(s), 1e-12f);
}

// ---------------- channel-attn QK partials ----------------
__global__ __launch_bounds__(256) void chanattn_qk_part(const bf16* __restrict__ qkv, const float* __restrict__ invn,
                                                        float* __restrict__ part){
    __shared__ float qs[64][36];
    __shared__ float ks[64][36];
    int bz = blockIdx.x;               // (b*8+hh)*TNS + s
    int bh = bz / TNS, s = bz % TNS;
    int b = bh >> 3, hh = bh & 7;
    int tid = threadIdx.x;
    int d = tid >> 3, e0 = (tid & 7) * 4;
    int sr = tid >> 2, sc8 = (tid & 3) * 8;
    float invq[8], invk[8];
    {
        float4 a0 = *(const float4*)(invn + b*512 + hh*32 + sc8);
        float4 a1 = *(const float4*)(invn + b*512 + hh*32 + sc8 + 4);
        float4 b0 = *(const float4*)(invn + b*512 + 256 + hh*32 + sc8);
        float4 b1 = *(const float4*)(invn + b*512 + 256 + hh*32 + sc8 + 4);
        invq[0]=a0.x; invq[1]=a0.y; invq[2]=a0.z; invq[3]=a0.w;
        invq[4]=a1.x; invq[5]=a1.y; invq[6]=a1.z; invq[7]=a1.w;
        invk[0]=b0.x; invk[1]=b0.y; invk[2]=b0.z; invk[3]=b0.w;
        invk[4]=b1.x; invk[5]=b1.y; invk[6]=b1.z; invk[7]=b1.w;
    }
    float acc[4] = {0.f,0.f,0.f,0.f};
    for (int it = 0; it < 7; it++){
        int n0 = s*448 + it*64;
        {
            long long rowb = (long long)(b*NPOS + n0 + sr) * 768;
            union { uint4 u; unsigned short us[8]; } qv, kv;
            qv.u = *(const uint4*)(qkv + rowb + hh*32 + sc8);
            kv.u = *(const uint4*)(qkv + rowb + 256 + hh*32 + sc8);
            #pragma unroll
            for (int i = 0; i < 8; i++){
                qs[sr][sc8+i] = bu(qv.us[i]) * invq[i];
                ks[sr][sc8+i] = bu(kv.us[i]) * invk[i];
            }
        }
        __syncthreads();
        #pragma unroll 4
        for (int r = 0; r < 64; r++){
            float qv = qs[r][d];
            #pragma unroll
            for (int j = 0; j < 4; j++) acc[j] += qv * ks[r][e0+j];
        }
        __syncthreads();
    }
    #pragma unroll
    for (int j = 0; j < 4; j++)
        part[(long long)bz*1024 + d*32 + e0 + j] = acc[j];
}
__global__ __launch_bounds__(256) void chanattn_qk_fin(const float* __restrict__ part, const float* __restrict__ temp,
                                                       float* __restrict__ attn){
    __shared__ float att_s[32][33];
    int bh = blockIdx.x;
    int hh = bh & 7;
    int tid = threadIdx.x;
    int d = tid >> 3, e0 = (tid & 7) * 4;
    float t = temp[hh];
    #pragma unroll
    for (int j = 0; j < 4; j++){
        float s = 0.f;
        for (int sp = 0; sp < TNS; sp++)
            s += part[((long long)bh*TNS + sp)*1024 + d*32 + e0 + j];
        att_s[d][e0+j] = s * t;
    }
    __syncthreads();
    if (tid < 32){
        float m = -1e30f;
        for (int e = 0; e < 32; e++) m = fmaxf(m, att_s[tid][e]);
        float s = 0.f;
        for (int e = 0; e < 32; e++){ float ev = expf(att_s[tid][e] - m); att_s[tid][e] = ev; s += ev; }
        float inv = 1.f / s;
        for (int e = 0; e < 32; e++) att_s[tid][e] *= inv;
    }
    __syncthreads();
    #pragma unroll
    for (int j = 0; j < 4; j++)
        attn[(long long)bh*1024 + d*32 + e0 + j] = att_s[d][e0+j];
}

// ---------------- combined weight: W_b[o][h*32+e] = sum_d capw[o][h*32+d]*attn[b][h][d][e] ----------------
__global__ __launch_bounds__(256) void wcomb_kernel(const float* __restrict__ capw, const float* __restrict__ attn,
                                                    bf16* __restrict__ Wb){
    __shared__ float at_s[8192];
    int b = blockIdx.x, og = blockIdx.y;
    int tid = threadIdx.x;
    #pragma unroll
    for (int j = 0; j < 8; j++)
        *(float4*)&at_s[tid*32 + j*4] = *(const float4*)(attn + (long long)b*8192 + tid*32 + j*4);
    __syncthreads();
    int o = og*32 + (tid & 31);
    int h = tid >> 5;
    float acc[32];
    #pragma unroll
    for (int e = 0; e < 32; e++) acc[e] = 0.f;
    for (int d = 0; d < 32; d++){
        float w = capw[(long long)o*256 + h*32 + d];
        const float* ar = &at_s[h*1024 + d*32];
        #pragma unroll
        for (int eq = 0; eq < 8; eq++){
            float4 av = *(const float4*)(ar + eq*4);
            acc[eq*4+0] += w*av.x; acc[eq*4+1] += w*av.y;
            acc[eq*4+2] += w*av.z; acc[eq*4+3] += w*av.w;
        }
    }
    bf16* dst = Wb + (long long)b*65536 + (long long)o*256 + h*32;
    #pragma unroll
    for (int eq = 0; eq < 4; eq++){
        union { uint4 u; unsigned short us[8]; } p;
        #pragma unroll
        for (int i = 0; i < 8; i++) p.us[i] = bfbits(acc[eq*8+i]);
        *(uint4*)(dst + eq*8) = p.u;
    }
}

// ---------------- orchestration ----------------
extern "C" void kernel_launch(void* const* d_in, const int* in_sizes, int n_in,
                              void* d_out, int out_size, void* d_ws, size_t ws_size,
                              hipStream_t stream){
    const float* x     = (const float*)d_in[0];
    const float* ln1g  = (const float*)d_in[3];
    const float* ln1b  = (const float*)d_in[4];
    const float* eakw  = (const float*)d_in[5];
    const float* eaqw  = (const float*)d_in[7];
    const float* eaqb  = (const float*)d_in[8];
    const float* eavw  = (const float*)d_in[9];
    const float* eavb  = (const float*)d_in[10];
    const float* earw  = (const float*)d_in[11];
    const float* earb  = (const float*)d_in[12];
    const float* ln2g  = (const float*)d_in[13];
    const float* ln2b  = (const float*)d_in[14];
    const float* m1w1  = (const float*)d_in[15];
    const float* m1b1  = (const float*)d_in[16];
    const float* m1dww = (const float*)d_in[17];
    const float* m1dwb = (const float*)d_in[18];
    const float* m1lg  = (const float*)d_in[19];
    const float* m1lb  = (const float*)d_in[20];
    const float* m1w2  = (const float*)d_in[21];
    const float* m1b2  = (const float*)d_in[22];
    const float* ln3g  = (const float*)d_in[23];
    const float* ln3b  = (const float*)d_in[24];
    const float* catemp= (const float*)d_in[25];
    const float* caqkvw= (const float*)d_in[26];
    const float* capw  = (const float*)d_in[27];
    const float* capb  = (const float*)d_in[28];
    const float* ln4g  = (const float*)d_in[29];
    const float* ln4b  = (const float*)d_in[30];
    const float* m2w1  = (const float*)d_in[31];
    const float* m2b1  = (const float*)d_in[32];
    const float* m2dww = (const float*)d_in[33];
    const float* m2dwb = (const float*)d_in[34];
    const float* m2lg  = (const float*)d_in[35];
    const float* m2lb  = (const float*)d_in[36];
    const float* m2w2  = (const float*)d_in[37];
    const float* m2b2  = (const float*)d_in[38];

    char* base = (char*)d_ws;
    auto alloc = [&](size_t nbytes){ char* p = base; base += (nbytes + 255) & ~(size_t)255; return p; };
    constexpr size_t SZ = (size_t)MTOT*CDIM*4;
    float* R  = (float*)alloc(SZ);
    float* A0 = (float*)alloc(SZ);
    float* A1 = (float*)alloc(SZ);
    float* B0 = (float*)alloc(SZ);
    float* B1 = (float*)alloc(SZ);
    bf16* A0b  = (bf16*)A0;                 // s1: ln1 out, then (after kq/v GEMMs) k-softmax bf16
    bf16* kb   = (bf16*)A0;                 //     same region, second life
    bf16* qb   = A0b + (size_t)MTOT*CDIM;   // s1: q softmax out (second half A0)
    bf16* vb   = (bf16*)A1;                 // s1: v bf16
    float* KQ  = B0;                        // s1: fused k|q f32 [MTOT,512] spans B0..B1
    bf16* attb = (bf16*)B0;                 // s1: att out (KQ dead)
    bf16* l2b  = (bf16*)A1;                 // s2: ln2 out
    bf16* F    = (bf16*)B0;                 // s2/s4: fc1 out
    bf16* G    = (bf16*)A0;                 // s2/s4: dwconv out
    bf16* l3b  = (bf16*)B0;                 // s3: ln3 out
    bf16* Qb   = (bf16*)A0;                 // s3: qkv
    bf16* l4b  = (bf16*)A0;                 // s4: ln4 out
    bf16* ctxb = (bf16*)alloc((size_t)BATCH*CDIM*CDIM*2);
    float* lmax = (float*)alloc((size_t)BATCH*NCHUNK*CDIM*4);
    float* lsum = (float*)alloc((size_t)BATCH*NCHUNK*CDIM*4);
    float* gmax = (float*)alloc((size_t)BATCH*CDIM*4);
    float* ginv = (float*)alloc((size_t)BATCH*CDIM*4);
    float* lss  = (float*)alloc((size_t)BATCH*NCHUNK*512*4);
    float* invn = (float*)alloc((size_t)BATCH*512*4);
    float* attnb= (float*)alloc((size_t)BATCH*8*32*32*4);
    float* ptn  = (float*)alloc((size_t)BATCH*TNS*CDIM*CDIM*4);
    float* pqk  = (float*)alloc((size_t)BATCH*8*TNS*1024*4);
    bf16* wbuf  = (bf16*)alloc((size_t)1572864*2);
    float* wT1  = (float*)alloc((size_t)9216*4);
    float* wT2  = (float*)alloc((size_t)9216*4);
    bf16* Wcb   = (bf16*)alloc((size_t)BATCH*CDIM*CDIM*2);

    bf16* kqw_b    = wbuf;                  // [512,256]: rows 0-255 k, 256-511 q
    bf16* eavw_b   = wbuf + 131072;
    bf16* earw_b   = wbuf + 196608;
    bf16* m1w1_b   = wbuf + 262144;
    bf16* m1w2_b   = wbuf + 524288;
    bf16* caqkvw_b = wbuf + 786432;
    bf16* m2w1_b   = wbuf + 1048576;
    bf16* m2w2_b   = wbuf + 1310720;

    dim3 blk(256);
    constexpr int MB = MTOT/128;            // 196
    long long sA1 = (long long)NPOS*CDIM;
    long long sB1 = (long long)CDIM*CDIM;

    // ---- weight prep ----
    {
        WArgs wa;
        const float* srcs[10] = {eakw, eaqw, eavw, earw, m1w1, m1w2, caqkvw, m2w1, m2w2, m2w2};
        bf16* dsts[10] = {kqw_b, kqw_b + 65536, eavw_b, earw_b, m1w1_b, m1w2_b, caqkvw_b, m2w1_b, m2w2_b, m2w2_b};
        int ns[10] = {65536, 65536, 65536, 65536, 262144, 262144, 196608, 262144, 262144, 0};
        for (int i = 0; i < 10; i++){ wa.src[i]=srcs[i]; wa.dst[i]=dsts[i]; wa.n[i]=ns[i]; }
        wcvt_kernel<<<dim3(128,10), blk, 0, stream>>>(wa);
        wtrans_kernel<<<dim3(36,2), blk, 0, stream>>>(m1dww, m2dww, wT1, wT2);
    }

    // ---- Stage 1: EfficientAttention ----
    ln4_kernel<bf16><<<MTOT/4, blk, 0, stream>>>(x, ln1g, ln1b, A0b);
    mfma_gemm<float><<<dim3(4,MB,1), blk, 0, stream>>>(A0b, kqw_b, nullptr, nullptr, KQ, MTOT, 512, 256, 256, 0,0,0,0); // k|q (k bias dropped: softmax-N invariant; q bias added in kqsm)
    mfma_gemm<bf16><<<dim3(2,MB,1), blk, 0, stream>>>(A0b, eavw_b, eavb, nullptr, vb, MTOT, 256, 256, 256, 0,0,0,0);
    colsm_p1<<<BATCH*NCHUNK, blk, 0, stream>>>(KQ, lmax, lsum);
    colsm_p2<<<BATCH, blk, 0, stream>>>(lmax, lsum, gmax, ginv);
    kqsm_kernel<<<MTOT/4, blk, 0, stream>>>(KQ, eaqb, gmax, ginv, kb, qb);   // kb overwrites dead ln1-out region
    gemm_tn_mfma<<<dim3(2,2,BATCH*TNS), blk, 0, stream>>>(vb, kb, ptn);
    ctx_reduce<<<(BATCH*65536)/256, blk, 0, stream>>>(ptn, ctxb);
    mfma_gemm<bf16><<<dim3(2,25,BATCH), blk, 0, stream>>>(qb, ctxb, nullptr, nullptr, attb,
            NPOS, 256, 256, 256, sA1, sB1, sA1, 0);
    mfma_gemm<float><<<dim3(2,MB,1), blk, 0, stream>>>(attb, earw_b, earb, x, R, MTOT, 256, 256, 256, 0,0,0,0);

    // ---- Stage 2: MixFFN #1 ----
    ln4_kernel<bf16><<<MTOT/4, blk, 0, stream>>>(R, ln2g, ln2b, l2b);
    mfma_gemm<bf16><<<dim3(8,MB,1), blk, 0, stream>>>(l2b, m1w1_b, m1b1, nullptr, F, MTOT, 1024, 256, 256, 0,0,0,0);
    dwconv_ln_gelu_kernel<<<BATCH*HH*14, blk, 0, stream>>>(F, wT1, m1dwb, m1lg, m1lb, G);
    mfma_gemm<float><<<dim3(2,MB,1), blk, 0, stream>>>(G, m1w2_b, m1b2, R, R, MTOT, 256, 1024, 1024, 0,0,0,0);

    // ---- Stage 3: ChannelAttention ----
    ln4_kernel<bf16><<<MTOT/4, blk, 0, stream>>>(R, ln3g, ln3b, l3b);
    mfma_gemm<bf16><<<dim3(6,MB,1), blk, 0, stream>>>(l3b, caqkvw_b, nullptr, nullptr, Qb, MTOT, 768, 256, 256, 0,0,0,0);
    ssq_p1<<<BATCH*NCHUNK, blk, 0, stream>>>(Qb, lss);
    ssq_p2<<<dim3(BATCH,2), blk, 0, stream>>>(lss, invn);
    chanattn_qk_part<<<BATCH*8*TNS, blk, 0, stream>>>(Qb, invn, pqk);
    chanattn_qk_fin<<<BATCH*8, blk, 0, stream>>>(pqk, catemp, attnb);
    wcomb_kernel<<<dim3(BATCH,8), blk, 0, stream>>>(capw, attnb, Wcb);
    mfma_gemm<float><<<dim3(2,25,BATCH), blk, 0, stream>>>(Qb + 512, Wcb, capb, R, R,
            NPOS, 256, 256, 768, (long long)NPOS*768, sB1, sA1, sA1);

    // ---- Stage 4: MixFFN #2 ----
    ln4_kernel<bf16><<<MTOT/4, blk, 0, stream>>>(R, ln4g, ln4b, l4b);
    mfma_gemm<bf16><<<dim3(8,MB,1), blk, 0, stream>>>(l4b, m2w1_b, m2b1, nullptr, F, MTOT, 1024, 256, 256, 0,0,0,0);
    dwconv_ln_gelu_kernel<<<BATCH*HH*14, blk, 0, stream>>>(F, wT2, m2dwb, m2lg, m2lb, G);
    mfma_gemm<float><<<dim3(2,MB,1), blk, 0, stream>>>(G, m2w2_b, m2b2, R, (float*)d_out, MTOT, 256, 1024, 1024, 0,0,0,0);
}

// Round 6
// 530.486 us; speedup vs baseline: 1.5137x; 1.0396x over previous
//
#include <hip/hip_runtime.h>
#include <hip/hip_bf16.h>

typedef __hip_bfloat16 bf16;
typedef __attribute__((ext_vector_type(8))) short short8;
typedef __attribute__((ext_vector_type(4))) float floatx4;

#define DI __device__ __forceinline__

DI unsigned short bfbits(float f){
    bf16 h = __float2bfloat16(f);
    return *reinterpret_cast<unsigned short*>(&h);
}
DI float bu(unsigned short u){
    union { unsigned int i; float f; } x; x.i = ((unsigned int)u) << 16; return x.f;
}

// exact-GELU via A&S 7.1.26 erf approx: |erf err| <= 1.5e-7 (<< bf16 noise).
DI float gelu_exact(float x){
    float z = fabsf(x) * 0.70710678118654752f;          // |x|/sqrt(2)
    float t = __builtin_amdgcn_rcpf(fmaf(0.3275911f, z, 1.f));
    float p = t * fmaf(t, fmaf(t, fmaf(t, fmaf(t, 1.061405429f, -1.453152027f),
                    1.421413741f), -0.284496736f), 0.254829592f);
    float e = __expf(-z*z);
    float er = fmaf(-p, e, 1.f);                        // erf(z), z>=0
    er = copysignf(er, x);
    return 0.5f * x * (1.f + er);
}

// direct global->LDS 16B load (m97 trick). lds dest: wave-uniform base + lane*16.
DI void gload16(const void* g, void* l){
    __builtin_amdgcn_global_load_lds(
        (const __attribute__((address_space(1))) unsigned int*)g,
        (__attribute__((address_space(3))) unsigned int*)l,
        16, 0, 0);
}

static constexpr int BATCH = 8;
static constexpr int HH = 56, WW = 56;
static constexpr int NPOS = HH * WW;        // 3136
static constexpr int CDIM = 256;
static constexpr int HIDD = 1024;
static constexpr int MTOT = BATCH * NPOS;   // 25088
static constexpr int NCHUNK = 49;           // 3136 / 64
static constexpr int LP = 40;               // LDS pitch for tn gemm (shorts)
static constexpr int TNS = 7;               // split-K for ctx TN gemm

// ---------------- weight f32 -> bf16 pre-convert ----------------
struct WArgs {
    const float* src[10];
    bf16* dst[10];
    int n[10];
};
__global__ __launch_bounds__(256) void wcvt_kernel(WArgs a){
    int wid = blockIdx.y;
    int i = (blockIdx.x*256 + threadIdx.x) * 8;
    if (i >= a.n[wid]) return;
    const float* s = a.src[wid] + i;
    float4 f0 = *(const float4*)(s);
    float4 f1 = *(const float4*)(s + 4);
    union { uint4 u; unsigned short us[8]; } p;
    p.us[0]=bfbits(f0.x); p.us[1]=bfbits(f0.y); p.us[2]=bfbits(f0.z); p.us[3]=bfbits(f0.w);
    p.us[4]=bfbits(f1.x); p.us[5]=bfbits(f1.y); p.us[6]=bfbits(f1.z); p.us[7]=bfbits(f1.w);
    *(uint4*)(a.dst[wid] + i) = p.u;
}

__global__ __launch_bounds__(256) void wtrans_kernel(const float* __restrict__ w1, const float* __restrict__ w2,
                                                     float* __restrict__ t1, float* __restrict__ t2){
    int i = blockIdx.x*256 + threadIdx.x;   // 0..9215
    const float* w = blockIdx.y ? w2 : w1;
    float* t = blockIdx.y ? t2 : t1;
    int tap = i >> 10, c = i & 1023;
    t[i] = w[c*9 + tap];
}

// ---------------- MFMA bf16 GEMM (NT), global_load_lds staging, 2-phase dbuf ----------------
template<typename TC>
__global__ __launch_bounds__(256) void mfma_gemm(
    const bf16* __restrict__ A, const bf16* __restrict__ Bw,
    const float* __restrict__ bias, const float* __restrict__ addend,
    TC* __restrict__ C, int M, int N, int K, int lda,
    long long strA, long long strB, long long strC, long long strAdd)
{
    __shared__ __align__(16) float smemf[8192];   // 32 KB: 2x {A 4096 shorts | B 4096 shorts}
    short* S = (short*)smemf;
    int tid = threadIdx.x;
    int bz = blockIdx.z;
    A  += (long long)bz * strA;
    Bw += (long long)bz * strB;
    C  += (long long)bz * strC;
    if (addend) addend += (long long)bz * strAdd;

    // --- bijective XCD chunk swizzle (m204) over the (x,y) tile space ---
    int gx = gridDim.x;
    int nwg = gx * gridDim.y;
    int bidl = blockIdx.y * gx + blockIdx.x;
    int qq = nwg >> 3, rr = nwg & 7;
    int xcd = bidl & 7, ixx = bidl >> 3;
    int tile = (xcd < rr) ? (xcd*(qq+1) + ixx) : (rr*(qq+1) + (xcd-rr)*qq + ixx);
    int n0 = (tile % gx) * 128, m0 = (tile / gx) * 128;

    int w = tid >> 6, lane = tid & 63, lm = lane & 15, quad = lane >> 4;
    int mw = (w >> 1) * 64, nw = (w & 1) * 64;

    // staging: wave w issues instructions t=2w,2w+1; lane covers chunk t*64+lane.
    int c0 = w*128 + lane, c1 = c0 + 64;
    int ar0 = c0 >> 2, ac0 = (c0 & 3) ^ (ar0 & 3);
    int ar1 = c1 >> 2, ac1 = (c1 & 3) ^ (ar1 & 3);
    int rgA0 = m0 + ar0; if (rgA0 > M-1) rgA0 = M-1;
    int rgA1 = m0 + ar1; if (rgA1 > M-1) rgA1 = M-1;
    short* aL0 = S + (2*w+0)*512;
    short* aL1 = S + (2*w+1)*512;
    short* bL0 = S + 4096 + (2*w+0)*512;
    short* bL1 = S + 4096 + (2*w+1)*512;
    const bf16* Arow0 = A + (long long)rgA0*lda + ac0*8;
    const bf16* Arow1 = A + (long long)rgA1*lda + ac1*8;
    const bf16* Brow0 = Bw + (long long)(n0+ar0)*K + ac0*8;
    const bf16* Brow1 = Bw + (long long)(n0+ar1)*K + ac1*8;

    floatx4 z = {0.f, 0.f, 0.f, 0.f};
    floatx4 acc[4][4];
    #pragma unroll
    for (int mi = 0; mi < 4; mi++)
        #pragma unroll
        for (int ni = 0; ni < 4; ni++) acc[mi][ni] = z;

    int sq = quad ^ (lm & 3);   // read-side swizzle (row&3 == lm&3 for all fragment rows)

    auto STAGE = [&](int k0, int poff){
        gload16(Arow0 + k0, aL0 + poff);
        gload16(Arow1 + k0, aL1 + poff);
        gload16(Brow0 + k0, bL0 + poff);
        gload16(Brow1 + k0, bL1 + poff);
    };

    STAGE(0, 0);
    __syncthreads();                 // drains prologue loads
    int NS = K >> 5;
    for (int st = 0; st < NS; st++){
        int poff = (st & 1) << 13;                       // 0 / 8192 shorts
        if (st + 1 < NS) STAGE((st+1)*32, poff ^ 8192);  // prefetch into other buffer
        short8 af[4], bfr[4];
        #pragma unroll
        for (int mi = 0; mi < 4; mi++)
            af[mi] = *(const short8*)&S[poff + (((mw + mi*16 + lm)<<2) + sq)*8];
        #pragma unroll
        for (int ni = 0; ni < 4; ni++)
            bfr[ni] = *(const short8*)&S[poff + 4096 + (((nw + ni*16 + lm)<<2) + sq)*8];
        #pragma unroll
        for (int mi = 0; mi < 4; mi++)
            #pragma unroll
            for (int ni = 0; ni < 4; ni++)
                acc[mi][ni] = __builtin_amdgcn_mfma_f32_16x16x32_bf16(af[mi], bfr[ni], acc[mi][ni], 0, 0, 0);
        __syncthreads();             // one barrier per K-step: readers done + prefetch landed
    }

    // --- epilogue: per-wave transpose through LDS, wide contiguous stores ---
    float bvv[4];
    #pragma unroll
    for (int ni = 0; ni < 4; ni++)
        bvv[ni] = bias ? bias[n0 + nw + ni*16 + lm] : 0.f;
    float* esc = smemf + w*1088;            // 16 rows x 68 floats per wave
    int rl0 = lane >> 3;                    // 0..7
    #pragma unroll
    for (int mi = 0; mi < 4; mi++){
        #pragma unroll
        for (int ni = 0; ni < 4; ni++)
            #pragma unroll
            for (int r = 0; r < 4; r++)
                esc[(quad*4 + r)*68 + ni*16 + lm] = acc[mi][ni][r] + bvv[ni];
        #pragma unroll
        for (int p = 0; p < 2; p++){
            int rloc = p*8 + rl0;
            int rg = m0 + mw + mi*16 + rloc;
            if (rg < M){
                if constexpr (sizeof(TC) == 2){
                    int cl = (lane & 7) * 8;        // 8 lanes x 8 bf16 = 128B/row
                    float4 u0 = *(const float4*)&esc[rloc*68 + cl];
                    float4 u1 = *(const float4*)&esc[rloc*68 + cl + 4];
                    if (addend){
                        long long ai = (long long)rg*N + (n0 + nw + cl);
                        float4 a0 = *(const float4*)(addend + ai);
                        float4 a1 = *(const float4*)(addend + ai + 4);
                        u0.x+=a0.x; u0.y+=a0.y; u0.z+=a0.z; u0.w+=a0.w;
                        u1.x+=a1.x; u1.y+=a1.y; u1.z+=a1.z; u1.w+=a1.w;
                    }
                    union { uint4 u; unsigned short us[8]; } pk;
                    pk.us[0]=bfbits(u0.x); pk.us[1]=bfbits(u0.y); pk.us[2]=bfbits(u0.z); pk.us[3]=bfbits(u0.w);
                    pk.us[4]=bfbits(u1.x); pk.us[5]=bfbits(u1.y); pk.us[6]=bfbits(u1.z); pk.us[7]=bfbits(u1.w);
                    *(uint4*)(C + (long long)rg*N + (n0 + nw + cl)) = pk.u;
                } else {
                    int cl4 = (lane & 7) * 4;       // 8 lanes x 4 f32 = 128B per half-row
                    long long co = (long long)rg*N + (n0 + nw);
                    float4 u0 = *(const float4*)&esc[rloc*68 + cl4];
                    float4 u1 = *(const float4*)&esc[rloc*68 + 32 + cl4];
                    if (addend){
                        float4 a0 = *(const float4*)(addend + co + cl4);
                        float4 a1 = *(const float4*)(addend + co + 32 + cl4);
                        u0.x+=a0.x; u0.y+=a0.y; u0.z+=a0.z; u0.w+=a0.w;
                        u1.x+=a1.x; u1.y+=a1.y; u1.z+=a1.z; u1.w+=a1.w;
                    }
                    *(float4*)(C + co + cl4) = u0;
                    *(float4*)(C + co + 32 + cl4) = u1;
                }
            }
        }
    }
}

// ---------------- MFMA GEMM + fused row-LayerNorm (N=256, 64x256 tile, grid x=1) ----------------
// Block owns FULL 256-col rows (64 of them) -> LN per row is block-local.
// Epilogue: transpose+bias+addend -> store C f32, accumulate per-row sum/sumsq via
// 8-lane shfl groups -> LDS -> cross-wave reduce -> re-read just-written C (L2-hot)
// -> normalize -> write bf16 lnout. Replaces the separate ln4_kernel.
// NOTE: lnout must NOT alias any buffer other blocks of this launch still read.
__global__ __launch_bounds__(256) void gemm_ln(
    const bf16* __restrict__ A, const bf16* __restrict__ Bw,
    const float* __restrict__ bias, const float* __restrict__ addend,
    float* __restrict__ C, bf16* __restrict__ lnout,
    const float* __restrict__ lg, const float* __restrict__ lb,
    int M, int K, int lda,
    long long strA, long long strB, long long strC, long long strAdd, long long strLn)
{
    __shared__ __align__(16) float smemf[10240];  // 40 KB: 2x {A 2048 shorts | B 8192 shorts}
    short* S = (short*)smemf;
    constexpr int POFF = 10240;                   // dbuf stride in shorts
    int tid = threadIdx.x;
    int bz = blockIdx.z;
    A      += (long long)bz * strA;
    Bw     += (long long)bz * strB;
    C      += (long long)bz * strC;
    addend += (long long)bz * strAdd;
    lnout  += (long long)bz * strLn;

    // bijective XCD swizzle over y tiles
    int nwg = gridDim.y;
    int bidl = blockIdx.y;
    int qq = nwg >> 3, rr = nwg & 7;
    int xcd = bidl & 7, ixx = bidl >> 3;
    int tile = (xcd < rr) ? (xcd*(qq+1) + ixx) : (rr*(qq+1) + (xcd-rr)*qq + ixx);
    int m0 = tile * 64;

    int w = tid >> 6, lane = tid & 63, lm = lane & 15, quad = lane >> 4;
    int nw = w * 64;                              // wave's 64-col chunk; all waves share rows

    // staging: 20 chunk-groups per K-step (A:4, B:16); wave w issues t=5w..5w+4.
    const bf16* gp[5];
    int lo[5];
    #pragma unroll
    for (int t5 = 0; t5 < 5; t5++){
        int t = w*5 + t5;
        if (t < 4){
            int c = t*64 + lane;
            int row = c >> 2, cg = (c & 3) ^ (row & 3);
            int rg = m0 + row; if (rg > M-1) rg = M-1;
            gp[t5] = A + (long long)rg*lda + cg*8;
            lo[t5] = t*512;                       // wave-uniform LDS base (HW adds lane*16B)
        } else {
            int c = (t-4)*64 + lane;
            int row = c >> 2, cg = (c & 3) ^ (row & 3);
            gp[t5] = Bw + (long long)row*K + cg*8;
            lo[t5] = 2048 + (t-4)*512;
        }
    }

    floatx4 z = {0.f,0.f,0.f,0.f};
    floatx4 acc[4][4];
    #pragma unroll
    for (int mi = 0; mi < 4; mi++)
        #pragma unroll
        for (int ni = 0; ni < 4; ni++) acc[mi][ni] = z;

    int sq = quad ^ (lm & 3);

    auto STAGE = [&](int k0, int poff){
        #pragma unroll
        for (int t5 = 0; t5 < 5; t5++)
            gload16(gp[t5] + k0, S + lo[t5] + poff);
    };

    STAGE(0, 0);
    __syncthreads();
    int NS = K >> 5;
    for (int st = 0; st < NS; st++){
        int poff = (st & 1) ? POFF : 0;
        if (st + 1 < NS) STAGE((st+1)*32, poff ^ POFF);
        short8 af[4], bfr[4];
        #pragma unroll
        for (int mi = 0; mi < 4; mi++)
            af[mi] = *(const short8*)&S[poff + (((mi*16 + lm)<<2) + sq)*8];
        #pragma unroll
        for (int ni = 0; ni < 4; ni++)
            bfr[ni] = *(const short8*)&S[poff + 2048 + (((nw + ni*16 + lm)<<2) + sq)*8];
        #pragma unroll
        for (int mi = 0; mi < 4; mi++)
            #pragma unroll
            for (int ni = 0; ni < 4; ni++)
                acc[mi][ni] = __builtin_amdgcn_mfma_f32_16x16x32_bf16(af[mi], bfr[ni], acc[mi][ni], 0, 0, 0);
        __syncthreads();
    }

    // --- epilogue pass 1: transpose, +bias +addend, store f32, row-stat partials ---
    float bvv[4];
    #pragma unroll
    for (int ni = 0; ni < 4; ni++)
        bvv[ni] = bias[nw + ni*16 + lm];
    float* esc  = smemf + w*1088;                 // 16 rows x 68 floats per wave
    float* ssum = smemf + 4608;                   // [4 waves][64 rows]
    float* ssq  = smemf + 4864;
    float* mrow = smemf + 5120;                   // [64]
    float* irow = smemf + 5184;                   // [64]
    int rl0 = lane >> 3, jo = lane & 7;
    int cl4 = jo * 4;
    #pragma unroll
    for (int mi = 0; mi < 4; mi++){
        #pragma unroll
        for (int ni = 0; ni < 4; ni++)
            #pragma unroll
            for (int r = 0; r < 4; r++)
                esc[(quad*4 + r)*68 + ni*16 + lm] = acc[mi][ni][r] + bvv[ni];
        #pragma unroll
        for (int p = 0; p < 2; p++){
            int rloc = p*8 + rl0;
            int rg = m0 + mi*16 + rloc;
            long long co = (long long)rg*256 + nw;
            float4 u0 = *(const float4*)&esc[rloc*68 + cl4];
            float4 u1 = *(const float4*)&esc[rloc*68 + 32 + cl4];
            float4 a0 = *(const float4*)(addend + co + cl4);
            float4 a1 = *(const float4*)(addend + co + 32 + cl4);
            u0.x+=a0.x; u0.y+=a0.y; u0.z+=a0.z; u0.w+=a0.w;
            u1.x+=a1.x; u1.y+=a1.y; u1.z+=a1.z; u1.w+=a1.w;
            *(float4*)(C + co + cl4) = u0;
            *(float4*)(C + co + 32 + cl4) = u1;
            float s = u0.x+u0.y+u0.z+u0.w + u1.x+u1.y+u1.z+u1.w;
            float q = u0.x*u0.x+u0.y*u0.y+u0.z*u0.z+u0.w*u0.w
                    + u1.x*u1.x+u1.y*u1.y+u1.z*u1.z+u1.w*u1.w;
            #pragma unroll
            for (int off = 1; off < 8; off <<= 1){
                s += __shfl_xor(s, off);
                q += __shfl_xor(q, off);
            }
            if (jo == 0){
                ssum[w*64 + mi*16 + rloc] = s;
                ssq [w*64 + mi*16 + rloc] = q;
            }
        }
    }
    __syncthreads();
    if (tid < 64){
        float s = ssum[tid] + ssum[64+tid] + ssum[128+tid] + ssum[192+tid];
        float q = ssq[tid]  + ssq[64+tid]  + ssq[128+tid]  + ssq[192+tid];
        float mean = s * (1.f/256.f);
        float var  = q * (1.f/256.f) - mean*mean;
        mrow[tid] = mean;
        irow[tid] = rsqrtf(var + 1e-5f);
    }
    __syncthreads();
    // --- epilogue pass 2: re-read C (L2-hot), normalize, write bf16 lnout ---
    int cl8 = jo * 8;
    float4 gl0 = *(const float4*)(lg + nw + cl8);
    float4 gl1 = *(const float4*)(lg + nw + cl8 + 4);
    float4 bl0 = *(const float4*)(lb + nw + cl8);
    float4 bl1 = *(const float4*)(lb + nw + cl8 + 4);
    float gg[8] = {gl0.x,gl0.y,gl0.z,gl0.w,gl1.x,gl1.y,gl1.z,gl1.w};
    float bbv[8] = {bl0.x,bl0.y,bl0.z,bl0.w,bl1.x,bl1.y,bl1.z,bl1.w};
    #pragma unroll
    for (int mi = 0; mi < 4; mi++){
        #pragma unroll
        for (int p = 0; p < 2; p++){
            int rloc = p*8 + rl0;
            int row64 = mi*16 + rloc;
            int rg = m0 + row64;
            float mean = mrow[row64], inv = irow[row64];
            long long co = (long long)rg*256 + nw + cl8;
            float4 v0 = *(const float4*)(C + co);
            float4 v1 = *(const float4*)(C + co + 4);
            float vv[8] = {v0.x,v0.y,v0.z,v0.w,v1.x,v1.y,v1.z,v1.w};
            union { uint4 u; unsigned short us[8]; } pk;
            #pragma unroll
            for (int i = 0; i < 8; i++)
                pk.us[i] = bfbits((vv[i]-mean)*inv*gg[i] + bbv[i]);
            *(uint4*)(lnout + co) = pk.u;
        }
    }
}

// ---------------- MFMA bf16 TN GEMM: part[s][vc][kc] = sum_{n in split s} V[n,vc]*K[n,kc] ----------------
__global__ __launch_bounds__(256) void gemm_tn_mfma(const bf16* __restrict__ V, const bf16* __restrict__ Kb,
                                                    float* __restrict__ part){
    __shared__ short As[128*LP];
    __shared__ short Bs[128*LP];
    int tid = threadIdx.x;
    int bz = blockIdx.z;           // b*TNS + s
    int b = bz / TNS, s = bz % TNS;
    const bf16* Vb = V  + (long long)b*NPOS*CDIM;
    const bf16* Kc = Kb + (long long)b*NPOS*CDIM;
    int m0 = blockIdx.y * 128, n0 = blockIdx.x * 128;
    int w = tid >> 6, lane = tid & 63, lm = lane & 15, quad = lane >> 4;
    int mw = (w >> 1) * 64, nw = (w & 1) * 64;

    floatx4 z = {0.f,0.f,0.f,0.f};
    floatx4 acc[4][4];
    #pragma unroll
    for (int mi = 0; mi < 4; mi++)
        #pragma unroll
        for (int ni = 0; ni < 4; ni++) acc[mi][ni] = z;

    int r = tid & 31, cgrp = tid >> 5;

    for (int step = 0; step < 448/32; step++){
        int nb = s*448 + step*32;
        #pragma unroll
        for (int cc = 0; cc < 2; cc++){
            int ch = cgrp*8 + cc*64;
            short8 va = *(const short8*)(Vb + (long long)(nb + r)*CDIM + m0 + ch);
            short8 ka = *(const short8*)(Kc + (long long)(nb + r)*CDIM + n0 + ch);
            #pragma unroll
            for (int i = 0; i < 8; i++){
                As[(ch+i)*LP + r] = va[i];
                Bs[(ch+i)*LP + r] = ka[i];
            }
        }
        __syncthreads();
        short8 af[4], bfr[4];
        #pragma unroll
        for (int mi = 0; mi < 4; mi++)
            af[mi] = *(const short8*)&As[(mw + mi*16 + lm)*LP + quad*8];
        #pragma unroll
        for (int ni = 0; ni < 4; ni++)
            bfr[ni] = *(const short8*)&Bs[(nw + ni*16 + lm)*LP + quad*8];
        #pragma unroll
        for (int mi = 0; mi < 4; mi++)
            #pragma unroll
            for (int ni = 0; ni < 4; ni++)
                acc[mi][ni] = __builtin_amdgcn_mfma_f32_16x16x32_bf16(af[mi], bfr[ni], acc[mi][ni], 0, 0, 0);
        __syncthreads();
    }

    float* pb = part + (long long)bz * CDIM * CDIM;
    #pragma unroll
    for (int ni = 0; ni < 4; ni++){
        int cg = n0 + nw + ni*16 + lm;
        #pragma unroll
        for (int mi = 0; mi < 4; mi++){
            #pragma unroll
            for (int rr = 0; rr < 4; rr++){
                int rg = m0 + mw + mi*16 + quad*4 + rr;
                pb[(long long)rg*CDIM + cg] = acc[mi][ni][rr];
            }
        }
    }
}

__global__ __launch_bounds__(256) void ctx_reduce(const float* __restrict__ part, bf16* __restrict__ ctxb){
    long long idx = (long long)blockIdx.x*256 + threadIdx.x;
    int b = (int)(idx >> 16);
    int rem = (int)(idx & 65535);
    float s = 0.f;
    #pragma unroll
    for (int sp = 0; sp < TNS; sp++)
        s += part[((long long)(b*TNS+sp) << 16) + rem];
    ctxb[idx] = __float2bfloat16(s);
}

// ---------------- LayerNorm: one wave per row ----------------
DI void st4o(float* p, long long i, float a, float b, float c, float d){
    float4 v = make_float4(a,b,c,d); *(float4*)(p + i) = v;
}
DI void st4o(bf16* p, long long i, float a, float b, float c, float d){
    union { unsigned long long u; unsigned short us[4]; } pk;
    pk.us[0]=bfbits(a); pk.us[1]=bfbits(b); pk.us[2]=bfbits(c); pk.us[3]=bfbits(d);
    *(unsigned long long*)(p + i) = pk.u;
}
template<typename TOUT>
__global__ __launch_bounds__(256) void ln4_kernel(const float* __restrict__ x, const float* __restrict__ g,
                                                  const float* __restrict__ b, TOUT* __restrict__ y){
    int wv = threadIdx.x >> 6, lane = threadIdx.x & 63;
    long long row = (long long)blockIdx.x*4 + wv;
    float4 v = *(const float4*)(x + row*256 + lane*4);
    float s  = v.x + v.y + v.z + v.w;
    float ss = v.x*v.x + v.y*v.y + v.z*v.z + v.w*v.w;
    #pragma unroll
    for (int off = 32; off > 0; off >>= 1){
        s  += __shfl_down(s,  off);
        ss += __shfl_down(ss, off);
    }
    s = __shfl(s, 0); ss = __shfl(ss, 0);
    float mean = s * (1.f/256.f);
    float var  = ss * (1.f/256.f) - mean*mean;
    float inv  = rsqrtf(var + 1e-5f);
    float4 gv = *(const float4*)(g + lane*4);
    float4 bv = *(const float4*)(b + lane*4);
    st4o(y, row*256 + lane*4,
         (v.x-mean)*inv*gv.x + bv.x, (v.y-mean)*inv*gv.y + bv.y,
         (v.z-mean)*inv*gv.z + bv.z, (v.w-mean)*inv*gv.w + bv.w);
}

// ---------------- column softmax over N (k = cols 0..255 of KQ[.,512]) ----------------
__global__ __launch_bounds__(256) void colsm_p1(const float* __restrict__ x, float* __restrict__ lmax, float* __restrict__ lsum){
    int b = blockIdx.x / NCHUNK, ch = blockIdx.x % NCHUNK;
    int c = threadIdx.x;
    const float* base = x + ((long long)b*NPOS + ch*64)*512 + c;
    float m = -1e30f;
    for (int r = 0; r < 64; r++) m = fmaxf(m, base[(long long)r*512]);
    float s = 0.f;
    for (int r = 0; r < 64; r++) s += expf(base[(long long)r*512] - m);
    lmax[(long long)blockIdx.x*CDIM + c] = m;
    lsum[(long long)blockIdx.x*CDIM + c] = s;
}
__global__ __launch_bounds__(256) void colsm_p2(const float* __restrict__ lmax, const float* __restrict__ lsum,
                                                float* __restrict__ gmax, float* __restrict__ ginv){
    int b = blockIdx.x; int c = threadIdx.x;
    float g = -1e30f;
    for (int ch = 0; ch < NCHUNK; ch++) g = fmaxf(g, lmax[((long long)b*NCHUNK+ch)*CDIM + c]);
    float s = 0.f;
    for (int ch = 0; ch < NCHUNK; ch++)
        s += lsum[((long long)b*NCHUNK+ch)*CDIM + c] * expf(lmax[((long long)b*NCHUNK+ch)*CDIM + c] - g);
    gmax[b*CDIM + c] = g; ginv[b*CDIM + c] = 1.f / s;
}

// ---------------- fused kq softmax: q row-softmax + k col-softmax apply, one pass over KQ ----------------
__global__ __launch_bounds__(256) void kqsm_kernel(const float* __restrict__ x, const float* __restrict__ bias,
                                                   const float* __restrict__ gmax, const float* __restrict__ ginv,
                                                   bf16* __restrict__ kb, bf16* __restrict__ qb){
    int wv = threadIdx.x >> 6, lane = threadIdx.x & 63;
    long long row = (long long)blockIdx.x*4 + wv;
    int b = blockIdx.x / 784;               // 784 blocks per batch (3136/4)
    // --- q row softmax (cols 256..511), bias added here ---
    float4 v = *(const float4*)(x + row*512 + 256 + lane*4);
    float4 bb = *(const float4*)(bias + lane*4);
    v.x += bb.x; v.y += bb.y; v.z += bb.z; v.w += bb.w;
    float m = fmaxf(fmaxf(v.x, v.y), fmaxf(v.z, v.w));
    #pragma unroll
    for (int off = 32; off > 0; off >>= 1) m = fmaxf(m, __shfl_down(m, off));
    m = __shfl(m, 0);
    float e0 = expf(v.x - m), e1 = expf(v.y - m), e2 = expf(v.z - m), e3 = expf(v.w - m);
    float s = e0 + e1 + e2 + e3;
    #pragma unroll
    for (int off = 32; off > 0; off >>= 1) s += __shfl_down(s, off);
    s = __shfl(s, 0);
    float inv = 1.f / s;
    st4o(qb, row*256 + lane*4, e0*inv, e1*inv, e2*inv, e3*inv);
    // --- k column softmax apply (cols 0..255) ---
    float4 kv = *(const float4*)(x + row*512 + lane*4);
    float4 gm = *(const float4*)(gmax + b*CDIM + lane*4);
    float4 gi = *(const float4*)(ginv + b*CDIM + lane*4);
    st4o(kb, row*256 + lane*4,
         expf(kv.x - gm.x)*gi.x, expf(kv.y - gm.y)*gi.y,
         expf(kv.z - gm.z)*gi.z, expf(kv.w - gm.w)*gi.w);
}

// ---------------- fused dwconv3x3 + skip + LN + GELU, direct-load, 4 positions/thread ----------------
// Adjacent positions share input columns: 4 pos need 6 cols (4.5 loads/pos vs 6) and
// weights are loaded once per 4 positions. Block = 8 positions x 1024 ch.
template<bool G>
DI void conv_core4(const bf16* __restrict__ fb, const float* __restrict__ wT,
                   int h, int pw0, int c0, float a[4][8]){
    #pragma unroll
    for (int r = 0; r < 3; r++){
        int hy = h - 1 + r;
        bool rv = !G || (hy >= 0 && hy < HH);
        int hyc = G ? min(max(hy, 0), HH-1) : hy;
        float u[6][8];
        #pragma unroll
        for (int c = 0; c < 6; c++){
            int wx = pw0 - 1 + c;
            bool vv = rv && (!G || (wx >= 0 && wx < WW));
            int wxc = G ? min(max(wx, 0), WW-1) : wx;
            uint4 raw = *(const uint4*)(fb + (long long)(hyc*WW + wxc)*HIDD + c0);
            unsigned short* us = (unsigned short*)&raw;
            #pragma unroll
            for (int i = 0; i < 8; i++){
                float xv = bu(us[i]);
                u[c][i] = (G && !vv) ? 0.f : xv;
            }
        }
        #pragma unroll
        for (int kx = 0; kx < 3; kx++){
            float4 wA = *(const float4*)(wT + (r*3+kx)*1024 + c0);
            float4 wB = *(const float4*)(wT + (r*3+kx)*1024 + c0 + 4);
            float wv[8] = {wA.x,wA.y,wA.z,wA.w,wB.x,wB.y,wB.z,wB.w};
            #pragma unroll
            for (int j = 0; j < 4; j++)
                #pragma unroll
                for (int i = 0; i < 8; i++)
                    a[j][i] = fmaf(u[kx+j][i], wv[i], a[j][i]);
        }
        if (r == 1){    // identity skip: + center value
            #pragma unroll
            for (int j = 0; j < 4; j++)
                #pragma unroll
                for (int i = 0; i < 8; i++) a[j][i] += u[j+1][i];
        }
    }
}

__global__ __launch_bounds__(256) void dwconv_ln_gelu_kernel(const bf16* __restrict__ f, const float* __restrict__ wT,
        const float* __restrict__ db, const float* __restrict__ lg, const float* __restrict__ lb, bf16* __restrict__ out){
    __shared__ float rs[8][128], rq[8][128], rfin[16];
    int tid = threadIdx.x;
    // XCD swizzle: consecutive blockIdx -> different batch images.
    int b = blockIdx.x & 7;
    int rem = blockIdx.x >> 3;              // 0..391
    int h = rem / 7, w0 = (rem % 7) * 8;
    const bf16* fb = f + (long long)b * NPOS * HIDD;
    int ph = tid >> 7, ct = tid & 127;
    int c0 = ct * 8;
    int pw0 = w0 + ph*4;                    // this thread's 4 positions: pw0..pw0+3

    float acc[4][8];
    {
        float4 d0 = *(const float4*)(db + c0);
        float4 d1 = *(const float4*)(db + c0 + 4);
        #pragma unroll
        for (int j = 0; j < 4; j++){
            acc[j][0]=d0.x; acc[j][1]=d0.y; acc[j][2]=d0.z; acc[j][3]=d0.w;
            acc[j][4]=d1.x; acc[j][5]=d1.y; acc[j][6]=d1.z; acc[j][7]=d1.w;
        }
    }
    bool interior = (h >= 1) && (h <= 54) && (pw0 >= 1) && (pw0 <= 51);
    if (interior) conv_core4<false>(fb, wT, h, pw0, c0, acc);
    else          conv_core4<true >(fb, wT, h, pw0, c0, acc);

    // LN partials: group g = ph*4 + j
    #pragma unroll
    for (int j = 0; j < 4; j++){
        float s = 0.f, q = 0.f;
        #pragma unroll
        for (int i = 0; i < 8; i++){ s += acc[j][i]; q += acc[j][i]*acc[j][i]; }
        rs[ph*4+j][ct] = s; rq[ph*4+j][ct] = q;
    }
    __syncthreads();
    {
        int g = tid >> 5, jn = tid & 31;    // 32 threads per group
        float s = rs[g][jn] + rs[g][jn+32] + rs[g][jn+64] + rs[g][jn+96];
        float q = rq[g][jn] + rq[g][jn+32] + rq[g][jn+64] + rq[g][jn+96];
        #pragma unroll
        for (int off = 16; off > 0; off >>= 1){   // xor < 32 stays within half-wave group
            s += __shfl_xor(s, off);
            q += __shfl_xor(q, off);
        }
        if (jn == 0){ rfin[g] = s; rfin[8+g] = q; }
    }
    __syncthreads();
    float4 g0 = *(const float4*)(lg + c0), g1 = *(const float4*)(lg + c0 + 4);
    float4 b0 = *(const float4*)(lb + c0), b1 = *(const float4*)(lb + c0 + 4);
    float gg[8] = {g0.x,g0.y,g0.z,g0.w,g1.x,g1.y,g1.z,g1.w};
    float bb[8] = {b0.x,b0.y,b0.z,b0.w,b1.x,b1.y,b1.z,b1.w};
    #pragma unroll
    for (int j = 0; j < 4; j++){
        int g = ph*4 + j;
        long long n = (long long)b*NPOS + h*WW + (pw0 + j);
        float mean = rfin[g] * (1.f/HIDD);
        float var  = rfin[8+g] * (1.f/HIDD) - mean*mean;
        float inv  = rsqrtf(var + 1e-5f);
        union { uint4 u; unsigned short us[8]; } ov;
        #pragma unroll
        for (int i = 0; i < 8; i++){
            float o = (acc[j][i]-mean)*inv*gg[i] + bb[i];
            ov.us[i] = bfbits(gelu_exact(o));
        }
        *(uint4*)(out + n*HIDD + c0) = ov.u;
    }
}

// ---------------- channel-attn: per-channel sum-sq over N ----------------
__global__ __launch_bounds__(256) void ssq_p1(const bf16* __restrict__ qkv, float* __restrict__ lss){
    __shared__ float red[4][64][8];
    int b = blockIdx.x / NCHUNK, ch = blockIdx.x % NCHUNK;
    int tid = threadIdx.x;
    int col = (tid & 63) * 8;
    int rg = tid >> 6;
    float s[8] = {0,0,0,0,0,0,0,0};
    for (int r = rg*16; r < rg*16 + 16; r++){
        long long row = (long long)(b*NPOS + ch*64 + r);
        union { uint4 u; unsigned short us[8]; } v;
        v.u = *(const uint4*)(qkv + row*768 + col);
        #pragma unroll
        for (int i = 0; i < 8; i++){ float f = bu(v.us[i]); s[i] += f*f; }
    }
    #pragma unroll
    for (int i = 0; i < 8; i++) red[rg][tid & 63][i] = s[i];
    __syncthreads();
    if (tid < 64){
        #pragma unroll
        for (int i = 0; i < 8; i++){
            float t = red[0][tid][i] + red[1][tid][i] + red[2][tid][i] + red[3][tid][i];
            lss[(long long)blockIdx.x*512 + tid*8 + i] = t;
        }
    }
}
__global__ __launch_bounds__(256) void ssq_p2(const float* __restrict__ lss, float* __restrict__ invn){
    int b = blockIdx.x; int c = blockIdx.y*256 + threadIdx.x;
    float s = 0.f;
    for (int ch = 0; ch < NCHUNK; ch++) s += lss[((long long)b*NCHUNK+ch)*512 + c];
    invn[b*512 + c] = 1.f / fmaxf(sqrtf(s), 1e-12f);
}

// ---------------- channel-attn QK partials ----------------
__global__ __launch_bounds__(256) void chanattn_qk_part(const bf16* __restrict__ qkv, const float* __restrict__ invn,
                                                        float* __restrict__ part){
    __shared__ float qs[64][36];
    __shared__ float ks[64][36];
    int bz = blockIdx.x;               // (b*8+hh)*TNS + s
    int bh = bz / TNS, s = bz % TNS;
    int b = bh >> 3, hh = bh & 7;
    int tid = threadIdx.x;
    int d = tid >> 3, e0 = (tid & 7) * 4;
    int sr = tid >> 2, sc8 = (tid & 3) * 8;
    float invq[8], invk[8];
    {
        float4 a0 = *(const float4*)(invn + b*512 + hh*32 + sc8);
        float4 a1 = *(const float4*)(invn + b*512 + hh*32 + sc8 + 4);
        float4 b0 = *(const float4*)(invn + b*512 + 256 + hh*32 + sc8);
        float4 b1 = *(const float4*)(invn + b*512 + 256 + hh*32 + sc8 + 4);
        invq[0]=a0.x; invq[1]=a0.y; invq[2]=a0.z; invq[3]=a0.w;
        invq[4]=a1.x; invq[5]=a1.y; invq[6]=a1.z; invq[7]=a1.w;
        invk[0]=b0.x; invk[1]=b0.y; invk[2]=b0.z; invk[3]=b0.w;
        invk[4]=b1.x; invk[5]=b1.y; invk[6]=b1.z; invk[7]=b1.w;
    }
    float acc[4] = {0.f,0.f,0.f,0.f};
    for (int it = 0; it < 7; it++){
        int n0 = s*448 + it*64;
        {
            long long rowb = (long long)(b*NPOS + n0 + sr) * 768;
            union { uint4 u; unsigned short us[8]; } qv, kv;
            qv.u = *(const uint4*)(qkv + rowb + hh*32 + sc8);
            kv.u = *(const uint4*)(qkv + rowb + 256 + hh*32 + sc8);
            #pragma unroll
            for (int i = 0; i < 8; i++){
                qs[sr][sc8+i] = bu(qv.us[i]) * invq[i];
                ks[sr][sc8+i] = bu(kv.us[i]) * invk[i];
            }
        }
        __syncthreads();
        #pragma unroll 4
        for (int r = 0; r < 64; r++){
            float qv = qs[r][d];
            #pragma unroll
            for (int j = 0; j < 4; j++) acc[j] += qv * ks[r][e0+j];
        }
        __syncthreads();
    }
    #pragma unroll
    for (int j = 0; j < 4; j++)
        part[(long long)bz*1024 + d*32 + e0 + j] = acc[j];
}
__global__ __launch_bounds__(256) void chanattn_qk_fin(const float* __restrict__ part, const float* __restrict__ temp,
                                                       float* __restrict__ attn){
    __shared__ float att_s[32][33];
    int bh = blockIdx.x;
    int hh = bh & 7;
    int tid = threadIdx.x;
    int d = tid >> 3, e0 = (tid & 7) * 4;
    float t = temp[hh];
    #pragma unroll
    for (int j = 0; j < 4; j++){
        float s = 0.f;
        for (int sp = 0; sp < TNS; sp++)
            s += part[((long long)bh*TNS + sp)*1024 + d*32 + e0 + j];
        att_s[d][e0+j] = s * t;
    }
    __syncthreads();
    if (tid < 32){
        float m = -1e30f;
        for (int e = 0; e < 32; e++) m = fmaxf(m, att_s[tid][e]);
        float s = 0.f;
        for (int e = 0; e < 32; e++){ float ev = expf(att_s[tid][e] - m); att_s[tid][e] = ev; s += ev; }
        float inv = 1.f / s;
        for (int e = 0; e < 32; e++) att_s[tid][e] *= inv;
    }
    __syncthreads();
    #pragma unroll
    for (int j = 0; j < 4; j++)
        attn[(long long)bh*1024 + d*32 + e0 + j] = att_s[d][e0+j];
}

// ---------------- combined weight: W_b[o][h*32+e] = sum_d capw[o][h*32+d]*attn[b][h][d][e] ----------------
__global__ __launch_bounds__(256) void wcomb_kernel(const float* __restrict__ capw, const float* __restrict__ attn,
                                                    bf16* __restrict__ Wb){
    __shared__ float at_s[8192];
    int b = blockIdx.x, og = blockIdx.y;
    int tid = threadIdx.x;
    #pragma unroll
    for (int j = 0; j < 8; j++)
        *(float4*)&at_s[tid*32 + j*4] = *(const float4*)(attn + (long long)b*8192 + tid*32 + j*4);
    __syncthreads();
    int o = og*32 + (tid & 31);
    int h = tid >> 5;
    float acc[32];
    #pragma unroll
    for (int e = 0; e < 32; e++) acc[e] = 0.f;
    for (int d = 0; d < 32; d++){
        float w = capw[(long long)o*256 + h*32 + d];
        const float* ar = &at_s[h*1024 + d*32];
        #pragma unroll
        for (int eq = 0; eq < 8; eq++){
            float4 av = *(const float4*)(ar + eq*4);
            acc[eq*4+0] += w*av.x; acc[eq*4+1] += w*av.y;
            acc[eq*4+2] += w*av.z; acc[eq*4+3] += w*av.w;
        }
    }
    bf16* dst = Wb + (long long)b*65536 + (long long)o*256 + h*32;
    #pragma unroll
    for (int eq = 0; eq < 4; eq++){
        union { uint4 u; unsigned short us[8]; } p;
        #pragma unroll
        for (int i = 0; i < 8; i++) p.us[i] = bfbits(acc[eq*8+i]);
        *(uint4*)(dst + eq*8) = p.u;
    }
}

// ---------------- orchestration ----------------
extern "C" void kernel_launch(void* const* d_in, const int* in_sizes, int n_in,
                              void* d_out, int out_size, void* d_ws, size_t ws_size,
                              hipStream_t stream){
    const float* x     = (const float*)d_in[0];
    const float* ln1g  = (const float*)d_in[3];
    const float* ln1b  = (const float*)d_in[4];
    const float* eakw  = (const float*)d_in[5];
    const float* eaqw  = (const float*)d_in[7];
    const float* eaqb  = (const float*)d_in[8];
    const float* eavw  = (const float*)d_in[9];
    const float* eavb  = (const float*)d_in[10];
    const float* earw  = (const float*)d_in[11];
    const float* earb  = (const float*)d_in[12];
    const float* ln2g  = (const float*)d_in[13];
    const float* ln2b  = (const float*)d_in[14];
    const float* m1w1  = (const float*)d_in[15];
    const float* m1b1  = (const float*)d_in[16];
    const float* m1dww = (const float*)d_in[17];
    const float* m1dwb = (const float*)d_in[18];
    const float* m1lg  = (const float*)d_in[19];
    const float* m1lb  = (const float*)d_in[20];
    const float* m1w2  = (const float*)d_in[21];
    const float* m1b2  = (const float*)d_in[22];
    const float* ln3g  = (const float*)d_in[23];
    const float* ln3b  = (const float*)d_in[24];
    const float* catemp= (const float*)d_in[25];
    const float* caqkvw= (const float*)d_in[26];
    const float* capw  = (const float*)d_in[27];
    const float* capb  = (const float*)d_in[28];
    const float* ln4g  = (const float*)d_in[29];
    const float* ln4b  = (const float*)d_in[30];
    const float* m2w1  = (const float*)d_in[31];
    const float* m2b1  = (const float*)d_in[32];
    const float* m2dww = (const float*)d_in[33];
    const float* m2dwb = (const float*)d_in[34];
    const float* m2lg  = (const float*)d_in[35];
    const float* m2lb  = (const float*)d_in[36];
    const float* m2w2  = (const float*)d_in[37];
    const float* m2b2  = (const float*)d_in[38];

    char* base = (char*)d_ws;
    auto alloc = [&](size_t nbytes){ char* p = base; base += (nbytes + 255) & ~(size_t)255; return p; };
    constexpr size_t SZ = (size_t)MTOT*CDIM*4;
    float* R  = (float*)alloc(SZ);
    float* A0 = (float*)alloc(SZ);
    float* A1 = (float*)alloc(SZ);
    float* B0 = (float*)alloc(SZ);
    float* B1 = (float*)alloc(SZ);
    bf16* A0b  = (bf16*)A0;                 // s1: ln1 out, then k-softmax bf16
    bf16* kb   = (bf16*)A0;                 //     same region, second life
    bf16* qb   = A0b + (size_t)MTOT*CDIM;   // s1: q softmax out (second half A0)
    bf16* vb   = (bf16*)A1;                 // s1: v bf16
    float* KQ  = B0;                        // s1: fused k|q f32 [MTOT,512] spans B0..B1
    bf16* attb = (bf16*)B0;                 // s1: att out (KQ dead)
    bf16* l2b  = (bf16*)A1;                 // s2: ln2 out (vb dead) — written by fused proj
    bf16* F    = (bf16*)B0;                 // s2/s4: fc1 out (spans B0+B1)
    bf16* G    = (bf16*)A0;                 // s2/s4: dwconv out
    bf16* l3b  = (bf16*)B0;                 // s3: ln3 out (F dead) — written by fused fc2#1
    bf16* Qb   = (bf16*)A0;                 // s3: qkv — 38.5MB: spans A0 + first 12.8MB of A1!
    bf16* ctxb = (bf16*)alloc((size_t)BATCH*CDIM*CDIM*2);
    float* lmax = (float*)alloc((size_t)BATCH*NCHUNK*CDIM*4);
    float* lsum = (float*)alloc((size_t)BATCH*NCHUNK*CDIM*4);
    float* gmax = (float*)alloc((size_t)BATCH*CDIM*4);
    float* ginv = (float*)alloc((size_t)BATCH*CDIM*4);
    float* lss  = (float*)alloc((size_t)BATCH*NCHUNK*512*4);
    float* invn = (float*)alloc((size_t)BATCH*512*4);
    float* attnb= (float*)alloc((size_t)BATCH*8*32*32*4);
    float* ptn  = (float*)alloc((size_t)BATCH*TNS*CDIM*CDIM*4);
    float* pqk  = (float*)alloc((size_t)BATCH*8*TNS*1024*4);
    bf16* wbuf  = (bf16*)alloc((size_t)1572864*2);
    float* wT1  = (float*)alloc((size_t)9216*4);
    float* wT2  = (float*)alloc((size_t)9216*4);
    bf16* Wcb   = (bf16*)alloc((size_t)BATCH*CDIM*CDIM*2);
    // RACE FIX (R5 bug): ln4 output gets a DEDICATED buffer. It is written by the
    // chan-apply gemm_ln launch whose other blocks are still READING Qb's spill
    // region in A1 — aliasing l4b=A1 corrupted batches 5-7's V operand.
    bf16* l4b   = (bf16*)alloc((size_t)MTOT*CDIM*2);

    bf16* kqw_b    = wbuf;                  // [512,256]: rows 0-255 k, 256-511 q
    bf16* eavw_b   = wbuf + 131072;
    bf16* earw_b   = wbuf + 196608;
    bf16* m1w1_b   = wbuf + 262144;
    bf16* m1w2_b   = wbuf + 524288;
    bf16* caqkvw_b = wbuf + 786432;
    bf16* m2w1_b   = wbuf + 1048576;
    bf16* m2w2_b   = wbuf + 1310720;

    dim3 blk(256);
    constexpr int MB = MTOT/128;            // 196
    constexpr int MB64 = MTOT/64;           // 392
    long long sA1 = (long long)NPOS*CDIM;
    long long sB1 = (long long)CDIM*CDIM;

    // ---- weight prep ----
    {
        WArgs wa;
        const float* srcs[10] = {eakw, eaqw, eavw, earw, m1w1, m1w2, caqkvw, m2w1, m2w2, m2w2};
        bf16* dsts[10] = {kqw_b, kqw_b + 65536, eavw_b, earw_b, m1w1_b, m1w2_b, caqkvw_b, m2w1_b, m2w2_b, m2w2_b};
        int ns[10] = {65536, 65536, 65536, 65536, 262144, 262144, 196608, 262144, 262144, 0};
        for (int i = 0; i < 10; i++){ wa.src[i]=srcs[i]; wa.dst[i]=dsts[i]; wa.n[i]=ns[i]; }
        wcvt_kernel<<<dim3(128,10), blk, 0, stream>>>(wa);
        wtrans_kernel<<<dim3(36,2), blk, 0, stream>>>(m1dww, m2dww, wT1, wT2);
    }

    // ---- Stage 1: EfficientAttention ----
    ln4_kernel<bf16><<<MTOT/4, blk, 0, stream>>>(x, ln1g, ln1b, A0b);
    mfma_gemm<float><<<dim3(4,MB,1), blk, 0, stream>>>(A0b, kqw_b, nullptr, nullptr, KQ, MTOT, 512, 256, 256, 0,0,0,0); // k|q
    mfma_gemm<bf16><<<dim3(2,MB,1), blk, 0, stream>>>(A0b, eavw_b, eavb, nullptr, vb, MTOT, 256, 256, 256, 0,0,0,0);
    colsm_p1<<<BATCH*NCHUNK, blk, 0, stream>>>(KQ, lmax, lsum);
    colsm_p2<<<BATCH, blk, 0, stream>>>(lmax, lsum, gmax, ginv);
    kqsm_kernel<<<MTOT/4, blk, 0, stream>>>(KQ, eaqb, gmax, ginv, kb, qb);
    gemm_tn_mfma<<<dim3(2,2,BATCH*TNS), blk, 0, stream>>>(vb, kb, ptn);
    ctx_reduce<<<(BATCH*65536)/256, blk, 0, stream>>>(ptn, ctxb);
    mfma_gemm<bf16><<<dim3(2,25,BATCH), blk, 0, stream>>>(qb, ctxb, nullptr, nullptr, attb,
            NPOS, 256, 256, 256, sA1, sB1, sA1, 0);
    // proj + residual + fused ln2 -> R, l2b
    gemm_ln<<<dim3(1,MB64,1), blk, 0, stream>>>(attb, earw_b, earb, x, R, l2b, ln2g, ln2b,
            MTOT, 256, 256, 0,0,0,0,0);

    // ---- Stage 2: MixFFN #1 ----
    mfma_gemm<bf16><<<dim3(8,MB,1), blk, 0, stream>>>(l2b, m1w1_b, m1b1, nullptr, F, MTOT, 1024, 256, 256, 0,0,0,0);
    dwconv_ln_gelu_kernel<<<BATCH*HH*7, blk, 0, stream>>>(F, wT1, m1dwb, m1lg, m1lb, G);
    // fc2 + residual + fused ln3 -> R, l3b
    gemm_ln<<<dim3(1,MB64,1), blk, 0, stream>>>(G, m1w2_b, m1b2, R, R, l3b, ln3g, ln3b,
            MTOT, 1024, 1024, 0,0,0,0,0);

    // ---- Stage 3: ChannelAttention ----
    mfma_gemm<bf16><<<dim3(6,MB,1), blk, 0, stream>>>(l3b, caqkvw_b, nullptr, nullptr, Qb, MTOT, 768, 256, 256, 0,0,0,0);
    ssq_p1<<<BATCH*NCHUNK, blk, 0, stream>>>(Qb, lss);
    ssq_p2<<<dim3(BATCH,2), blk, 0, stream>>>(lss, invn);
    chanattn_qk_part<<<BATCH*8*TNS, blk, 0, stream>>>(Qb, invn, pqk);
    chanattn_qk_fin<<<BATCH*8, blk, 0, stream>>>(pqk, catemp, attnb);
    wcomb_kernel<<<dim3(BATCH,8), blk, 0, stream>>>(capw, attnb, Wcb);
    // chan apply + residual + fused ln4 -> R, l4b (dedicated buffer, no alias with Qb)
    gemm_ln<<<dim3(1,NPOS/64,BATCH), blk, 0, stream>>>(Qb + 512, Wcb, capb, R, R, l4b, ln4g, ln4b,
            NPOS, 256, 768, (long long)NPOS*768, sB1, sA1, sA1, (long long)NPOS*CDIM);

    // ---- Stage 4: MixFFN #2 ----
    mfma_gemm<bf16><<<dim3(8,MB,1), blk, 0, stream>>>(l4b, m2w1_b, m2b1, nullptr, F, MTOT, 1024, 256, 256, 0,0,0,0);
    dwconv_ln_gelu_kernel<<<BATCH*HH*7, blk, 0, stream>>>(F, wT2, m2dwb, m2lg, m2lb, G);
    mfma_gemm<float><<<dim3(2,MB,1), blk, 0, stream>>>(G, m2w2_b, m2b2, R, (float*)d_out, MTOT, 256, 1024, 1024, 0,0,0,0);
}